// Round 4
// baseline (445.074 us; speedup 1.0000x reference)
//
#include <hip/hip_runtime.h>
#include <math.h>

typedef __bf16 bf16;
typedef __bf16 bf16x8 __attribute__((ext_vector_type(8)));
typedef __bf16 bf16x4 __attribute__((ext_vector_type(4)));
typedef __bf16 bf16x2 __attribute__((ext_vector_type(2)));
typedef float f32x4 __attribute__((ext_vector_type(4)));
typedef short s16x4 __attribute__((ext_vector_type(4)));

// ---------------- constants ----------------
constexpr int Bsz = 8, HIMG = 24, WIMG = 24;
constexpr int Lq = 576;
constexpr int WIDTH = 1024, NCH = 8, CW = 128;
constexpr int NHEADS = 8, HD = 16, HALF = 8;
constexpr float EPS = 1e-6f;
constexpr float LAMINIT = 0.2f;
// 1/sqrt(8) * log2(e): scores exit MFMA in log2 domain -> v_exp_f32 directly
constexpr float QSCALE_E = 0.35355339059327373f * 1.4426950408889634f;
constexpr int ROWS = Bsz * Lq;              // 4608
constexpr long PSTRIDE = 4718592;           // bf16 elements per MLP partial buffer

__device__ __forceinline__ float fexp2(float x) {
#if __has_builtin(__builtin_amdgcn_exp2f)
  return __builtin_amdgcn_exp2f(x);
#else
  return exp2f(x);
#endif
}

// ---------------- workspace byte offsets ----------------
constexpr size_t B_HB    = 0;                        // bf16 h [4608][1024]
constexpr size_t B_G2B   = B_HB    + 9437184;        // bf16 g2/partial0; POS f32 early
constexpr size_t B_ENCB  = B_G2B   + 9437184;        // bf16 enc [640][128]
constexpr size_t B_POSWT = B_ENCB  + 163840;         // bf16 [1024][128]
constexpr size_t B_QKVWT = B_POSWT + 262144;         // bf16 [8][384][128]
constexpr size_t B_OWT   = B_QKVWT + 786432;         // bf16 [8][128][128]
constexpr size_t B_SE    = B_OWT   + 262144;         // f32 [8][1024]
constexpr size_t B_T1    = B_SE    + 32768;          // f32 [8][256]
constexpr size_t B_MP    = B_T1    + 8192;           // f32 [8][16][1024]
constexpr size_t B_RW    = B_MP    + 524288;         // f32 [64]
constexpr size_t B_LAM   = B_RW    + 256;            // f32 [8]
constexpr size_t B_POOL  = B_LAM   + 256;            // = 20914688; phase-shared pool
// pool (MLP small): W1T 8388608 | W2T 8388608 | HID 18874368            (58.7 MB)
// pool (MLP big):   W1T 8388608 | W2T 8388608 | HID 37748736            (75.4 MB)
// pool (MLP big2):  ... + PART1 bf16 9437184 after HID                  (84.9 MB)
// pool (MLP big3):  ... + PARTS bf16 4x9437184 after HID                (113.2 MB)
// pool (chan):      QKV 28311552 | DC 9437184 (out-proj IN-PLACE on DC) (58.7 MB)
constexpr size_t WS_BIG  = B_POOL + 8388608 + 8388608 + 37748736;     // 75440640
constexpr size_t WS_BIG2 = WS_BIG + 9437184;                          // 84877824
constexpr size_t WS_BIG3 = WS_BIG + 4 * 9437184;                      // 113189376

// ---------------- helpers ----------------
__device__ __forceinline__ float blockReduceSum256(float v, float* red) {
  #pragma unroll
  for (int off = 32; off; off >>= 1) v += __shfl_down(v, off, 64);
  int lane = threadIdx.x & 63, wid = threadIdx.x >> 6;
  if (lane == 0) red[wid] = v;
  __syncthreads();
  float total = 0.f;
  #pragma unroll
  for (int i = 0; i < 4; i++) total += red[i];
  return total;
}
__device__ __forceinline__ float silu(float x) { return x / (1.f + __expf(-x)); }

__device__ __forceinline__ void gl16(const bf16* g, bf16* l) {
  __builtin_amdgcn_global_load_lds(
      (const __attribute__((address_space(1))) void*)g,
      (__attribute__((address_space(3))) void*)l, 16, 0, 0);
}

// v_mfma_f32_16x16x16_bf16 wrapper (A,B = 4 bf16/lane; k = quad*4+j)
__device__ __forceinline__ f32x4 mfma16(bf16x4 a, bf16x4 b, f32x4 c) {
#if __has_builtin(__builtin_amdgcn_mfma_f32_16x16x16bf16_1k)
  union { bf16x4 h; s16x4 s; } ua, ub;
  ua.h = a; ub.h = b;
  return __builtin_amdgcn_mfma_f32_16x16x16bf16_1k(ua.s, ub.s, c, 0, 0, 0);
#else
  f32x4 d = c;
  asm volatile("v_mfma_f32_16x16x16_bf16 %0, %1, %2, %0"
               : "+v"(d) : "v"(a), "v"(b));
  return d;
#endif
}

// ---------------- batched cast+transpose of ALL weights, one dispatch -------------
__device__ __forceinline__ void tcast_tile(const float* __restrict__ W,
    bf16* __restrict__ Wt, int K, int N, long zo, int bx, int by) {
  __shared__ float t[32][33];
  int n0 = bx * 32, k0 = by * 32;
  int tid = threadIdx.x;
  int r = tid >> 3, c4 = (tid & 7) * 4;
  const float4 v = *(const float4*)(W + zo + (long)(k0 + r) * N + n0 + c4);
  t[c4 + 0][r] = v.x; t[c4 + 1][r] = v.y; t[c4 + 2][r] = v.z; t[c4 + 3][r] = v.w;
  __syncthreads();
  bf16* dst = Wt + zo + (long)(n0 + r) * K + k0 + c4;
  bf16x4 o4;
  o4[0] = (bf16)t[r][c4 + 0]; o4[1] = (bf16)t[r][c4 + 1];
  o4[2] = (bf16)t[r][c4 + 2]; o4[3] = (bf16)t[r][c4 + 3];
  *(bf16x4*)dst = o4;
}

__global__ __launch_bounds__(256) void k_tcast_all(
    const float* __restrict__ w1, const float* __restrict__ w2,
    const float* __restrict__ posw, const float* __restrict__ qkvw,
    const float* __restrict__ outw,
    bf16* __restrict__ W1T, bf16* __restrict__ W2T, bf16* __restrict__ POSWT,
    bf16* __restrict__ QKVWT, bf16* __restrict__ OWT) {
  int bid = blockIdx.x;
  if (bid < 4096) {
    tcast_tile(w1, W1T, 1024, 4096, 0, bid % 128, bid / 128);
  } else if (bid < 8192) {
    int t = bid - 4096;
    tcast_tile(w2, W2T, 4096, 1024, 0, t % 32, t / 32);
  } else if (bid < 8320) {
    int t = bid - 8192;
    tcast_tile(posw, POSWT, 128, 1024, 0, t % 32, t / 32);
  } else if (bid < 8704) {
    int t = bid - 8320;
    int z = t / 48; t -= z * 48;
    tcast_tile(qkvw, QKVWT, 128, 384, (long)z * 49152, t % 12, t / 12);
  } else {
    int t = bid - 8704;
    int z = t / 16; t -= z * 16;
    tcast_tile(outw, OWT, 128, 128, (long)z * 16384, t % 4, t / 4);
  }
}

// ---------------- positional encoding (bf16 out) ----------------
__global__ void k_enc_b(const float* __restrict__ fh, const float* __restrict__ fw,
                        const float* __restrict__ ph, const float* __restrict__ pw,
                        bf16* __restrict__ enc) {
  int idx = blockIdx.x * blockDim.x + threadIdx.x;
  if (idx >= Lq * 128) return;
  int l = idx >> 7, c = idx & 127;
  int hh = l / WIMG, ww = l % WIMG;
  float v;
  if (c < 64) {
    int f = c & 31;
    float fr = log1pf(__expf(fh[f])) * 10.f;
    float a = (hh / (float)HIMG) * fr + ph[f];
    v = (c < 32) ? sinf(a) : cosf(a);
  } else {
    int f = c & 31;
    float fr = log1pf(__expf(fw[f])) * 10.f;
    float a = (ww / (float)WIMG) * fr + pw[f];
    v = (c < 96) ? sinf(a) : cosf(a);
  }
  enc[idx] = (bf16)v;
}

// ---------------- bf16 MFMA GEMM 128x128 ----------------
// SWZ=0: 3D grid (x=n, y=m, z).  SWZ=1 (gemm1): 1D grid 1152; XCD-pinned groups
// (m, n-half): all 16 n-tiles of a group share lid%8 -> same XCD L2 serves A-panel.
// SWZ=2 (gemm2 K-split): 1D grid 8*G; group G=(m,z) owns its 8 n-tiles on one XCD.
template <int ACT, int OUTBF, int SWZ>
__global__ __launch_bounds__(256) void gemm_bt(
    const bf16* __restrict__ A, int lda, long aZs,
    const bf16* __restrict__ Bt, int ldb, long bZs,
    const float* __restrict__ bias, int biasZs,
    void* __restrict__ Cv, int ldc, long cZs,
    int M, int N, int K) {
  __shared__ bf16 As[128 * 32];
  __shared__ bf16 Bs[128 * 32];
  int tid = threadIdx.x;
  int m0, n0, z;
  if constexpr (SWZ == 0) {
    m0 = blockIdx.y * 128; n0 = blockIdx.x * 128; z = blockIdx.z;
  } else if constexpr (SWZ == 1) {
    int lid = blockIdx.x;
    int xcd = lid & 7, idx = lid >> 3;
    int j = idx & 15, G = xcd + 8 * (idx >> 4);   // G in [0,72)
    m0 = (G % 36) * 128; n0 = ((G / 36) * 16 + j) * 128; z = 0;
  } else {
    int lid = blockIdx.x;
    int xcd = lid & 7, idx = lid >> 3;
    int n = idx & 7, G = xcd + 8 * (idx >> 3);    // G in [0, grid/8)
    m0 = (G % 36) * 128; n0 = n * 128; z = G / 36;
  }
  const bf16* Ab = A + (long)z * aZs;
  const bf16* Bb = Bt + (long)z * bZs;
  f32x4 acc[4][4] = {};
  int wv = tid >> 6, lane = tid & 63;
  int wrow = (wv >> 1) * 64, wcol = (wv & 1) * 64;
  int lm = lane & 15, lq = lane >> 4;
  const bf16* ag = Ab + (long)(m0 + (tid >> 2)) * lda + (tid & 3) * 8;
  const bf16* bg = Bb + (long)(n0 + (tid >> 2)) * ldb + (tid & 3) * 8;
  bf16* asd = As + tid * 8;
  bf16* bsd = Bs + tid * 8;
  for (int k0 = 0; k0 < K; k0 += 32) {
    gl16(ag + k0, asd);
    gl16(ag + k0 + 64L * lda, asd + 2048);
    gl16(bg + k0, bsd);
    gl16(bg + k0 + 64L * ldb, bsd + 2048);
    __syncthreads();
    bf16x8 af[4], bfr[4];
    #pragma unroll
    for (int i = 0; i < 4; i++) {
      af[i]  = *(const bf16x8*)(As + (wrow + i * 16 + lm) * 32 + lq * 8);
      bfr[i] = *(const bf16x8*)(Bs + (wcol + i * 16 + lm) * 32 + lq * 8);
    }
    #pragma unroll
    for (int i = 0; i < 4; i++)
      #pragma unroll
      for (int j = 0; j < 4; j++)
        acc[i][j] = __builtin_amdgcn_mfma_f32_16x16x32_bf16(af[i], bfr[j], acc[i][j], 0, 0, 0);
    __syncthreads();
  }
  long cz = (long)z * cZs;
  const float* bz = bias ? bias + (long)z * biasZs : nullptr;
  #pragma unroll
  for (int i = 0; i < 4; i++) {
    int row = m0 + wrow + i * 16 + lq * 4;
    #pragma unroll
    for (int j = 0; j < 4; j++) {
      int col = n0 + wcol + j * 16 + lm;
      float bv = bz ? bz[col] : 0.f;
      #pragma unroll
      for (int r = 0; r < 4; r++) {
        float v = acc[i][j][r] + bv;
        if (ACT == 1) v = silu(v);
        long off = cz + (long)(row + r) * ldc + col;
        if (OUTBF) ((bf16*)Cv)[off] = (bf16)v;
        else       ((float*)Cv)[off] = v;
      }
    }
  }
}

// ---------------- 256x256 8-wave free-run MFMA GEMM ----------------
// 256^2 tile, BK=64, 512 threads = 8 waves (2M x 4N), per-wave output 128x64
// (acc[8][4] f32x4), LDS 128 KiB = 2 buffers x (A 256x64 + B 256x64) bf16.
// Schedule: ONE __syncthreads per K-tile (its vmcnt(0)+barrier both drains the
// stage issued a full iteration earlier -- ~2500-cycle issue-to-wait distance,
// so the drain is free -- and hands over the double buffers). NO inner
// barriers: waves slip freely, so one wave's ds_reads overlap another's MFMAs
// (the measured MFMA/VALU-pipe co-scheduling mechanism). Body ordered as 4
// quadrant clusters with setprio(1) around each MFMA group; B(nq0) fragments
// kept live across the iter (24 ds_read_b128/wave/iter).
// LDS swizzle: slot ^= (row&7) within each 128B row (ds_read_b128 lanes spread
// evenly over all 8 16B slot-columns -> all 32 banks, conflict-free). Applied
// on the *global source* of global_load_lds (LDS dest stays linear, required
// by gl16) and identically on the ds_read address (row===lm mod 8 for all
// fragment reads).
template <int ACT>
__global__ __launch_bounds__(512) void gemm256(
    const bf16* __restrict__ A, int lda, long aZs,
    const bf16* __restrict__ Bt, int ldb, long bZs,
    const float* __restrict__ bias,
    bf16* __restrict__ C, int ldc, long cZs,
    int Mtiles, int Ntiles, int K) {
  __shared__ bf16 LDS[65536];   // [buf:2][mat:2][half:2][128][64] bf16 = 128 KiB
  const int tid = threadIdx.x;
  // XCD-aware bijective swizzle (gridDim.x % 8 == 0 in all launches here)
  const int cpx = gridDim.x >> 3;
  const int wg = (blockIdx.x & 7) * cpx + (blockIdx.x >> 3);
  const int per_z = Mtiles * Ntiles;
  const int z = wg / per_z, rwg = wg % per_z;
  const int m0 = (rwg / Ntiles) * 256, n0 = (rwg % Ntiles) * 256;
  const bf16* Ab = A + (long)z * aZs;
  const bf16* Bb = Bt + (long)z * bZs;
  // --- staging geometry: 2 x 16B chunks/thread per 128x64 half-tile ---
  const int c0 = tid, c1 = tid + 512;
  const int sr0 = c0 >> 3, sc0 = ((c0 & 7) ^ (sr0 & 7)) * 8;  // pre-swizzled src col
  const int sr1 = c1 >> 3, sc1 = ((c1 & 7) ^ (sr1 & 7)) * 8;
  const long a00 = (long)(m0 + sr0) * lda + sc0;
  const long a01 = (long)(m0 + sr1) * lda + sc1;
  const long a10 = (long)(m0 + 128 + sr0) * lda + sc0;
  const long a11 = (long)(m0 + 128 + sr1) * lda + sc1;
  const long b00 = (long)(n0 + sr0) * ldb + sc0;
  const long b01 = (long)(n0 + sr1) * ldb + sc1;
  const long b10 = (long)(n0 + 128 + sr0) * ldb + sc0;
  const long b11 = (long)(n0 + 128 + sr1) * ldb + sc1;
  const int d0 = c0 * 8, d1 = c1 * 8;                 // linear LDS dest (elems)
  auto stage = [&](int kt, int buf) {
    const bf16* Ak = Ab + kt * 64;
    const bf16* Bk = Bb + kt * 64;
    bf16* L = LDS + buf * 32768;
    gl16(Ak + a00, L + d0);         gl16(Ak + a01, L + d1);
    gl16(Ak + a10, L + 8192 + d0);  gl16(Ak + a11, L + 8192 + d1);
    gl16(Bk + b00, L + 16384 + d0); gl16(Bk + b01, L + 16384 + d1);
    gl16(Bk + b10, L + 24576 + d0); gl16(Bk + b11, L + 24576 + d1);
  };
  // --- wave geometry: 8 waves = 2M x 4N; per-wave output 128 x 64 ---
  const int wv = tid >> 6, lane = tid & 63;
  const int wm = wv >> 2, wn = wv & 3;
  const int lm = lane & 15, lq = lane >> 4;
  const int sw = lm & 7;                              // row&7 read-side XOR
  const int abase = wm * 8192;                        // wave's A half
  const int bbase = 16384 + (wn >> 1) * 8192;         // wave's B half
  const int brow0 = (wn & 1) * 64;                    // wave's rows within B half
  const int kq0 = (lq ^ sw) * 8;                      // swizzled slot, ks=0
  const int kq1 = ((4 + lq) ^ sw) * 8;                // swizzled slot, ks=1
  f32x4 acc[8][4] = {};
  const int NT = K >> 6;
  stage(0, 0);
  for (int s = 0; s < NT; ++s) {
    __syncthreads();   // vmcnt(0)+barrier: stage(s) landed; buffers handed over
    if (s + 1 < NT) stage(s + 1, (s + 1) & 1);
    const int bb = (s & 1) * 32768;
    const bf16* La = LDS + bb + abase + lm * 64;
    const bf16* Lb = LDS + bb + bbase + (brow0 + lm) * 64;
    bf16x8 a0[4][2], a1[4][2], b0[2][2], b1[2][2];
    #pragma unroll
    for (int f = 0; f < 4; f++) {
      a0[f][0] = *(const bf16x8*)(La + f * 1024 + kq0);
      a0[f][1] = *(const bf16x8*)(La + f * 1024 + kq1);
    }
    #pragma unroll
    for (int g = 0; g < 2; g++) {
      b0[g][0] = *(const bf16x8*)(Lb + g * 1024 + kq0);
      b0[g][1] = *(const bf16x8*)(Lb + g * 1024 + kq1);
    }
    // ---- Q00: acc[f][g] += A0 . B0 ----
    __builtin_amdgcn_s_setprio(1);
    #pragma unroll
    for (int f = 0; f < 4; f++)
      #pragma unroll
      for (int g = 0; g < 2; g++) {
        acc[f][g] = __builtin_amdgcn_mfma_f32_16x16x32_bf16(a0[f][0], b0[g][0], acc[f][g], 0, 0, 0);
        acc[f][g] = __builtin_amdgcn_mfma_f32_16x16x32_bf16(a0[f][1], b0[g][1], acc[f][g], 0, 0, 0);
      }
    __builtin_amdgcn_s_setprio(0);
    #pragma unroll
    for (int g = 0; g < 2; g++) {
      b1[g][0] = *(const bf16x8*)(Lb + 2048 + g * 1024 + kq0);
      b1[g][1] = *(const bf16x8*)(Lb + 2048 + g * 1024 + kq1);
    }
    // ---- Q01: acc[f][2+g] += A0 . B1 ----
    __builtin_amdgcn_s_setprio(1);
    #pragma unroll
    for (int f = 0; f < 4; f++)
      #pragma unroll
      for (int g = 0; g < 2; g++) {
        acc[f][2 + g] = __builtin_amdgcn_mfma_f32_16x16x32_bf16(a0[f][0], b1[g][0], acc[f][2 + g], 0, 0, 0);
        acc[f][2 + g] = __builtin_amdgcn_mfma_f32_16x16x32_bf16(a0[f][1], b1[g][1], acc[f][2 + g], 0, 0, 0);
      }
    __builtin_amdgcn_s_setprio(0);
    #pragma unroll
    for (int f = 0; f < 4; f++) {
      a1[f][0] = *(const bf16x8*)(La + 4096 + f * 1024 + kq0);
      a1[f][1] = *(const bf16x8*)(La + 4096 + f * 1024 + kq1);
    }
    // ---- Q11: acc[4+f][2+g] += A1 . B1 ----
    __builtin_amdgcn_s_setprio(1);
    #pragma unroll
    for (int f = 0; f < 4; f++)
      #pragma unroll
      for (int g = 0; g < 2; g++) {
        acc[4 + f][2 + g] = __builtin_amdgcn_mfma_f32_16x16x32_bf16(a1[f][0], b1[g][0], acc[4 + f][2 + g], 0, 0, 0);
        acc[4 + f][2 + g] = __builtin_amdgcn_mfma_f32_16x16x32_bf16(a1[f][1], b1[g][1], acc[4 + f][2 + g], 0, 0, 0);
      }
    __builtin_amdgcn_s_setprio(0);
    // ---- Q10: acc[4+f][g] += A1 . B0 (b0 kept live from phase 0) ----
    __builtin_amdgcn_s_setprio(1);
    #pragma unroll
    for (int f = 0; f < 4; f++)
      #pragma unroll
      for (int g = 0; g < 2; g++) {
        acc[4 + f][g] = __builtin_amdgcn_mfma_f32_16x16x32_bf16(a1[f][0], b0[g][0], acc[4 + f][g], 0, 0, 0);
        acc[4 + f][g] = __builtin_amdgcn_mfma_f32_16x16x32_bf16(a1[f][1], b0[g][1], acc[4 + f][g], 0, 0, 0);
      }
    __builtin_amdgcn_s_setprio(0);
  }
  // ---- epilogue ----
  const long cz = (long)z * cZs;
  #pragma unroll
  for (int i = 0; i < 8; i++) {
    const int row = m0 + wm * 128 + (i >> 2) * 64 + (i & 3) * 16 + lq * 4;
    #pragma unroll
    for (int j = 0; j < 4; j++) {
      const int col = n0 + wn * 64 + (j >> 1) * 32 + (j & 1) * 16 + lm;
      const float bv = bias ? bias[col] : 0.f;
      #pragma unroll
      for (int rr = 0; rr < 4; rr++) {
        float v = acc[i][j][rr] + bv;
        if (ACT == 1) v = silu(v);
        C[cz + (long)(row + rr) * ldc + col] = (bf16)v;
      }
    }
  }
}

// ---------------- bf16 MFMA GEMM 64x128 tile ----------------
// NORM=1 (qkv mode): after silu, 8-col-group rmsnorm for Q (x==0, qn, prescale) and
// K (x==1, kn); V (x==2) passthrough.
template <int ACT, int OUTBF, int ACC, int NORM>
__global__ __launch_bounds__(256) void gemm64(
    const bf16* __restrict__ A, int lda, long aZs,
    const bf16* __restrict__ Bt, int ldb, long bZs,
    const float* __restrict__ bias, int biasZs,
    void* __restrict__ Cv, int ldc, long cZs,
    int M, int N, int K,
    const float* __restrict__ qn, const float* __restrict__ kn) {
  __shared__ bf16 As[64 * 32];
  __shared__ bf16 Bs[128 * 32];
  int tid = threadIdx.x;
  int m0 = blockIdx.y * 64, n0 = blockIdx.x * 128;
  int z = blockIdx.z;
  const bf16* Ab = A + (long)z * aZs;
  const bf16* Bb = Bt + (long)z * bZs;
  f32x4 acc[4][2] = {};
  int wv = tid >> 6, lane = tid & 63;
  int lm = lane & 15, lq = lane >> 4;
  int wcol = wv * 32;
  const bf16* ag = Ab + (long)(m0 + (tid >> 2)) * lda + (tid & 3) * 8;
  const bf16* bg = Bb + (long)(n0 + (tid >> 2)) * ldb + (tid & 3) * 8;
  bf16* asd = As + tid * 8;
  bf16* bsd = Bs + tid * 8;
  for (int k0 = 0; k0 < K; k0 += 32) {
    gl16(ag + k0, asd);
    gl16(bg + k0, bsd);
    gl16(bg + k0 + 64L * ldb, bsd + 2048);
    __syncthreads();
    bf16x8 af[4], bfr[2];
    #pragma unroll
    for (int i = 0; i < 4; i++)
      af[i] = *(const bf16x8*)(As + (i * 16 + lm) * 32 + lq * 8);
    #pragma unroll
    for (int j = 0; j < 2; j++)
      bfr[j] = *(const bf16x8*)(Bs + (wcol + j * 16 + lm) * 32 + lq * 8);
    #pragma unroll
    for (int i = 0; i < 4; i++)
      #pragma unroll
      for (int j = 0; j < 2; j++)
        acc[i][j] = __builtin_amdgcn_mfma_f32_16x16x32_bf16(af[i], bfr[j], acc[i][j], 0, 0, 0);
    __syncthreads();
  }
  long cz = (long)z * cZs;
  const float* bz = bias ? bias + (long)z * biasZs : nullptr;
  if constexpr (NORM == 0) {
    #pragma unroll
    for (int i = 0; i < 4; i++) {
      int row = m0 + i * 16 + lq * 4;
      #pragma unroll
      for (int j = 0; j < 2; j++) {
        int col = n0 + wcol + j * 16 + lm;
        float bv = bz ? bz[col] : 0.f;
        #pragma unroll
        for (int r = 0; r < 4; r++) {
          float v = acc[i][j][r] + bv;
          long off = cz + (long)(row + r) * ldc + col;
          if (ACC) v += (float)((bf16*)Cv)[off];
          if (ACT == 1) v = silu(v);
          if (OUTBF) ((bf16*)Cv)[off] = (bf16)v;
          else       ((float*)Cv)[off] = v;
        }
      }
    }
  } else {
    int nsec = blockIdx.x;              // 0=Q, 1=K, 2=V
    bool don = nsec < 2;
    float wnv = 1.f;
    if (nsec == 0) wnv = qn[z * 8 + (lm & 7)] * QSCALE_E;
    else if (nsec == 1) wnv = kn[z * 8 + (lm & 7)];
    #pragma unroll
    for (int i = 0; i < 4; i++) {
      int row = m0 + i * 16 + lq * 4;
      #pragma unroll
      for (int j = 0; j < 2; j++) {
        int col = n0 + wcol + j * 16 + lm;
        float bv = bz ? bz[col] : 0.f;
        #pragma unroll
        for (int r = 0; r < 4; r++) {
          float v = acc[i][j][r] + bv;
          if (ACT == 1) v = silu(v);
          float s = v * v;
          s += __shfl_xor(s, 1);
          s += __shfl_xor(s, 2);
          s += __shfl_xor(s, 4);
          if (don) v = v * rsqrtf(s * 0.125f + EPS) * wnv;
          ((bf16*)Cv)[cz + (long)(row + r) * ldc + col] = (bf16)v;
        }
      }
    }
  }
}

// ---------------- embed + rmsnorm -> bf16 h ----------------
__global__ __launch_bounds__(256) void k_embed(const float* __restrict__ x,
    const float* __restrict__ emb, const float* __restrict__ pos,
    const float* __restrict__ nw, bf16* __restrict__ h) {
  __shared__ float red[4];
  int row = blockIdx.x;
  int l = row % Lq;
  int xi = (int)(x[row] * 255.f);
  xi = min(max(xi, 0), 255);
  const float* er = emb + (long)xi * WIDTH;
  const float* pr = pos + (long)l * WIDTH;
  int c0 = threadIdx.x * 4;
  float v[4]; float ss = 0.f;
  #pragma unroll
  for (int i = 0; i < 4; i++) { v[i] = er[c0 + i] + pr[c0 + i]; ss += v[i] * v[i]; }
  ss = blockReduceSum256(ss, red);
  float r = rsqrtf(ss / WIDTH + EPS);
  bf16* hr = h + (long)row * WIDTH;
  #pragma unroll
  for (int i = 0; i < 4; i++) hr[c0 + i] = (bf16)(v[i] * r * nw[c0 + i]);
}

// ---------------- mean over L, phase 1: 16 partials per b ----------------
__global__ void k_meanl_p(const bf16* __restrict__ h, float* __restrict__ part) {
  int lp = blockIdx.x, b = blockIdx.y, t = threadIdx.x;
  const bf16* p = h + ((long)b * Lq + (long)lp * 36) * WIDTH + t * 4;
  float a0 = 0, a1 = 0, a2 = 0, a3 = 0;
  for (int l = 0; l < 36; l++) {
    bf16x4 v = *(const bf16x4*)(p + (long)l * WIDTH);
    a0 += (float)v[0]; a1 += (float)v[1]; a2 += (float)v[2]; a3 += (float)v[3];
  }
  float* dst = part + ((long)b * 16 + lp) * WIDTH + t * 4;
  dst[0] = a0; dst[1] = a1; dst[2] = a2; dst[3] = a3;
}

// ---------------- SE phase 1 ----------------
__global__ __launch_bounds__(256) void k_se1(const float* __restrict__ part,
    const float* __restrict__ w1, const float* __restrict__ b1,
    float* __restrict__ t1) {
  __shared__ float sv[1024];
  __shared__ float red[256];
  int jb = blockIdx.x, b = blockIdx.y, t = threadIdx.x;
  for (int c = t; c < 1024; c += 256) {
    float a = 0.f;
    #pragma unroll
    for (int lp = 0; lp < 16; lp++) a += part[((long)b * 16 + lp) * 1024 + c];
    sv[c] = a * (1.f / 576.f);
  }
  __syncthreads();
  int j = t & 7, pt = t >> 3;
  int j0 = jb * 8;
  float acc = 0.f;
  int c0 = pt * 32;
  #pragma unroll 8
  for (int c = c0; c < c0 + 32; c++) acc += sv[c] * w1[c * 256 + j0 + j];
  red[t] = acc;
  __syncthreads();
  if (t < 8) {
    float a = b1[j0 + t];
    #pragma unroll
    for (int p = 0; p < 32; p++) a += red[p * 8 + t];
    t1[b * 256 + j0 + t] = silu(a);
  }
}

// ---------------- SE phase 2 ----------------
__global__ __launch_bounds__(256) void k_se2(const float* __restrict__ t1,
    const float* __restrict__ w2, const float* __restrict__ b2,
    float* __restrict__ s) {
  __shared__ float red[256];
  int jb = blockIdx.x, b = blockIdx.y, t = threadIdx.x;
  int j = t & 31, pt = t >> 5;
  int j0 = jb * 32;
  const float* tb = t1 + b * 256;
  float acc = 0.f;
  int c0 = pt * 32;
  #pragma unroll 8
  for (int c = c0; c < c0 + 32; c++) acc += tb[c] * w2[c * 1024 + j0 + j];
  red[t] = acc;
  __syncthreads();
  if (t < 32) {
    float a = b2[j0 + t];
    #pragma unroll
    for (int p = 0; p < 8; p++) a += red[p * 32 + t];
    s[b * 1024 + j0 + t] = 1.f / (1.f + __expf(-a));
  }
}

// ---------------- mix: h += rmsnorm(h*(s-1), mw) ----------------
__global__ __launch_bounds__(256) void k_mix_b(bf16* __restrict__ h,
    const float* __restrict__ s, const float* __restrict__ mw) {
  __shared__ float red[4];
  int row = blockIdx.x;
  int b = row / Lq;
  bf16* hr = h + (long)row * WIDTH;
  const float* sb = s + b * WIDTH;
  int c0 = threadIdx.x * 4;
  float hv[4], y[4]; float ss = 0.f;
  #pragma unroll
  for (int i = 0; i < 4; i++) {
    hv[i] = (float)hr[c0 + i];
    y[i] = hv[i] * (sb[c0 + i] - 1.f); ss += y[i] * y[i];
  }
  ss = blockReduceSum256(ss, red);
  float r = rsqrtf(ss / WIDTH + EPS);
  #pragma unroll
  for (int i = 0; i < 4; i++) hr[c0 + i] = (bf16)(hv[i] + y[i] * r * mw[c0 + i]);
}

// ---------------- h += rmsnorm(g, mw) ----------------
__global__ __launch_bounds__(256) void k_addnorm_b(bf16* __restrict__ h,
    const bf16* __restrict__ g, const float* __restrict__ mw) {
  __shared__ float red[4];
  int row = blockIdx.x;
  bf16* hr = h + (long)row * WIDTH;
  const bf16* gr = g + (long)row * WIDTH;
  int c0 = threadIdx.x * 4;
  float y[4]; float ss = 0.f;
  #pragma unroll
  for (int i = 0; i < 4; i++) { y[i] = (float)gr[c0 + i]; ss += y[i] * y[i]; }
  ss = blockReduceSum256(ss, red);
  float r = rsqrtf(ss / WIDTH + EPS);
  #pragma unroll
  for (int i = 0; i < 4; i++)
    hr[c0 + i] = (bf16)((float)hr[c0 + i] + y[i] * r * mw[c0 + i]);
}

// ---------------- h += rmsnorm(p0 + p1 + b2, mw)  (2-way K-split partials) --------
__global__ __launch_bounds__(256) void k_addnorm2(bf16* __restrict__ h,
    const bf16* __restrict__ p0, const bf16* __restrict__ p1,
    const float* __restrict__ b2, const float* __restrict__ mw) {
  __shared__ float red[4];
  int row = blockIdx.x;
  bf16* hr = h + (long)row * WIDTH;
  const bf16* g0 = p0 + (long)row * WIDTH;
  const bf16* g1 = p1 + (long)row * WIDTH;
  int c0 = threadIdx.x * 4;
  float y[4]; float ss = 0.f;
  #pragma unroll
  for (int i = 0; i < 4; i++) {
    y[i] = (float)g0[c0 + i] + (float)g1[c0 + i] + b2[c0 + i];
    ss += y[i] * y[i];
  }
  ss = blockReduceSum256(ss, red);
  float r = rsqrtf(ss / WIDTH + EPS);
  #pragma unroll
  for (int i = 0; i < 4; i++)
    hr[c0 + i] = (bf16)((float)hr[c0 + i] + y[i] * r * mw[c0 + i]);
}

// ---------------- h += rmsnorm(p0+p1+p2+p3 + b2, mw)  (4-way K-split) -------------
__global__ __launch_bounds__(256) void k_addnorm4(bf16* __restrict__ h,
    const bf16* __restrict__ parts, const float* __restrict__ b2,
    const float* __restrict__ mw) {
  __shared__ float red[4];
  int row = blockIdx.x;
  bf16* hr = h + (long)row * WIDTH;
  const bf16* g0 = parts + (long)row * WIDTH;
  int c0 = threadIdx.x * 4;
  float y[4]; float ss = 0.f;
  #pragma unroll
  for (int i = 0; i < 4; i++) {
    float a = b2[c0 + i];
    #pragma unroll
    for (int p = 0; p < 4; p++) a += (float)g0[(long)p * PSTRIDE + c0 + i];
    y[i] = a; ss += a * a;
  }
  ss = blockReduceSum256(ss, red);
  float r = rsqrtf(ss / WIDTH + EPS);
  #pragma unroll
  for (int i = 0; i < 4; i++)
    hr[c0 + i] = (bf16)((float)hr[c0 + i] + y[i] * r * mw[c0 + i]);
}

// ---------------- router + lambdas ----------------
__global__ __launch_bounds__(256) void k_router(const float* __restrict__ part,
    const float* __restrict__ rwgt, const float* __restrict__ rb,
    const float* __restrict__ lq1, const float* __restrict__ lk1,
    const float* __restrict__ lq2, const float* __restrict__ lk2,
    float* __restrict__ rw, float* __restrict__ lam) {
  __shared__ float sv[1024];
  __shared__ float red[256];
  __shared__ float lg[8];
  int b = blockIdx.x, t = threadIdx.x;
  for (int c = t; c < 1024; c += 256) {
    float a = 0.f;
    #pragma unroll
    for (int lp = 0; lp < 16; lp++) a += part[((long)b * 16 + lp) * 1024 + c];
    sv[c] = a * (1.f / 576.f);
  }
  __syncthreads();
  int j = t & 7, pt = t >> 3;
  float acc = 0.f;
  int c0 = pt * 32;
  #pragma unroll 8
  for (int c = c0; c < c0 + 32; c++) acc += sv[c] * rwgt[c * 8 + j];
  red[t] = acc;
  __syncthreads();
  if (t < 8) {
    float a = rb[t];
    for (int p = 0; p < 32; p++) a += red[p * 8 + t];
    lg[t] = a;
  }
  __syncthreads();
  if (t == 0) {
    float v[8]; bool sel[8];
    #pragma unroll
    for (int i = 0; i < 8; i++) { v[i] = lg[i]; sel[i] = false; }
    int idxs[4]; float vals[4];
    for (int s = 0; s < 4; s++) {
      int bi = -1; float bv = -1e30f;
      for (int i = 0; i < 8; i++) if (!sel[i] && v[i] > bv) { bv = v[i]; bi = i; }
      sel[bi] = true; idxs[s] = bi; vals[s] = bv;
    }
    float m = vals[0], den = 0.f, e[4];
    for (int s = 0; s < 4; s++) { e[s] = __expf(vals[s] - m); den += e[s]; }
    for (int i = 0; i < 8; i++) rw[b * 8 + i] = 0.f;
    for (int s = 0; s < 4; s++) rw[b * 8 + idxs[s]] = e[s] / den;
  }
  if (b == 0 && t >= 8 && t < 16) {
    int c = t - 8;
    float d1 = 0.f, d2 = 0.f;
    for (int i = 0; i < 8; i++) {
      d1 += lq1[c * 8 + i] * lk1[c * 8 + i];
      d2 += lq2[c * 8 + i] * lk2[c * 8 + i];
    }
    lam[c] = __expf(d1) - __expf(d2) + LAMINIT;
  }
}

// ---------------- MFMA causal differential attention (prenormed Q/K) --------------
// den on the MFMA pipe (ONES ones-vector trick). V staged ROW-MAJOR padded
// [576][20] (pad=20 elems: 4-row lq-step = 40 dwords == 8 mod 32 banks ->
// the 4x ds_read_u16 PV fragment gather covers all 32 banks 2-way = free).
// K is NOT staged: read 16B/lane direct from global (L2-resident, reused by
// all waves of the slice). LDS 23 KB -> 6 blocks/CU; grid y=3 for 6/CU
// resident. pr map: u = wv*3 + y in [0,12): u<6 single pr=17-u (cost 13-18);
// u>=6 pair {17-u, u-6} (cost 13).
__global__ __launch_bounds__(256) void k_attn_mfma(
    const bf16* __restrict__ qkv, const float* __restrict__ lam,
    const float* __restrict__ hnw, bf16* __restrict__ dc) {
  __shared__ bf16 Vs[576 * 20];
  int tid = threadIdx.x;
  int slice = blockIdx.x; int zc = slice >> 3, b = slice & 7;
  int head = blockIdx.z;
  const bf16* qkvb = qkv + ((long)zc * ROWS + (long)b * Lq) * 384;
  for (int i = tid; i < 1152; i += 256) {
    int row = i >> 1, dh = i & 1;
    bf16x8 v = *(const bf16x8*)(qkvb + (long)row * 384 + 256 + head * 16 + dh * 8);
    *(bf16x8*)(Vs + row * 20 + dh * 8) = v;
  }
  __syncthreads();
  int wv = tid >> 6, lane = tid & 63;
  int lm = lane & 15, lq = lane >> 4;
  float lamv = lam[zc];
  float hwv[4];
  #pragma unroll
  for (int r = 0; r < 4; r++) hwv[r] = hnw[zc * 16 + lq * 4 + r] * (1.f - LAMINIT);
  const bf16 one = (bf16)1.0f;
  const bf16x4 ONES = {one, one, one, one};
  const bf16* kbase = qkvb + 128 + head * 16 + lq * 8;   // K section, per-lane slot
  int u = wv * 3 + blockIdx.y;          // u in [0,12)
  int prA = 17 - u;
  int prB = (u >= 6) ? (u - 6) : -1;
  for (int pi = 0; pi < 2; pi++) {
    int pr = (pi == 0) ? prA : prB;
    if (pr < 0) continue;
    bf16x8 bq0[2] = {{}, {}}, bq1[2] = {{}, {}};
    if (lq < 2) {
      #pragma unroll
      for (int tile = 0; tile < 2; tile++) {
        bf16x8 t8 = *(const bf16x8*)(
            qkvb + (long)(pr * 32 + tile * 16 + lm) * 384 + head * 16 + lq * 8);
        if (lq == 0) bq0[tile] = t8; else bq1[tile] = t8;
      }
    }
    f32x4 o[2][2] = {};
    f32x4 dacc[2][2] = {};
    for (int kc = 0; kc <= pr; kc++) {
      f32x4 sT[2][2][2] = {};
      #pragma unroll
      for (int t = 0; t < 2; t++) {
        bf16x8 aK = {};
        if (lq < 2) aK = *(const bf16x8*)(kbase + (long)(kc * 32 + t * 16 + lm) * 384);
        #pragma unroll
        for (int tile = 0; tile < 2; tile++) {
          sT[t][tile][0] = __builtin_amdgcn_mfma_f32_16x16x32_bf16(aK, bq0[tile], sT[t][tile][0], 0, 0, 0);
          sT[t][tile][1] = __builtin_amdgcn_mfma_f32_16x16x32_bf16(aK, bq1[tile], sT[t][tile][1], 0, 0, 0);
        }
      }
      bool diag = (kc == pr);
      #pragma unroll
      for (int t = 0; t < 2; t++) {
        const bf16* vb = Vs + (kc * 32 + t * 16 + lq * 4) * 20 + lm;
        bf16x4 aV;
        aV[0] = vb[0]; aV[1] = vb[20]; aV[2] = vb[40]; aV[3] = vb[60];
        #pragma unroll
        for (int tile = 0; tile < 2; tile++) {
          if (diag && tile == 0 && t == 1) continue;
          bool masked = diag && (tile == t);
          #pragma unroll
          for (int h2 = 0; h2 < 2; h2++) {
            bf16x4 pb;
            #pragma unroll
            for (int r = 0; r < 4; r++) {
              float ev = fexp2(sT[t][tile][h2][r]);
              if (masked && (lq * 4 + r > lm)) ev = 0.f;
              pb[r] = (bf16)ev;
            }
            dacc[tile][h2] = mfma16(ONES, pb, dacc[tile][h2]);
            o[tile][h2] = mfma16(aV, pb, o[tile][h2]);
          }
        }
      }
    }
    #pragma unroll
    for (int tile = 0; tile < 2; tile++) {
      float inv1 = 1.f / dacc[tile][0][0];
      float inv2 = lamv / dacc[tile][1][0];
      float dff[4]; float ss = 0.f;
      #pragma unroll
      for (int r = 0; r < 4; r++) {
        dff[r] = o[tile][0][r] * inv1 - o[tile][1][r] * inv2;
        ss += dff[r] * dff[r];
      }
      ss += __shfl_xor(ss, 16);
      ss += __shfl_xor(ss, 32);
      float rr = rsqrtf(ss * 0.0625f + EPS);
      bf16x4 outp;
      #pragma unroll
      for (int r = 0; r < 4; r++) outp[r] = (bf16)(dff[r] * rr * hwv[r]);
      long rowg = (long)zc * ROWS + (long)b * Lq + pr * 32 + tile * 16 + lm;
      *(bf16x4*)(dc + rowg * 128 + head * 16 + lq * 4) = outp;
    }
  }
}

// ---------------- seg + pool fused: 16 bins, 1-wave blocks ----------------
__global__ __launch_bounds__(64) void k_segpool(const bf16* __restrict__ h,
    const bf16* __restrict__ op, const float* __restrict__ segw,
    const float* __restrict__ rw, float* __restrict__ part) {
  int lp = blockIdx.x, b = blockIdx.y, ch = blockIdx.z;
  int t = threadIdx.x;
  int c0 = t * 2;
  float w0 = segw[ch * 128 + c0], w1 = segw[ch * 128 + c0 + 1];
  float rwv = rw[b * 8 + ch];
  float a0 = 0.f, a1 = 0.f;
  for (int l = 0; l < 36; l++) {
    int row = b * Lq + lp * 36 + l;
    const bf16* oprow = op + (long)ch * ROWS * CW + (long)row * CW;
    bf16x2 yv = *(const bf16x2*)(oprow + c0);
    float y0 = (float)yv[0], y1 = (float)yv[1];
    float ss = y0 * y0 + y1 * y1;
    #pragma unroll
    for (int m = 1; m < 64; m <<= 1) ss += __shfl_xor(ss, m);
    float r = rsqrtf(ss * (1.f / 128.f) + EPS);
    bf16x2 hv = *(const bf16x2*)(h + (long)row * WIDTH + ch * 128 + c0);
    a0 += ((float)hv[0] + y0 * r * w0) * rwv;
    a1 += ((float)hv[1] + y1 * r * w1) * rwv;
  }
  float* dst = part + ((long)b * 16 + lp) * 1024 + ch * 128 + c0;
  dst[0] = a0; dst[1] = a1;
}

// ---------------- head (reads 16 pool partials) ----------------
__global__ __launch_bounds__(256) void k_head(const float* __restrict__ part,
    const float* __restrict__ hw, const float* __restrict__ hb, float* __restrict__ out) {
  __shared__ float pool[1024];
  __shared__ float red[256];
  int b = blockIdx.x, t = threadIdx.x;
  for (int c = t; c < 1024; c += 256) {
    float a = 0.f;
    #pragma unroll
    for (int lp = 0; lp < 16; lp++) a += part[((long)b * 16 + lp) * 1024 + c];
    pool[c] = a * (1.f / 576.f);
  }
  __syncthreads();
  int j = t & 15, pt = t >> 4;
  float acc = 0.f;
  if (j < 10)
    for (int c = pt * 64; c < pt * 64 + 64; c++)
      acc += pool[c] * hw[c * 10 + j];
  red[t] = acc;
  __syncthreads();
  if (t < 10) {
    float a = hb[t];
    for (int p = 0; p < 16; p++) a += red[p * 16 + t];
    out[b * 10 + t] = a;
  }
}

// ---------------- launcher ----------------
extern "C" void kernel_launch(void* const* d_in, const int* in_sizes, int n_in,
                              void* d_out, int out_size, void* d_ws, size_t ws_size,
                              hipStream_t stream) {
  const float* x          = (const float*)d_in[0];
  const float* pixel_embed= (const float*)d_in[2];
  const float* freq_h     = (const float*)d_in[3];
  const float* freq_w     = (const float*)d_in[4];
  const float* phase_h    = (const float*)d_in[5];
  const float* phase_w    = (const float*)d_in[6];
  const float* pos_proj_w = (const float*)d_in[7];
  const float* pos_proj_b = (const float*)d_in[8];
  const float* embed_norm = (const float*)d_in[9];
  const float* se_w1      = (const float*)d_in[10];
  const float* se_b1      = (const float*)d_in[11];
  const float* se_w2      = (const float*)d_in[12];
  const float* se_b2      = (const float*)d_in[13];
  const float* mix_norm   = (const float*)d_in[14];
  const float* mlp_w1     = (const float*)d_in[15];
  const float* mlp_b1     = (const float*)d_in[16];
  const float* mlp_w2     = (const float*)d_in[17];
  const float* mlp_b2     = (const float*)d_in[18];
  const float* mlp_norm   = (const float*)d_in[19];
  const float* router_w   = (const float*)d_in[20];
  const float* router_b   = (const float*)d_in[21];
  const float* qkv_w      = (const float*)d_in[22];
  const float* qkv_b      = (const float*)d_in[23];
  const float* q_norm_w   = (const float*)d_in[24];
  const float* k_norm_w   = (const float*)d_in[25];
  const float* head_norm_w= (const float*)d_in[26];
  const float* lam_q1     = (const float*)d_in[27];
  const float* lam_k1     = (const float*)d_in[28];
  const float* lam_q2     = (const float*)d_in[29];
  const float* lam_k2     = (const float*)d_in[30];
  const float* out_w      = (const float*)d_in[31];
  const float* out_b      = (const float*)d_in[32];
  const float* seg_norm_w = (const float*)d_in[33];
  const float* head_w     = (const float*)d_in[34];
  const float* head_b     = (const float*)d_in[35];

  char* W = (char*)d_ws;
  bf16*  HB    = (bf16*)(W + B_HB);
  bf16*  G2B   = (bf16*)(W + B_G2B);
  float* POS   = (float*)(W + B_G2B);      // POS lives in G2B region (dead until MLP)
  bf16*  ENCB  = (bf16*)(W + B_ENCB);
  bf16*  POSWT = (bf16*)(W + B_POSWT);
  bf16*  QKVWT = (bf16*)(W + B_QKVWT);
  bf16*  OWT   = (bf16*)(W + B_OWT);
  float* SE    = (float*)(W + B_SE);
  float* T1    = (float*)(W + B_T1);
  float* MP    = (float*)(W + B_MP);
  float* RW    = (float*)(W + B_RW);
  float* LAM   = (float*)(W + B_LAM);
  char*  P     = W + B_POOL;
  bf16*  W1T   = (bf16*)P;
  bf16*  W2T   = (bf16*)(P + 8388608);
  bf16*  HID   = (bf16*)(P + 16777216);
  bf16*  PARTS = (bf16*)(P + 16777216 + 37748736);   // after full-width HID
  bf16*  QKV   = (bf16*)P;
  bf16*  DC    = (bf16*)(P + 28311552);
  float* out   = (float*)d_out;
  const int tier = (ws_size >= WS_BIG3) ? 3 : (ws_size >= WS_BIG2) ? 2
                 : (ws_size >= WS_BIG) ? 1 : 0;

  // 0. all weight casts in one dispatch
  k_tcast_all<<<8832, 256, 0, stream>>>(mlp_w1, mlp_w2, pos_proj_w, qkv_w, out_w,
                                        W1T, W2T, POSWT, QKVWT, OWT);
  // 1. positional encoding + projection (POS f32 in G2B region)
  k_enc_b<<<288, 256, 0, stream>>>(freq_h, freq_w, phase_h, phase_w, ENCB);
  gemm64<0, 0, 0, 0><<<dim3(8, 10, 1), 256, 0, stream>>>(
      ENCB, 128, 0, POSWT, 128, 0, pos_proj_b, 0, POS, 1024, 0, 640, 1024, 128,
      nullptr, nullptr);
  // 2. embed + rmsnorm -> bf16 h
  k_embed<<<ROWS, 256, 0, stream>>>(x, pixel_embed, POS, embed_norm, HB);
  // 3. SE gate
  k_meanl_p<<<dim3(16, 8), 256, 0, stream>>>(HB, MP);
  k_se1<<<dim3(32, 8), 256, 0, stream>>>(MP, se_w1, se_b1, T1);
  k_se2<<<dim3(32, 8), 256, 0, stream>>>(T1, se_w2, se_b2, SE);
  k_mix_b<<<ROWS, 256, 0, stream>>>(HB, SE, mix_norm);
  // 4. MLP
  if (tier >= 1) {
    // gemm1 main: 256^2 8-wave kernel, rows 0..4095 (16m x 16n = 256 blocks,
    // exactly one block-wave over 256 CUs); 128^2 tail covers rows 4096..4607.
    gemm256<1><<<256, 512, 0, stream>>>(
        HB, 1024, 0, W1T, 1024, 0, mlp_b1,
        HID, 4096, 0, 16, 16, 1024);
    gemm_bt<1, 1, 0><<<dim3(32, 4, 1), 256, 0, stream>>>(
        HB + 4096L * 1024, 1024, 0, W1T, 1024, 0, mlp_b1, 0,
        HID + 4096L * 4096, 4096, 0, 512, 4096, 1024);
    if (tier == 3) {
      // gemm2 main: 4-way K-split, 16m x 4n x 4z = 256 blocks; tail 128^2.
      gemm256<0><<<256, 512, 0, stream>>>(
          HID, 4096, 1024, W2T, 4096, 1024, nullptr,
          PARTS, 1024, PSTRIDE, 16, 4, 1024);
      gemm_bt<0, 1, 0><<<dim3(8, 4, 4), 256, 0, stream>>>(
          HID + 4096L * 4096, 4096, 1024, W2T, 4096, 1024, nullptr, 0,
          PARTS + 4096L * 1024, 1024, PSTRIDE, 512, 1024, 1024);
      k_addnorm4<<<ROWS, 256, 0, stream>>>(HB, PARTS, mlp_b2, mlp_norm);
    } else if (tier == 2) {
      // gemm2: 2-way K-split, XCD-pinned, partials in G2B + PARTS[0]
      gemm_bt<0, 1, 2><<<576, 256, 0, stream>>>(
          HID, 4096, 2048, W2T, 4096, 2048, nullptr, 0,
          G2B, 1024, (long)(PARTS - G2B), 4608, 1024, 2048);
      k_addnorm2<<<ROWS, 256, 0, stream>>>(HB, G2B, PARTS, mlp_b2, mlp_norm);
    } else {
      gemm64<0, 1, 0, 0><<<dim3(8, 72, 1), 256, 0, stream>>>(
          HID, 4096, 0, W2T, 4096, 0, mlp_b2, 0,
          G2B, 1024, 0, 4608, 1024, 4096, nullptr, nullptr);
      k_addnorm_b<<<ROWS, 256, 0, stream>>>(HB, G2B, mlp_norm);
    }
  } else {
    gemm_bt<1, 1, 0><<<dim3(16, 36, 1), 256, 0, stream>>>(
        HB, 1024, 0, W1T, 1024, 0, mlp_b1, 0, HID, 2048, 0, 4608, 2048, 1024);
    gemm64<0, 1, 0, 0><<<dim3(8, 72, 1), 256, 0, stream>>>(
        HID, 2048, 0, W2T, 4096, 0, mlp_b2, 0, G2B, 1024, 0, 4608, 1024, 2048,
        nullptr, nullptr);
    gemm_bt<1, 1, 0><<<dim3(16, 36, 1), 256, 0, stream>>>(
        HB, 1024, 0, W1T + 2048L * 1024, 1024, 0, mlp_b1 + 2048, 0, HID, 2048, 0,
        4608, 2048, 1024);
    gemm64<0, 1, 1, 0><<<dim3(8, 72, 1), 256, 0, stream>>>(
        HID, 2048, 0, W2T + 2048, 4096, 0, nullptr, 0, G2B, 1024, 0,
        4608, 1024, 2048, nullptr, nullptr);
    k_addnorm_b<<<ROWS, 256, 0, stream>>>(HB, G2B, mlp_norm);
  }
  // 5. router + lambdas
  k_meanl_p<<<dim3(16, 8), 256, 0, stream>>>(HB, MP);
  k_router<<<8, 256, 0, stream>>>(MP, router_w, router_b,
                                  lam_q1, lam_k1, lam_q2, lam_k2, RW, LAM);
  // 6. qkv-proj with fused silu + Q/K rmsnorm (+ Q prescale) in epilogue
  gemm64<1, 1, 0, 1><<<dim3(3, 72, 8), 256, 0, stream>>>(
      HB, 1024, CW, QKVWT, 128, 384 * 128, qkv_b, 384,
      QKV, 384, (long)ROWS * 384, ROWS, 384, 128, q_norm_w, k_norm_w);
  // 7. attention (prenormed), out-proj in-place on DC
  k_attn_mfma<<<dim3(64, 3, 8), 256, 0, stream>>>(QKV, LAM, head_norm_w, DC);
  gemm64<1, 1, 0, 0><<<dim3(1, 72, 8), 256, 0, stream>>>(
      DC, 128, (long)ROWS * 128, OWT, 128, 128 * 128, out_b, 128,
      DC, 128, (long)ROWS * 128, ROWS, 128, 128, nullptr, nullptr);
  // 8. seg + pool fused -> 16 partials; head folds the final reduce
  k_segpool<<<dim3(16, 8, 8), 64, 0, stream>>>(HB, DC, seg_norm_w, RW, MP);
  k_head<<<8, 256, 0, stream>>>(MP, head_w, head_b, out);
}

// Round 5
// 439.693 us; speedup vs baseline: 1.0122x; 1.0122x over previous
//
#include <hip/hip_runtime.h>
#include <math.h>

typedef __bf16 bf16;
typedef __bf16 bf16x8 __attribute__((ext_vector_type(8)));
typedef __bf16 bf16x4 __attribute__((ext_vector_type(4)));
typedef __bf16 bf16x2 __attribute__((ext_vector_type(2)));
typedef float f32x4 __attribute__((ext_vector_type(4)));
typedef short s16x4 __attribute__((ext_vector_type(4)));

// ---------------- constants ----------------
constexpr int Bsz = 8, HIMG = 24, WIMG = 24;
constexpr int Lq = 576;
constexpr int WIDTH = 1024, NCH = 8, CW = 128;
constexpr int NHEADS = 8, HD = 16, HALF = 8;
constexpr float EPS = 1e-6f;
constexpr float LAMINIT = 0.2f;
// 1/sqrt(8) * log2(e): scores exit MFMA in log2 domain -> v_exp_f32 directly
constexpr float QSCALE_E = 0.35355339059327373f * 1.4426950408889634f;
constexpr int ROWS = Bsz * Lq;              // 4608
constexpr long PSTRIDE = 4718592;           // bf16 elements per MLP partial buffer

__device__ __forceinline__ float fexp2(float x) {
#if __has_builtin(__builtin_amdgcn_exp2f)
  return __builtin_amdgcn_exp2f(x);
#else
  return exp2f(x);
#endif
}

// ---------------- workspace byte offsets ----------------
constexpr size_t B_HB    = 0;                        // bf16 h [4608][1024]
constexpr size_t B_G2B   = B_HB    + 9437184;        // bf16 g2/partial0; POS f32 early
constexpr size_t B_ENCB  = B_G2B   + 9437184;        // bf16 enc [640][128]
constexpr size_t B_POSWT = B_ENCB  + 163840;         // bf16 [1024][128]
constexpr size_t B_QKVWT = B_POSWT + 262144;         // bf16 [8][384][128]
constexpr size_t B_OWT   = B_QKVWT + 786432;         // bf16 [8][128][128]
constexpr size_t B_SE    = B_OWT   + 262144;         // f32 [8][1024]
constexpr size_t B_T1    = B_SE    + 32768;          // f32 [8][256]
constexpr size_t B_MP    = B_T1    + 8192;           // f32 [8][16][1024]
constexpr size_t B_RW    = B_MP    + 524288;         // f32 [64]
constexpr size_t B_LAM   = B_RW    + 256;            // f32 [8]
constexpr size_t B_POOL  = B_LAM   + 256;            // = 20914688; phase-shared pool
// pool (MLP small): W1T 8388608 | W2T 8388608 | HID 18874368            (58.7 MB)
// pool (MLP big):   W1T 8388608 | W2T 8388608 | HID 37748736            (75.4 MB)
// pool (MLP big2):  ... + PART1 bf16 9437184 after HID                  (84.9 MB)
// pool (MLP big3):  ... + PARTS bf16 4x9437184 after HID                (113.2 MB)
// pool (chan):      QKV 28311552 | DC 9437184 (out-proj IN-PLACE on DC) (58.7 MB)
constexpr size_t WS_BIG  = B_POOL + 8388608 + 8388608 + 37748736;     // 75440640
constexpr size_t WS_BIG2 = WS_BIG + 9437184;                          // 84877824
constexpr size_t WS_BIG3 = WS_BIG + 4 * 9437184;                      // 113189376

// ---------------- helpers ----------------
__device__ __forceinline__ float blockReduceSum256(float v, float* red) {
  #pragma unroll
  for (int off = 32; off; off >>= 1) v += __shfl_down(v, off, 64);
  int lane = threadIdx.x & 63, wid = threadIdx.x >> 6;
  if (lane == 0) red[wid] = v;
  __syncthreads();
  float total = 0.f;
  #pragma unroll
  for (int i = 0; i < 4; i++) total += red[i];
  return total;
}
__device__ __forceinline__ float silu(float x) { return x / (1.f + __expf(-x)); }

__device__ __forceinline__ void gl16(const bf16* g, bf16* l) {
  __builtin_amdgcn_global_load_lds(
      (const __attribute__((address_space(1))) void*)g,
      (__attribute__((address_space(3))) void*)l, 16, 0, 0);
}

// v_mfma_f32_16x16x16_bf16 wrapper (A,B = 4 bf16/lane; k = quad*4+j)
__device__ __forceinline__ f32x4 mfma16(bf16x4 a, bf16x4 b, f32x4 c) {
#if __has_builtin(__builtin_amdgcn_mfma_f32_16x16x16bf16_1k)
  union { bf16x4 h; s16x4 s; } ua, ub;
  ua.h = a; ub.h = b;
  return __builtin_amdgcn_mfma_f32_16x16x16bf16_1k(ua.s, ub.s, c, 0, 0, 0);
#else
  f32x4 d = c;
  asm volatile("v_mfma_f32_16x16x16_bf16 %0, %1, %2, %0"
               : "+v"(d) : "v"(a), "v"(b));
  return d;
#endif
}

// ---------------- batched cast+transpose of ALL weights, one dispatch -------------
__device__ __forceinline__ void tcast_tile(const float* __restrict__ W,
    bf16* __restrict__ Wt, int K, int N, long zo, int bx, int by) {
  __shared__ float t[32][33];
  int n0 = bx * 32, k0 = by * 32;
  int tid = threadIdx.x;
  int r = tid >> 3, c4 = (tid & 7) * 4;
  const float4 v = *(const float4*)(W + zo + (long)(k0 + r) * N + n0 + c4);
  t[c4 + 0][r] = v.x; t[c4 + 1][r] = v.y; t[c4 + 2][r] = v.z; t[c4 + 3][r] = v.w;
  __syncthreads();
  bf16* dst = Wt + zo + (long)(n0 + r) * K + k0 + c4;
  bf16x4 o4;
  o4[0] = (bf16)t[r][c4 + 0]; o4[1] = (bf16)t[r][c4 + 1];
  o4[2] = (bf16)t[r][c4 + 2]; o4[3] = (bf16)t[r][c4 + 3];
  *(bf16x4*)dst = o4;
}

__global__ __launch_bounds__(256) void k_tcast_all(
    const float* __restrict__ w1, const float* __restrict__ w2,
    const float* __restrict__ posw, const float* __restrict__ qkvw,
    const float* __restrict__ outw,
    bf16* __restrict__ W1T, bf16* __restrict__ W2T, bf16* __restrict__ POSWT,
    bf16* __restrict__ QKVWT, bf16* __restrict__ OWT) {
  int bid = blockIdx.x;
  if (bid < 4096) {
    tcast_tile(w1, W1T, 1024, 4096, 0, bid % 128, bid / 128);
  } else if (bid < 8192) {
    int t = bid - 4096;
    tcast_tile(w2, W2T, 4096, 1024, 0, t % 32, t / 32);
  } else if (bid < 8320) {
    int t = bid - 8192;
    tcast_tile(posw, POSWT, 128, 1024, 0, t % 32, t / 32);
  } else if (bid < 8704) {
    int t = bid - 8320;
    int z = t / 48; t -= z * 48;
    tcast_tile(qkvw, QKVWT, 128, 384, (long)z * 49152, t % 12, t / 12);
  } else {
    int t = bid - 8704;
    int z = t / 16; t -= z * 16;
    tcast_tile(outw, OWT, 128, 128, (long)z * 16384, t % 4, t / 4);
  }
}

// ---------------- positional encoding (bf16 out) ----------------
__global__ void k_enc_b(const float* __restrict__ fh, const float* __restrict__ fw,
                        const float* __restrict__ ph, const float* __restrict__ pw,
                        bf16* __restrict__ enc) {
  int idx = blockIdx.x * blockDim.x + threadIdx.x;
  if (idx >= Lq * 128) return;
  int l = idx >> 7, c = idx & 127;
  int hh = l / WIMG, ww = l % WIMG;
  float v;
  if (c < 64) {
    int f = c & 31;
    float fr = log1pf(__expf(fh[f])) * 10.f;
    float a = (hh / (float)HIMG) * fr + ph[f];
    v = (c < 32) ? sinf(a) : cosf(a);
  } else {
    int f = c & 31;
    float fr = log1pf(__expf(fw[f])) * 10.f;
    float a = (ww / (float)WIMG) * fr + pw[f];
    v = (c < 96) ? sinf(a) : cosf(a);
  }
  enc[idx] = (bf16)v;
}

// ---------------- bf16 MFMA GEMM 128x128 ----------------
// SWZ=0: 3D grid (x=n, y=m, z).  SWZ=1 (gemm1): 1D grid 1152; XCD-pinned groups
// (m, n-half): all 16 n-tiles of a group share lid%8 -> same XCD L2 serves A-panel.
// SWZ=2 (gemm2 K-split): 1D grid 8*G; group G=(m,z) owns its 8 n-tiles on one XCD.
template <int ACT, int OUTBF, int SWZ>
__global__ __launch_bounds__(256) void gemm_bt(
    const bf16* __restrict__ A, int lda, long aZs,
    const bf16* __restrict__ Bt, int ldb, long bZs,
    const float* __restrict__ bias, int biasZs,
    void* __restrict__ Cv, int ldc, long cZs,
    int M, int N, int K) {
  __shared__ bf16 As[128 * 32];
  __shared__ bf16 Bs[128 * 32];
  int tid = threadIdx.x;
  int m0, n0, z;
  if constexpr (SWZ == 0) {
    m0 = blockIdx.y * 128; n0 = blockIdx.x * 128; z = blockIdx.z;
  } else if constexpr (SWZ == 1) {
    int lid = blockIdx.x;
    int xcd = lid & 7, idx = lid >> 3;
    int j = idx & 15, G = xcd + 8 * (idx >> 4);   // G in [0,72)
    m0 = (G % 36) * 128; n0 = ((G / 36) * 16 + j) * 128; z = 0;
  } else {
    int lid = blockIdx.x;
    int xcd = lid & 7, idx = lid >> 3;
    int n = idx & 7, G = xcd + 8 * (idx >> 3);    // G in [0, grid/8)
    m0 = (G % 36) * 128; n0 = n * 128; z = G / 36;
  }
  const bf16* Ab = A + (long)z * aZs;
  const bf16* Bb = Bt + (long)z * bZs;
  f32x4 acc[4][4] = {};
  int wv = tid >> 6, lane = tid & 63;
  int wrow = (wv >> 1) * 64, wcol = (wv & 1) * 64;
  int lm = lane & 15, lq = lane >> 4;
  const bf16* ag = Ab + (long)(m0 + (tid >> 2)) * lda + (tid & 3) * 8;
  const bf16* bg = Bb + (long)(n0 + (tid >> 2)) * ldb + (tid & 3) * 8;
  bf16* asd = As + tid * 8;
  bf16* bsd = Bs + tid * 8;
  for (int k0 = 0; k0 < K; k0 += 32) {
    gl16(ag + k0, asd);
    gl16(ag + k0 + 64L * lda, asd + 2048);
    gl16(bg + k0, bsd);
    gl16(bg + k0 + 64L * ldb, bsd + 2048);
    __syncthreads();
    bf16x8 af[4], bfr[4];
    #pragma unroll
    for (int i = 0; i < 4; i++) {
      af[i]  = *(const bf16x8*)(As + (wrow + i * 16 + lm) * 32 + lq * 8);
      bfr[i] = *(const bf16x8*)(Bs + (wcol + i * 16 + lm) * 32 + lq * 8);
    }
    #pragma unroll
    for (int i = 0; i < 4; i++)
      #pragma unroll
      for (int j = 0; j < 4; j++)
        acc[i][j] = __builtin_amdgcn_mfma_f32_16x16x32_bf16(af[i], bfr[j], acc[i][j], 0, 0, 0);
    __syncthreads();
  }
  long cz = (long)z * cZs;
  const float* bz = bias ? bias + (long)z * biasZs : nullptr;
  #pragma unroll
  for (int i = 0; i < 4; i++) {
    int row = m0 + wrow + i * 16 + lq * 4;
    #pragma unroll
    for (int j = 0; j < 4; j++) {
      int col = n0 + wcol + j * 16 + lm;
      float bv = bz ? bz[col] : 0.f;
      #pragma unroll
      for (int r = 0; r < 4; r++) {
        float v = acc[i][j][r] + bv;
        if (ACT == 1) v = silu(v);
        long off = cz + (long)(row + r) * ldc + col;
        if (OUTBF) ((bf16*)Cv)[off] = (bf16)v;
        else       ((float*)Cv)[off] = v;
      }
    }
  }
}

// ---------------- 256x256 8-wave free-run MFMA GEMM ----------------
// 256^2 tile, BK=64, 512 threads = 8 waves (2M x 4N), per-wave output 128x64
// (acc[8][4] f32x4), LDS 128 KiB = 2 buffers x (A 256x64 + B 256x64) bf16.
// Schedule: ONE __syncthreads per K-tile (its vmcnt(0)+barrier both drains the
// stage issued a full iteration earlier and hands over the double buffers).
// NO inner barriers: waves slip freely, so one wave's ds_reads overlap another
// wave's MFMAs. setprio(1) around each MFMA cluster; b0 kept live across iter.
// LDS swizzle: slot ^= (row&7) within each 128B row; applied on the global
// source (LDS dest linear, required by gl16) and on the ds_read address.
template <int ACT>
__global__ __launch_bounds__(512) void gemm256(
    const bf16* __restrict__ A, int lda, long aZs,
    const bf16* __restrict__ Bt, int ldb, long bZs,
    const float* __restrict__ bias,
    bf16* __restrict__ C, int ldc, long cZs,
    int Mtiles, int Ntiles, int K) {
  __shared__ bf16 LDS[65536];   // [buf:2][mat:2][half:2][128][64] bf16 = 128 KiB
  const int tid = threadIdx.x;
  // XCD-aware bijective swizzle (gridDim.x % 8 == 0 in all launches here)
  const int cpx = gridDim.x >> 3;
  const int wg = (blockIdx.x & 7) * cpx + (blockIdx.x >> 3);
  const int per_z = Mtiles * Ntiles;
  const int z = wg / per_z, rwg = wg % per_z;
  const int m0 = (rwg / Ntiles) * 256, n0 = (rwg % Ntiles) * 256;
  const bf16* Ab = A + (long)z * aZs;
  const bf16* Bb = Bt + (long)z * bZs;
  // --- staging geometry: 2 x 16B chunks/thread per 128x64 half-tile ---
  const int c0 = tid, c1 = tid + 512;
  const int sr0 = c0 >> 3, sc0 = ((c0 & 7) ^ (sr0 & 7)) * 8;  // pre-swizzled src col
  const int sr1 = c1 >> 3, sc1 = ((c1 & 7) ^ (sr1 & 7)) * 8;
  const long a00 = (long)(m0 + sr0) * lda + sc0;
  const long a01 = (long)(m0 + sr1) * lda + sc1;
  const long a10 = (long)(m0 + 128 + sr0) * lda + sc0;
  const long a11 = (long)(m0 + 128 + sr1) * lda + sc1;
  const long b00 = (long)(n0 + sr0) * ldb + sc0;
  const long b01 = (long)(n0 + sr1) * ldb + sc1;
  const long b10 = (long)(n0 + 128 + sr0) * ldb + sc0;
  const long b11 = (long)(n0 + 128 + sr1) * ldb + sc1;
  const int d0 = c0 * 8, d1 = c1 * 8;                 // linear LDS dest (elems)
  auto stage = [&](int kt, int buf) {
    const bf16* Ak = Ab + kt * 64;
    const bf16* Bk = Bb + kt * 64;
    bf16* L = LDS + buf * 32768;
    gl16(Ak + a00, L + d0);         gl16(Ak + a01, L + d1);
    gl16(Ak + a10, L + 8192 + d0);  gl16(Ak + a11, L + 8192 + d1);
    gl16(Bk + b00, L + 16384 + d0); gl16(Bk + b01, L + 16384 + d1);
    gl16(Bk + b10, L + 24576 + d0); gl16(Bk + b11, L + 24576 + d1);
  };
  // --- wave geometry: 8 waves = 2M x 4N; per-wave output 128 x 64 ---
  const int wv = tid >> 6, lane = tid & 63;
  const int wm = wv >> 2, wn = wv & 3;
  const int lm = lane & 15, lq = lane >> 4;
  const int sw = lm & 7;                              // row&7 read-side XOR
  const int abase = wm * 8192;                        // wave's A half
  const int bbase = 16384 + (wn >> 1) * 8192;         // wave's B half
  const int brow0 = (wn & 1) * 64;                    // wave's rows within B half
  const int kq0 = (lq ^ sw) * 8;                      // swizzled slot, ks=0
  const int kq1 = ((4 + lq) ^ sw) * 8;                // swizzled slot, ks=1
  f32x4 acc[8][4] = {};
  const int NT = K >> 6;
  stage(0, 0);
  for (int s = 0; s < NT; ++s) {
    __syncthreads();   // vmcnt(0)+barrier: stage(s) landed; buffers handed over
    if (s + 1 < NT) stage(s + 1, (s + 1) & 1);
    const int bb = (s & 1) * 32768;
    const bf16* La = LDS + bb + abase + lm * 64;
    const bf16* Lb = LDS + bb + bbase + (brow0 + lm) * 64;
    bf16x8 a0[4][2], a1[4][2], b0[2][2], b1[2][2];
    #pragma unroll
    for (int f = 0; f < 4; f++) {
      a0[f][0] = *(const bf16x8*)(La + f * 1024 + kq0);
      a0[f][1] = *(const bf16x8*)(La + f * 1024 + kq1);
    }
    #pragma unroll
    for (int g = 0; g < 2; g++) {
      b0[g][0] = *(const bf16x8*)(Lb + g * 1024 + kq0);
      b0[g][1] = *(const bf16x8*)(Lb + g * 1024 + kq1);
    }
    // ---- Q00: acc[f][g] += A0 . B0 ----
    __builtin_amdgcn_s_setprio(1);
    #pragma unroll
    for (int f = 0; f < 4; f++)
      #pragma unroll
      for (int g = 0; g < 2; g++) {
        acc[f][g] = __builtin_amdgcn_mfma_f32_16x16x32_bf16(a0[f][0], b0[g][0], acc[f][g], 0, 0, 0);
        acc[f][g] = __builtin_amdgcn_mfma_f32_16x16x32_bf16(a0[f][1], b0[g][1], acc[f][g], 0, 0, 0);
      }
    __builtin_amdgcn_s_setprio(0);
    #pragma unroll
    for (int g = 0; g < 2; g++) {
      b1[g][0] = *(const bf16x8*)(Lb + 2048 + g * 1024 + kq0);
      b1[g][1] = *(const bf16x8*)(Lb + 2048 + g * 1024 + kq1);
    }
    // ---- Q01: acc[f][2+g] += A0 . B1 ----
    __builtin_amdgcn_s_setprio(1);
    #pragma unroll
    for (int f = 0; f < 4; f++)
      #pragma unroll
      for (int g = 0; g < 2; g++) {
        acc[f][2 + g] = __builtin_amdgcn_mfma_f32_16x16x32_bf16(a0[f][0], b1[g][0], acc[f][2 + g], 0, 0, 0);
        acc[f][2 + g] = __builtin_amdgcn_mfma_f32_16x16x32_bf16(a0[f][1], b1[g][1], acc[f][2 + g], 0, 0, 0);
      }
    __builtin_amdgcn_s_setprio(0);
    #pragma unroll
    for (int f = 0; f < 4; f++) {
      a1[f][0] = *(const bf16x8*)(La + 4096 + f * 1024 + kq0);
      a1[f][1] = *(const bf16x8*)(La + 4096 + f * 1024 + kq1);
    }
    // ---- Q11: acc[4+f][2+g] += A1 . B1 ----
    __builtin_amdgcn_s_setprio(1);
    #pragma unroll
    for (int f = 0; f < 4; f++)
      #pragma unroll
      for (int g = 0; g < 2; g++) {
        acc[4 + f][2 + g] = __builtin_amdgcn_mfma_f32_16x16x32_bf16(a1[f][0], b1[g][0], acc[4 + f][2 + g], 0, 0, 0);
        acc[4 + f][2 + g] = __builtin_amdgcn_mfma_f32_16x16x32_bf16(a1[f][1], b1[g][1], acc[4 + f][2 + g], 0, 0, 0);
      }
    __builtin_amdgcn_s_setprio(0);
    // ---- Q10: acc[4+f][g] += A1 . B0 (b0 kept live from phase 0) ----
    __builtin_amdgcn_s_setprio(1);
    #pragma unroll
    for (int f = 0; f < 4; f++)
      #pragma unroll
      for (int g = 0; g < 2; g++) {
        acc[4 + f][g] = __builtin_amdgcn_mfma_f32_16x16x32_bf16(a1[f][0], b0[g][0], acc[4 + f][g], 0, 0, 0);
        acc[4 + f][g] = __builtin_amdgcn_mfma_f32_16x16x32_bf16(a1[f][1], b0[g][1], acc[4 + f][g], 0, 0, 0);
      }
    __builtin_amdgcn_s_setprio(0);
  }
  // ---- epilogue ----
  const long cz = (long)z * cZs;
  #pragma unroll
  for (int i = 0; i < 8; i++) {
    const int row = m0 + wm * 128 + (i >> 2) * 64 + (i & 3) * 16 + lq * 4;
    #pragma unroll
    for (int j = 0; j < 4; j++) {
      const int col = n0 + wn * 64 + (j >> 1) * 32 + (j & 1) * 16 + lm;
      const float bv = bias ? bias[col] : 0.f;
      #pragma unroll
      for (int rr = 0; rr < 4; rr++) {
        float v = acc[i][j][rr] + bv;
        if (ACT == 1) v = silu(v);
        C[cz + (long)(row + rr) * ldc + col] = (bf16)v;
      }
    }
  }
}

// ---------------- bf16 MFMA GEMM 64x128 tile ----------------
// NORM=1 (qkv mode): after silu, 8-col-group rmsnorm for Q (x==0, qn, prescale) and
// K (x==1, kn); V (x==2) passthrough.
template <int ACT, int OUTBF, int ACC, int NORM>
__global__ __launch_bounds__(256) void gemm64(
    const bf16* __restrict__ A, int lda, long aZs,
    const bf16* __restrict__ Bt, int ldb, long bZs,
    const float* __restrict__ bias, int biasZs,
    void* __restrict__ Cv, int ldc, long cZs,
    int M, int N, int K,
    const float* __restrict__ qn, const float* __restrict__ kn) {
  __shared__ bf16 As[64 * 32];
  __shared__ bf16 Bs[128 * 32];
  int tid = threadIdx.x;
  int m0 = blockIdx.y * 64, n0 = blockIdx.x * 128;
  int z = blockIdx.z;
  const bf16* Ab = A + (long)z * aZs;
  const bf16* Bb = Bt + (long)z * bZs;
  f32x4 acc[4][2] = {};
  int wv = tid >> 6, lane = tid & 63;
  int lm = lane & 15, lq = lane >> 4;
  int wcol = wv * 32;
  const bf16* ag = Ab + (long)(m0 + (tid >> 2)) * lda + (tid & 3) * 8;
  const bf16* bg = Bb + (long)(n0 + (tid >> 2)) * ldb + (tid & 3) * 8;
  bf16* asd = As + tid * 8;
  bf16* bsd = Bs + tid * 8;
  for (int k0 = 0; k0 < K; k0 += 32) {
    gl16(ag + k0, asd);
    gl16(bg + k0, bsd);
    gl16(bg + k0 + 64L * ldb, bsd + 2048);
    __syncthreads();
    bf16x8 af[4], bfr[2];
    #pragma unroll
    for (int i = 0; i < 4; i++)
      af[i] = *(const bf16x8*)(As + (i * 16 + lm) * 32 + lq * 8);
    #pragma unroll
    for (int j = 0; j < 2; j++)
      bfr[j] = *(const bf16x8*)(Bs + (wcol + j * 16 + lm) * 32 + lq * 8);
    #pragma unroll
    for (int i = 0; i < 4; i++)
      #pragma unroll
      for (int j = 0; j < 2; j++)
        acc[i][j] = __builtin_amdgcn_mfma_f32_16x16x32_bf16(af[i], bfr[j], acc[i][j], 0, 0, 0);
    __syncthreads();
  }
  long cz = (long)z * cZs;
  const float* bz = bias ? bias + (long)z * biasZs : nullptr;
  if constexpr (NORM == 0) {
    #pragma unroll
    for (int i = 0; i < 4; i++) {
      int row = m0 + i * 16 + lq * 4;
      #pragma unroll
      for (int j = 0; j < 2; j++) {
        int col = n0 + wcol + j * 16 + lm;
        float bv = bz ? bz[col] : 0.f;
        #pragma unroll
        for (int r = 0; r < 4; r++) {
          float v = acc[i][j][r] + bv;
          long off = cz + (long)(row + r) * ldc + col;
          if (ACC) v += (float)((bf16*)Cv)[off];
          if (ACT == 1) v = silu(v);
          if (OUTBF) ((bf16*)Cv)[off] = (bf16)v;
          else       ((float*)Cv)[off] = v;
        }
      }
    }
  } else {
    int nsec = blockIdx.x;              // 0=Q, 1=K, 2=V
    bool don = nsec < 2;
    float wnv = 1.f;
    if (nsec == 0) wnv = qn[z * 8 + (lm & 7)] * QSCALE_E;
    else if (nsec == 1) wnv = kn[z * 8 + (lm & 7)];
    #pragma unroll
    for (int i = 0; i < 4; i++) {
      int row = m0 + i * 16 + lq * 4;
      #pragma unroll
      for (int j = 0; j < 2; j++) {
        int col = n0 + wcol + j * 16 + lm;
        float bv = bz ? bz[col] : 0.f;
        #pragma unroll
        for (int r = 0; r < 4; r++) {
          float v = acc[i][j][r] + bv;
          if (ACT == 1) v = silu(v);
          float s = v * v;
          s += __shfl_xor(s, 1);
          s += __shfl_xor(s, 2);
          s += __shfl_xor(s, 4);
          if (don) v = v * rsqrtf(s * 0.125f + EPS) * wnv;
          ((bf16*)Cv)[cz + (long)(row + r) * ldc + col] = (bf16)v;
        }
      }
    }
  }
}

// ---------------- embed + rmsnorm -> bf16 h ----------------
__global__ __launch_bounds__(256) void k_embed(const float* __restrict__ x,
    const float* __restrict__ emb, const float* __restrict__ pos,
    const float* __restrict__ nw, bf16* __restrict__ h) {
  __shared__ float red[4];
  int row = blockIdx.x;
  int l = row % Lq;
  int xi = (int)(x[row] * 255.f);
  xi = min(max(xi, 0), 255);
  const float* er = emb + (long)xi * WIDTH;
  const float* pr = pos + (long)l * WIDTH;
  int c0 = threadIdx.x * 4;
  float v[4]; float ss = 0.f;
  #pragma unroll
  for (int i = 0; i < 4; i++) { v[i] = er[c0 + i] + pr[c0 + i]; ss += v[i] * v[i]; }
  ss = blockReduceSum256(ss, red);
  float r = rsqrtf(ss / WIDTH + EPS);
  bf16* hr = h + (long)row * WIDTH;
  #pragma unroll
  for (int i = 0; i < 4; i++) hr[c0 + i] = (bf16)(v[i] * r * nw[c0 + i]);
}

// ---------------- mean over L, phase 1: 16 partials per b ----------------
__global__ void k_meanl_p(const bf16* __restrict__ h, float* __restrict__ part) {
  int lp = blockIdx.x, b = blockIdx.y, t = threadIdx.x;
  const bf16* p = h + ((long)b * Lq + (long)lp * 36) * WIDTH + t * 4;
  float a0 = 0, a1 = 0, a2 = 0, a3 = 0;
  for (int l = 0; l < 36; l++) {
    bf16x4 v = *(const bf16x4*)(p + (long)l * WIDTH);
    a0 += (float)v[0]; a1 += (float)v[1]; a2 += (float)v[2]; a3 += (float)v[3];
  }
  float* dst = part + ((long)b * 16 + lp) * WIDTH + t * 4;
  dst[0] = a0; dst[1] = a1; dst[2] = a2; dst[3] = a3;
}

// ---------------- SE phase 1 ----------------
__global__ __launch_bounds__(256) void k_se1(const float* __restrict__ part,
    const float* __restrict__ w1, const float* __restrict__ b1,
    float* __restrict__ t1) {
  __shared__ float sv[1024];
  __shared__ float red[256];
  int jb = blockIdx.x, b = blockIdx.y, t = threadIdx.x;
  for (int c = t; c < 1024; c += 256) {
    float a = 0.f;
    #pragma unroll
    for (int lp = 0; lp < 16; lp++) a += part[((long)b * 16 + lp) * 1024 + c];
    sv[c] = a * (1.f / 576.f);
  }
  __syncthreads();
  int j = t & 7, pt = t >> 3;
  int j0 = jb * 8;
  float acc = 0.f;
  int c0 = pt * 32;
  #pragma unroll 8
  for (int c = c0; c < c0 + 32; c++) acc += sv[c] * w1[c * 256 + j0 + j];
  red[t] = acc;
  __syncthreads();
  if (t < 8) {
    float a = b1[j0 + t];
    #pragma unroll
    for (int p = 0; p < 32; p++) a += red[p * 8 + t];
    t1[b * 256 + j0 + t] = silu(a);
  }
}

// ---------------- SE phase 2 ----------------
__global__ __launch_bounds__(256) void k_se2(const float* __restrict__ t1,
    const float* __restrict__ w2, const float* __restrict__ b2,
    float* __restrict__ s) {
  __shared__ float red[256];
  int jb = blockIdx.x, b = blockIdx.y, t = threadIdx.x;
  int j = t & 31, pt = t >> 5;
  int j0 = jb * 32;
  const float* tb = t1 + b * 256;
  float acc = 0.f;
  int c0 = pt * 32;
  #pragma unroll 8
  for (int c = c0; c < c0 + 32; c++) acc += tb[c] * w2[c * 1024 + j0 + j];
  red[t] = acc;
  __syncthreads();
  if (t < 32) {
    float a = b2[j0 + t];
    #pragma unroll
    for (int p = 0; p < 8; p++) a += red[p * 32 + t];
    s[b * 1024 + j0 + t] = 1.f / (1.f + __expf(-a));
  }
}

// ---------------- mix: h += rmsnorm(h*(s-1), mw) ----------------
__global__ __launch_bounds__(256) void k_mix_b(bf16* __restrict__ h,
    const float* __restrict__ s, const float* __restrict__ mw) {
  __shared__ float red[4];
  int row = blockIdx.x;
  int b = row / Lq;
  bf16* hr = h + (long)row * WIDTH;
  const float* sb = s + b * WIDTH;
  int c0 = threadIdx.x * 4;
  float hv[4], y[4]; float ss = 0.f;
  #pragma unroll
  for (int i = 0; i < 4; i++) {
    hv[i] = (float)hr[c0 + i];
    y[i] = hv[i] * (sb[c0 + i] - 1.f); ss += y[i] * y[i];
  }
  ss = blockReduceSum256(ss, red);
  float r = rsqrtf(ss / WIDTH + EPS);
  #pragma unroll
  for (int i = 0; i < 4; i++) hr[c0 + i] = (bf16)(hv[i] + y[i] * r * mw[c0 + i]);
}

// ---------------- h += rmsnorm(g, mw) ----------------
__global__ __launch_bounds__(256) void k_addnorm_b(bf16* __restrict__ h,
    const bf16* __restrict__ g, const float* __restrict__ mw) {
  __shared__ float red[4];
  int row = blockIdx.x;
  bf16* hr = h + (long)row * WIDTH;
  const bf16* gr = g + (long)row * WIDTH;
  int c0 = threadIdx.x * 4;
  float y[4]; float ss = 0.f;
  #pragma unroll
  for (int i = 0; i < 4; i++) { y[i] = (float)gr[c0 + i]; ss += y[i] * y[i]; }
  ss = blockReduceSum256(ss, red);
  float r = rsqrtf(ss / WIDTH + EPS);
  #pragma unroll
  for (int i = 0; i < 4; i++)
    hr[c0 + i] = (bf16)((float)hr[c0 + i] + y[i] * r * mw[c0 + i]);
}

// ---------------- h += rmsnorm(p0 + p1 + b2, mw)  (2-way K-split partials) --------
__global__ __launch_bounds__(256) void k_addnorm2(bf16* __restrict__ h,
    const bf16* __restrict__ p0, const bf16* __restrict__ p1,
    const float* __restrict__ b2, const float* __restrict__ mw) {
  __shared__ float red[4];
  int row = blockIdx.x;
  bf16* hr = h + (long)row * WIDTH;
  const bf16* g0 = p0 + (long)row * WIDTH;
  const bf16* g1 = p1 + (long)row * WIDTH;
  int c0 = threadIdx.x * 4;
  float y[4]; float ss = 0.f;
  #pragma unroll
  for (int i = 0; i < 4; i++) {
    y[i] = (float)g0[c0 + i] + (float)g1[c0 + i] + b2[c0 + i];
    ss += y[i] * y[i];
  }
  ss = blockReduceSum256(ss, red);
  float r = rsqrtf(ss / WIDTH + EPS);
  #pragma unroll
  for (int i = 0; i < 4; i++)
    hr[c0 + i] = (bf16)((float)hr[c0 + i] + y[i] * r * mw[c0 + i]);
}

// ---------------- h += rmsnorm(p0+p1+p2+p3 + b2, mw)  (4-way K-split) -------------
__global__ __launch_bounds__(256) void k_addnorm4(bf16* __restrict__ h,
    const bf16* __restrict__ parts, const float* __restrict__ b2,
    const float* __restrict__ mw) {
  __shared__ float red[4];
  int row = blockIdx.x;
  bf16* hr = h + (long)row * WIDTH;
  const bf16* g0 = parts + (long)row * WIDTH;
  int c0 = threadIdx.x * 4;
  float y[4]; float ss = 0.f;
  #pragma unroll
  for (int i = 0; i < 4; i++) {
    float a = b2[c0 + i];
    #pragma unroll
    for (int p = 0; p < 4; p++) a += (float)g0[(long)p * PSTRIDE + c0 + i];
    y[i] = a; ss += a * a;
  }
  ss = blockReduceSum256(ss, red);
  float r = rsqrtf(ss / WIDTH + EPS);
  #pragma unroll
  for (int i = 0; i < 4; i++)
    hr[c0 + i] = (bf16)((float)hr[c0 + i] + y[i] * r * mw[c0 + i]);
}

// ---------------- router + lambdas ----------------
__global__ __launch_bounds__(256) void k_router(const float* __restrict__ part,
    const float* __restrict__ rwgt, const float* __restrict__ rb,
    const float* __restrict__ lq1, const float* __restrict__ lk1,
    const float* __restrict__ lq2, const float* __restrict__ lk2,
    float* __restrict__ rw, float* __restrict__ lam) {
  __shared__ float sv[1024];
  __shared__ float red[256];
  __shared__ float lg[8];
  int b = blockIdx.x, t = threadIdx.x;
  for (int c = t; c < 1024; c += 256) {
    float a = 0.f;
    #pragma unroll
    for (int lp = 0; lp < 16; lp++) a += part[((long)b * 16 + lp) * 1024 + c];
    sv[c] = a * (1.f / 576.f);
  }
  __syncthreads();
  int j = t & 7, pt = t >> 3;
  float acc = 0.f;
  int c0 = pt * 32;
  #pragma unroll 8
  for (int c = c0; c < c0 + 32; c++) acc += sv[c] * rwgt[c * 8 + j];
  red[t] = acc;
  __syncthreads();
  if (t < 8) {
    float a = rb[t];
    for (int p = 0; p < 32; p++) a += red[p * 8 + t];
    lg[t] = a;
  }
  __syncthreads();
  if (t == 0) {
    float v[8]; bool sel[8];
    #pragma unroll
    for (int i = 0; i < 8; i++) { v[i] = lg[i]; sel[i] = false; }
    int idxs[4]; float vals[4];
    for (int s = 0; s < 4; s++) {
      int bi = -1; float bv = -1e30f;
      for (int i = 0; i < 8; i++) if (!sel[i] && v[i] > bv) { bv = v[i]; bi = i; }
      sel[bi] = true; idxs[s] = bi; vals[s] = bv;
    }
    float m = vals[0], den = 0.f, e[4];
    for (int s = 0; s < 4; s++) { e[s] = __expf(vals[s] - m); den += e[s]; }
    for (int i = 0; i < 8; i++) rw[b * 8 + i] = 0.f;
    for (int s = 0; s < 4; s++) rw[b * 8 + idxs[s]] = e[s] / den;
  }
  if (b == 0 && t >= 8 && t < 16) {
    int c = t - 8;
    float d1 = 0.f, d2 = 0.f;
    for (int i = 0; i < 8; i++) {
      d1 += lq1[c * 8 + i] * lk1[c * 8 + i];
      d2 += lq2[c * 8 + i] * lk2[c * 8 + i];
    }
    lam[c] = __expf(d1) - __expf(d2) + LAMINIT;
  }
}

// ---------------- MFMA causal differential attention (prenormed Q/K) --------------
// den on the MFMA pipe (ONES ones-vector trick). K staged in LDS via gl16
// ([576][16], off the QK critical path). V staged ROW-MAJOR padded [576][18]
// (stride 18 elems = 9 dwords: the 4x ds_read_u16 PV gather's lq-groups start
// at dword offsets {0,4,8,12}+lm/2 -> adjacent groups overlap 2-way only =
// free). LDS 39168 B -> 4 blocks/CU. pr map (y=2): u = by*4+wv in [0,8):
// u<6 pair {u+2, 17-u}; u>=6 triple {u-6, u+2, 17-u}.
__global__ __launch_bounds__(256) void k_attn_mfma(
    const bf16* __restrict__ qkv, const float* __restrict__ lam,
    const float* __restrict__ hnw, bf16* __restrict__ dc) {
  __shared__ bf16 Ks[576 * 16];     // 18432 B
  __shared__ bf16 Vs[576 * 18];     // 20736 B
  int tid = threadIdx.x;
  int slice = blockIdx.x; int zc = slice >> 3, b = slice & 7;
  int head = blockIdx.z;
  const bf16* qkvb = qkv + ((long)zc * ROWS + (long)b * Lq) * 384;
  for (int i = tid; i < 1152; i += 256) {
    int row = i >> 1, hf = i & 1;
    gl16(qkvb + (long)row * 384 + 128 + head * 16 + hf * 8, Ks + i * 8);
  }
  for (int i = tid; i < 1152; i += 256) {
    int row = i >> 1, dh = i & 1;
    bf16x8 v = *(const bf16x8*)(qkvb + (long)row * 384 + 256 + head * 16 + dh * 8);
    *(bf16x8*)(Vs + row * 18 + dh * 8) = v;
  }
  __syncthreads();
  int wv = tid >> 6, lane = tid & 63;
  int lm = lane & 15, lq = lane >> 4;
  float lamv = lam[zc];
  float hwv[4];
  #pragma unroll
  for (int r = 0; r < 4; r++) hwv[r] = hnw[zc * 16 + lq * 4 + r] * (1.f - LAMINIT);
  const bf16 one = (bf16)1.0f;
  const bf16x4 ONES = {one, one, one, one};
  int u = blockIdx.y * 4 + wv;
  int prA, prB, prC;
  if (u < 6) { prA = u + 2; prB = 17 - u; prC = -1; }
  else       { int v2 = u - 6; prA = v2; prB = 8 + v2; prC = 11 - v2; }
  for (int pi = 0; pi < 3; pi++) {
    int pr = (pi == 0) ? prA : (pi == 1) ? prB : prC;
    if (pr < 0) continue;
    bf16x8 bq0[2] = {{}, {}}, bq1[2] = {{}, {}};
    if (lq < 2) {
      #pragma unroll
      for (int tile = 0; tile < 2; tile++) {
        bf16x8 t8 = *(const bf16x8*)(
            qkvb + (long)(pr * 32 + tile * 16 + lm) * 384 + head * 16 + lq * 8);
        if (lq == 0) bq0[tile] = t8; else bq1[tile] = t8;
      }
    }
    f32x4 o[2][2] = {};
    f32x4 dacc[2][2] = {};
    for (int kc = 0; kc <= pr; kc++) {
      f32x4 sT[2][2][2] = {};
      #pragma unroll
      for (int t = 0; t < 2; t++) {
        bf16x8 aK = {};
        if (lq < 2) aK = *(const bf16x8*)(Ks + (kc * 32 + t * 16 + lm) * 16 + lq * 8);
        #pragma unroll
        for (int tile = 0; tile < 2; tile++) {
          sT[t][tile][0] = __builtin_amdgcn_mfma_f32_16x16x32_bf16(aK, bq0[tile], sT[t][tile][0], 0, 0, 0);
          sT[t][tile][1] = __builtin_amdgcn_mfma_f32_16x16x32_bf16(aK, bq1[tile], sT[t][tile][1], 0, 0, 0);
        }
      }
      bool diag = (kc == pr);
      #pragma unroll
      for (int t = 0; t < 2; t++) {
        const bf16* vb = Vs + (kc * 32 + t * 16 + lq * 4) * 18 + lm;
        bf16x4 aV;
        aV[0] = vb[0]; aV[1] = vb[18]; aV[2] = vb[36]; aV[3] = vb[54];
        #pragma unroll
        for (int tile = 0; tile < 2; tile++) {
          if (diag && tile == 0 && t == 1) continue;
          bool masked = diag && (tile == t);
          #pragma unroll
          for (int h2 = 0; h2 < 2; h2++) {
            bf16x4 pb;
            #pragma unroll
            for (int r = 0; r < 4; r++) {
              float ev = fexp2(sT[t][tile][h2][r]);
              if (masked && (lq * 4 + r > lm)) ev = 0.f;
              pb[r] = (bf16)ev;
            }
            dacc[tile][h2] = mfma16(ONES, pb, dacc[tile][h2]);
            o[tile][h2] = mfma16(aV, pb, o[tile][h2]);
          }
        }
      }
    }
    #pragma unroll
    for (int tile = 0; tile < 2; tile++) {
      float inv1 = 1.f / dacc[tile][0][0];
      float inv2 = lamv / dacc[tile][1][0];
      float dff[4]; float ss = 0.f;
      #pragma unroll
      for (int r = 0; r < 4; r++) {
        dff[r] = o[tile][0][r] * inv1 - o[tile][1][r] * inv2;
        ss += dff[r] * dff[r];
      }
      ss += __shfl_xor(ss, 16);
      ss += __shfl_xor(ss, 32);
      float rr = rsqrtf(ss * 0.0625f + EPS);
      bf16x4 outp;
      #pragma unroll
      for (int r = 0; r < 4; r++) outp[r] = (bf16)(dff[r] * rr * hwv[r]);
      long rowg = (long)zc * ROWS + (long)b * Lq + pr * 32 + tile * 16 + lm;
      *(bf16x4*)(dc + rowg * 128 + head * 16 + lq * 4) = outp;
    }
  }
}

// ---------------- seg + pool fused: 16 bins, 1-wave blocks ----------------
__global__ __launch_bounds__(64) void k_segpool(const bf16* __restrict__ h,
    const bf16* __restrict__ op, const float* __restrict__ segw,
    const float* __restrict__ rw, float* __restrict__ part) {
  int lp = blockIdx.x, b = blockIdx.y, ch = blockIdx.z;
  int t = threadIdx.x;
  int c0 = t * 2;
  float w0 = segw[ch * 128 + c0], w1 = segw[ch * 128 + c0 + 1];
  float rwv = rw[b * 8 + ch];
  float a0 = 0.f, a1 = 0.f;
  for (int l = 0; l < 36; l++) {
    int row = b * Lq + lp * 36 + l;
    const bf16* oprow = op + (long)ch * ROWS * CW + (long)row * CW;
    bf16x2 yv = *(const bf16x2*)(oprow + c0);
    float y0 = (float)yv[0], y1 = (float)yv[1];
    float ss = y0 * y0 + y1 * y1;
    #pragma unroll
    for (int m = 1; m < 64; m <<= 1) ss += __shfl_xor(ss, m);
    float r = rsqrtf(ss * (1.f / 128.f) + EPS);
    bf16x2 hv = *(const bf16x2*)(h + (long)row * WIDTH + ch * 128 + c0);
    a0 += ((float)hv[0] + y0 * r * w0) * rwv;
    a1 += ((float)hv[1] + y1 * r * w1) * rwv;
  }
  float* dst = part + ((long)b * 16 + lp) * 1024 + ch * 128 + c0;
  dst[0] = a0; dst[1] = a1;
}

// ---------------- head (reads 16 pool partials) ----------------
__global__ __launch_bounds__(256) void k_head(const float* __restrict__ part,
    const float* __restrict__ hw, const float* __restrict__ hb, float* __restrict__ out) {
  __shared__ float pool[1024];
  __shared__ float red[256];
  int b = blockIdx.x, t = threadIdx.x;
  for (int c = t; c < 1024; c += 256) {
    float a = 0.f;
    #pragma unroll
    for (int lp = 0; lp < 16; lp++) a += part[((long)b * 16 + lp) * 1024 + c];
    pool[c] = a * (1.f / 576.f);
  }
  __syncthreads();
  int j = t & 15, pt = t >> 4;
  float acc = 0.f;
  if (j < 10)
    for (int c = pt * 64; c < pt * 64 + 64; c++)
      acc += pool[c] * hw[c * 10 + j];
  red[t] = acc;
  __syncthreads();
  if (t < 10) {
    float a = hb[t];
    for (int p = 0; p < 16; p++) a += red[p * 16 + t];
    out[b * 10 + t] = a;
  }
}

// ---------------- launcher ----------------
extern "C" void kernel_launch(void* const* d_in, const int* in_sizes, int n_in,
                              void* d_out, int out_size, void* d_ws, size_t ws_size,
                              hipStream_t stream) {
  const float* x          = (const float*)d_in[0];
  const float* pixel_embed= (const float*)d_in[2];
  const float* freq_h     = (const float*)d_in[3];
  const float* freq_w     = (const float*)d_in[4];
  const float* phase_h    = (const float*)d_in[5];
  const float* phase_w    = (const float*)d_in[6];
  const float* pos_proj_w = (const float*)d_in[7];
  const float* pos_proj_b = (const float*)d_in[8];
  const float* embed_norm = (const float*)d_in[9];
  const float* se_w1      = (const float*)d_in[10];
  const float* se_b1      = (const float*)d_in[11];
  const float* se_w2      = (const float*)d_in[12];
  const float* se_b2      = (const float*)d_in[13];
  const float* mix_norm   = (const float*)d_in[14];
  const float* mlp_w1     = (const float*)d_in[15];
  const float* mlp_b1     = (const float*)d_in[16];
  const float* mlp_w2     = (const float*)d_in[17];
  const float* mlp_b2     = (const float*)d_in[18];
  const float* mlp_norm   = (const float*)d_in[19];
  const float* router_w   = (const float*)d_in[20];
  const float* router_b   = (const float*)d_in[21];
  const float* qkv_w      = (const float*)d_in[22];
  const float* qkv_b      = (const float*)d_in[23];
  const float* q_norm_w   = (const float*)d_in[24];
  const float* k_norm_w   = (const float*)d_in[25];
  const float* head_norm_w= (const float*)d_in[26];
  const float* lam_q1     = (const float*)d_in[27];
  const float* lam_k1     = (const float*)d_in[28];
  const float* lam_q2     = (const float*)d_in[29];
  const float* lam_k2     = (const float*)d_in[30];
  const float* out_w      = (const float*)d_in[31];
  const float* out_b      = (const float*)d_in[32];
  const float* seg_norm_w = (const float*)d_in[33];
  const float* head_w     = (const float*)d_in[34];
  const float* head_b     = (const float*)d_in[35];

  char* W = (char*)d_ws;
  bf16*  HB    = (bf16*)(W + B_HB);
  bf16*  G2B   = (bf16*)(W + B_G2B);
  float* POS   = (float*)(W + B_G2B);      // POS lives in G2B region (dead until MLP)
  bf16*  ENCB  = (bf16*)(W + B_ENCB);
  bf16*  POSWT = (bf16*)(W + B_POSWT);
  bf16*  QKVWT = (bf16*)(W + B_QKVWT);
  bf16*  OWT   = (bf16*)(W + B_OWT);
  float* SE    = (float*)(W + B_SE);
  float* T1    = (float*)(W + B_T1);
  float* MP    = (float*)(W + B_MP);
  float* RW    = (float*)(W + B_RW);
  float* LAM   = (float*)(W + B_LAM);
  char*  P     = W + B_POOL;
  bf16*  W1T   = (bf16*)P;
  bf16*  W2T   = (bf16*)(P + 8388608);
  bf16*  HID   = (bf16*)(P + 16777216);
  bf16*  PARTS = (bf16*)(P + 16777216 + 37748736);   // after full-width HID
  bf16*  QKV   = (bf16*)P;
  bf16*  DC    = (bf16*)(P + 28311552);
  float* out   = (float*)d_out;
  const int tier = (ws_size >= WS_BIG3) ? 3 : (ws_size >= WS_BIG2) ? 2
                 : (ws_size >= WS_BIG) ? 1 : 0;

  // 0. all weight casts in one dispatch
  k_tcast_all<<<8832, 256, 0, stream>>>(mlp_w1, mlp_w2, pos_proj_w, qkv_w, out_w,
                                        W1T, W2T, POSWT, QKVWT, OWT);
  // 1. positional encoding + projection (POS f32 in G2B region)
  k_enc_b<<<288, 256, 0, stream>>>(freq_h, freq_w, phase_h, phase_w, ENCB);
  gemm64<0, 0, 0, 0><<<dim3(8, 10, 1), 256, 0, stream>>>(
      ENCB, 128, 0, POSWT, 128, 0, pos_proj_b, 0, POS, 1024, 0, 640, 1024, 128,
      nullptr, nullptr);
  // 2. embed + rmsnorm -> bf16 h
  k_embed<<<ROWS, 256, 0, stream>>>(x, pixel_embed, POS, embed_norm, HB);
  // 3. SE gate
  k_meanl_p<<<dim3(16, 8), 256, 0, stream>>>(HB, MP);
  k_se1<<<dim3(32, 8), 256, 0, stream>>>(MP, se_w1, se_b1, T1);
  k_se2<<<dim3(32, 8), 256, 0, stream>>>(T1, se_w2, se_b2, SE);
  k_mix_b<<<ROWS, 256, 0, stream>>>(HB, SE, mix_norm);
  // 4. MLP
  if (tier >= 1) {
    // gemm1 main: 256^2 8-wave kernel, rows 0..4095 (16m x 16n = 256 blocks,
    // exactly one block-wave over 256 CUs); 128^2 tail covers rows 4096..4607.
    gemm256<1><<<256, 512, 0, stream>>>(
        HB, 1024, 0, W1T, 1024, 0, mlp_b1,
        HID, 4096, 0, 16, 16, 1024);
    gemm_bt<1, 1, 0><<<dim3(32, 4, 1), 256, 0, stream>>>(
        HB + 4096L * 1024, 1024, 0, W1T, 1024, 0, mlp_b1, 0,
        HID + 4096L * 4096, 4096, 0, 512, 4096, 1024);
    if (tier == 3) {
      // gemm2 main: 4-way K-split, 16m x 4n x 4z = 256 blocks; tail 128^2.
      gemm256<0><<<256, 512, 0, stream>>>(
          HID, 4096, 1024, W2T, 4096, 1024, nullptr,
          PARTS, 1024, PSTRIDE, 16, 4, 1024);
      gemm_bt<0, 1, 0><<<dim3(8, 4, 4), 256, 0, stream>>>(
          HID + 4096L * 4096, 4096, 1024, W2T, 4096, 1024, nullptr, 0,
          PARTS + 4096L * 1024, 1024, PSTRIDE, 512, 1024, 1024);
      k_addnorm4<<<ROWS, 256, 0, stream>>>(HB, PARTS, mlp_b2, mlp_norm);
    } else if (tier == 2) {
      // gemm2: 2-way K-split, XCD-pinned, partials in G2B + PARTS[0]
      gemm_bt<0, 1, 2><<<576, 256, 0, stream>>>(
          HID, 4096, 2048, W2T, 4096, 2048, nullptr, 0,
          G2B, 1024, (long)(PARTS - G2B), 4608, 1024, 2048);
      k_addnorm2<<<ROWS, 256, 0, stream>>>(HB, G2B, PARTS, mlp_b2, mlp_norm);
    } else {
      gemm64<0, 1, 0, 0><<<dim3(8, 72, 1), 256, 0, stream>>>(
          HID, 4096, 0, W2T, 4096, 0, mlp_b2, 0,
          G2B, 1024, 0, 4608, 1024, 4096, nullptr, nullptr);
      k_addnorm_b<<<ROWS, 256, 0, stream>>>(HB, G2B, mlp_norm);
    }
  } else {
    gemm_bt<1, 1, 0><<<dim3(16, 36, 1), 256, 0, stream>>>(
        HB, 1024, 0, W1T, 1024, 0, mlp_b1, 0, HID, 2048, 0, 4608, 2048, 1024);
    gemm64<0, 1, 0, 0><<<dim3(8, 72, 1), 256, 0, stream>>>(
        HID, 2048, 0, W2T, 4096, 0, mlp_b2, 0, G2B, 1024, 0, 4608, 1024, 2048,
        nullptr, nullptr);
    gemm_bt<1, 1, 0><<<dim3(16, 36, 1), 256, 0, stream>>>(
        HB, 1024, 0, W1T + 2048L * 1024, 1024, 0, mlp_b1 + 2048, 0, HID, 2048, 0,
        4608, 2048, 1024);
    gemm64<0, 1, 1, 0><<<dim3(8, 72, 1), 256, 0, stream>>>(
        HID, 2048, 0, W2T + 2048, 4096, 0, nullptr, 0, G2B, 1024, 0,
        4608, 1024, 2048, nullptr, nullptr);
    k_addnorm_b<<<ROWS, 256, 0, stream>>>(HB, G2B, mlp_norm);
  }
  // 5. router + lambdas
  k_meanl_p<<<dim3(16, 8), 256, 0, stream>>>(HB, MP);
  k_router<<<8, 256, 0, stream>>>(MP, router_w, router_b,
                                  lam_q1, lam_k1, lam_q2, lam_k2, RW, LAM);
  // 6. qkv-proj with fused silu + Q/K rmsnorm (+ Q prescale) in epilogue
  gemm64<1, 1, 0, 1><<<dim3(3, 72, 8), 256, 0, stream>>>(
      HB, 1024, CW, QKVWT, 128, 384 * 128, qkv_b, 384,
      QKV, 384, (long)ROWS * 384, ROWS, 384, 128, q_norm_w, k_norm_w);
  // 7. attention (prenormed), out-proj in-place on DC
  k_attn_mfma<<<dim3(64, 2, 8), 256, 0, stream>>>(QKV, LAM, head_norm_w, DC);
  gemm64<1, 1, 0, 0><<<dim3(1, 72, 8), 256, 0, stream>>>(
      DC, 128, (long)ROWS * 128, OWT, 128, 128 * 128, out_b, 128,
      DC, 128, (long)ROWS * 128, ROWS, 128, 128, nullptr, nullptr);
  // 8. seg + pool fused -> 16 partials; head folds the final reduce
  k_segpool<<<dim3(16, 8, 8), 64, 0, stream>>>(HB, DC, seg_norm_w, RW, MP);
  k_head<<<8, 256, 0, stream>>>(MP, head_w, head_b, out);
}

// Round 6
// 429.284 us; speedup vs baseline: 1.0368x; 1.0242x over previous
//
#include <hip/hip_runtime.h>
#include <math.h>

typedef __bf16 bf16;
typedef __bf16 bf16x8 __attribute__((ext_vector_type(8)));
typedef __bf16 bf16x4 __attribute__((ext_vector_type(4)));
typedef __bf16 bf16x2 __attribute__((ext_vector_type(2)));
typedef float f32x4 __attribute__((ext_vector_type(4)));
typedef short s16x4 __attribute__((ext_vector_type(4)));

// ---------------- constants ----------------
constexpr int Bsz = 8, HIMG = 24, WIMG = 24;
constexpr int Lq = 576;
constexpr int WIDTH = 1024, NCH = 8, CW = 128;
constexpr int NHEADS = 8, HD = 16, HALF = 8;
constexpr float EPS = 1e-6f;
constexpr float LAMINIT = 0.2f;
// 1/sqrt(8) * log2(e): scores exit MFMA in log2 domain -> v_exp_f32 directly
constexpr float QSCALE_E = 0.35355339059327373f * 1.4426950408889634f;
constexpr int ROWS = Bsz * Lq;              // 4608
constexpr long PSTRIDE = 4718592;           // bf16 elements per MLP partial buffer

__device__ __forceinline__ float fexp2(float x) {
#if __has_builtin(__builtin_amdgcn_exp2f)
  return __builtin_amdgcn_exp2f(x);
#else
  return exp2f(x);
#endif
}

// ---------------- workspace byte offsets ----------------
constexpr size_t B_HB    = 0;                        // bf16 h [4608][1024]
constexpr size_t B_G2B   = B_HB    + 9437184;        // bf16 g2/partial0; POS f32 early
constexpr size_t B_ENCB  = B_G2B   + 9437184;        // bf16 enc [640][128]
constexpr size_t B_POSWT = B_ENCB  + 163840;         // bf16 [1024][128]
constexpr size_t B_QKVWT = B_POSWT + 262144;         // bf16 [8][384][128]
constexpr size_t B_OWT   = B_QKVWT + 786432;         // bf16 [8][128][128]
constexpr size_t B_SE    = B_OWT   + 262144;         // f32 [8][1024]
constexpr size_t B_T1    = B_SE    + 32768;          // f32 [8][256]
constexpr size_t B_MP    = B_T1    + 8192;           // f32 [8][16][1024]
constexpr size_t B_RW    = B_MP    + 524288;         // f32 [64]
constexpr size_t B_LAM   = B_RW    + 256;            // f32 [8]
constexpr size_t B_POOL  = B_LAM   + 256;            // = 20914688; phase-shared pool
// pool (MLP small): W1T 8388608 | W2T 8388608 | HID 18874368            (58.7 MB)
// pool (MLP big):   W1T 8388608 | W2T 8388608 | HID 37748736            (75.4 MB)
// pool (MLP big2):  ... + PART1 bf16 9437184 after HID                  (84.9 MB)
// pool (MLP big3):  ... + PARTS bf16 4x9437184 after HID                (113.2 MB)
// pool (chan):      QKV 28311552 | DC 9437184 (out-proj IN-PLACE on DC) (58.7 MB)
constexpr size_t WS_BIG  = B_POOL + 8388608 + 8388608 + 37748736;     // 75440640
constexpr size_t WS_BIG2 = WS_BIG + 9437184;                          // 84877824
constexpr size_t WS_BIG3 = WS_BIG + 4 * 9437184;                      // 113189376

// ---------------- helpers ----------------
__device__ __forceinline__ float blockReduceSum256(float v, float* red) {
  #pragma unroll
  for (int off = 32; off; off >>= 1) v += __shfl_down(v, off, 64);
  int lane = threadIdx.x & 63, wid = threadIdx.x >> 6;
  if (lane == 0) red[wid] = v;
  __syncthreads();
  float total = 0.f;
  #pragma unroll
  for (int i = 0; i < 4; i++) total += red[i];
  return total;
}
__device__ __forceinline__ float silu(float x) { return x / (1.f + __expf(-x)); }

__device__ __forceinline__ void gl16(const bf16* g, bf16* l) {
  __builtin_amdgcn_global_load_lds(
      (const __attribute__((address_space(1))) void*)g,
      (__attribute__((address_space(3))) void*)l, 16, 0, 0);
}

// v_mfma_f32_16x16x16_bf16 wrapper (A,B = 4 bf16/lane; k = quad*4+j)
__device__ __forceinline__ f32x4 mfma16(bf16x4 a, bf16x4 b, f32x4 c) {
#if __has_builtin(__builtin_amdgcn_mfma_f32_16x16x16bf16_1k)
  union { bf16x4 h; s16x4 s; } ua, ub;
  ua.h = a; ub.h = b;
  return __builtin_amdgcn_mfma_f32_16x16x16bf16_1k(ua.s, ub.s, c, 0, 0, 0);
#else
  f32x4 d = c;
  asm volatile("v_mfma_f32_16x16x16_bf16 %0, %1, %2, %0"
               : "+v"(d) : "v"(a), "v"(b));
  return d;
#endif
}

// ---------------- batched cast+transpose of ALL weights, one dispatch -------------
__device__ __forceinline__ void tcast_tile(const float* __restrict__ W,
    bf16* __restrict__ Wt, int K, int N, long zo, int bx, int by) {
  __shared__ float t[32][33];
  int n0 = bx * 32, k0 = by * 32;
  int tid = threadIdx.x;
  int r = tid >> 3, c4 = (tid & 7) * 4;
  const float4 v = *(const float4*)(W + zo + (long)(k0 + r) * N + n0 + c4);
  t[c4 + 0][r] = v.x; t[c4 + 1][r] = v.y; t[c4 + 2][r] = v.z; t[c4 + 3][r] = v.w;
  __syncthreads();
  bf16* dst = Wt + zo + (long)(n0 + r) * K + k0 + c4;
  bf16x4 o4;
  o4[0] = (bf16)t[r][c4 + 0]; o4[1] = (bf16)t[r][c4 + 1];
  o4[2] = (bf16)t[r][c4 + 2]; o4[3] = (bf16)t[r][c4 + 3];
  *(bf16x4*)dst = o4;
}

__global__ __launch_bounds__(256) void k_tcast_all(
    const float* __restrict__ w1, const float* __restrict__ w2,
    const float* __restrict__ posw, const float* __restrict__ qkvw,
    const float* __restrict__ outw,
    bf16* __restrict__ W1T, bf16* __restrict__ W2T, bf16* __restrict__ POSWT,
    bf16* __restrict__ QKVWT, bf16* __restrict__ OWT) {
  int bid = blockIdx.x;
  if (bid < 4096) {
    tcast_tile(w1, W1T, 1024, 4096, 0, bid % 128, bid / 128);
  } else if (bid < 8192) {
    int t = bid - 4096;
    tcast_tile(w2, W2T, 4096, 1024, 0, t % 32, t / 32);
  } else if (bid < 8320) {
    int t = bid - 8192;
    tcast_tile(posw, POSWT, 128, 1024, 0, t % 32, t / 32);
  } else if (bid < 8704) {
    int t = bid - 8320;
    int z = t / 48; t -= z * 48;
    tcast_tile(qkvw, QKVWT, 128, 384, (long)z * 49152, t % 12, t / 12);
  } else {
    int t = bid - 8704;
    int z = t / 16; t -= z * 16;
    tcast_tile(outw, OWT, 128, 128, (long)z * 16384, t % 4, t / 4);
  }
}

// ---------------- positional encoding (bf16 out) ----------------
__global__ void k_enc_b(const float* __restrict__ fh, const float* __restrict__ fw,
                        const float* __restrict__ ph, const float* __restrict__ pw,
                        bf16* __restrict__ enc) {
  int idx = blockIdx.x * blockDim.x + threadIdx.x;
  if (idx >= Lq * 128) return;
  int l = idx >> 7, c = idx & 127;
  int hh = l / WIMG, ww = l % WIMG;
  float v;
  if (c < 64) {
    int f = c & 31;
    float fr = log1pf(__expf(fh[f])) * 10.f;
    float a = (hh / (float)HIMG) * fr + ph[f];
    v = (c < 32) ? sinf(a) : cosf(a);
  } else {
    int f = c & 31;
    float fr = log1pf(__expf(fw[f])) * 10.f;
    float a = (ww / (float)WIMG) * fr + pw[f];
    v = (c < 96) ? sinf(a) : cosf(a);
  }
  enc[idx] = (bf16)v;
}

// ---------------- bf16 MFMA GEMM 128x128 ----------------
// SWZ=0: 3D grid (x=n, y=m, z).  SWZ=1 (gemm1): 1D grid 1152; XCD-pinned groups
// (m, n-half): all 16 n-tiles of a group share lid%8 -> same XCD L2 serves A-panel.
// SWZ=2 (gemm2 K-split): 1D grid 8*G; group G=(m,z) owns its 8 n-tiles on one XCD.
template <int ACT, int OUTBF, int SWZ>
__global__ __launch_bounds__(256) void gemm_bt(
    const bf16* __restrict__ A, int lda, long aZs,
    const bf16* __restrict__ Bt, int ldb, long bZs,
    const float* __restrict__ bias, int biasZs,
    void* __restrict__ Cv, int ldc, long cZs,
    int M, int N, int K) {
  __shared__ bf16 As[128 * 32];
  __shared__ bf16 Bs[128 * 32];
  int tid = threadIdx.x;
  int m0, n0, z;
  if constexpr (SWZ == 0) {
    m0 = blockIdx.y * 128; n0 = blockIdx.x * 128; z = blockIdx.z;
  } else if constexpr (SWZ == 1) {
    int lid = blockIdx.x;
    int xcd = lid & 7, idx = lid >> 3;
    int j = idx & 15, G = xcd + 8 * (idx >> 4);   // G in [0,72)
    m0 = (G % 36) * 128; n0 = ((G / 36) * 16 + j) * 128; z = 0;
  } else {
    int lid = blockIdx.x;
    int xcd = lid & 7, idx = lid >> 3;
    int n = idx & 7, G = xcd + 8 * (idx >> 3);    // G in [0, grid/8)
    m0 = (G % 36) * 128; n0 = n * 128; z = G / 36;
  }
  const bf16* Ab = A + (long)z * aZs;
  const bf16* Bb = Bt + (long)z * bZs;
  f32x4 acc[4][4] = {};
  int wv = tid >> 6, lane = tid & 63;
  int wrow = (wv >> 1) * 64, wcol = (wv & 1) * 64;
  int lm = lane & 15, lq = lane >> 4;
  const bf16* ag = Ab + (long)(m0 + (tid >> 2)) * lda + (tid & 3) * 8;
  const bf16* bg = Bb + (long)(n0 + (tid >> 2)) * ldb + (tid & 3) * 8;
  bf16* asd = As + tid * 8;
  bf16* bsd = Bs + tid * 8;
  for (int k0 = 0; k0 < K; k0 += 32) {
    gl16(ag + k0, asd);
    gl16(ag + k0 + 64L * lda, asd + 2048);
    gl16(bg + k0, bsd);
    gl16(bg + k0 + 64L * ldb, bsd + 2048);
    __syncthreads();
    bf16x8 af[4], bfr[4];
    #pragma unroll
    for (int i = 0; i < 4; i++) {
      af[i]  = *(const bf16x8*)(As + (wrow + i * 16 + lm) * 32 + lq * 8);
      bfr[i] = *(const bf16x8*)(Bs + (wcol + i * 16 + lm) * 32 + lq * 8);
    }
    #pragma unroll
    for (int i = 0; i < 4; i++)
      #pragma unroll
      for (int j = 0; j < 4; j++)
        acc[i][j] = __builtin_amdgcn_mfma_f32_16x16x32_bf16(af[i], bfr[j], acc[i][j], 0, 0, 0);
    __syncthreads();
  }
  long cz = (long)z * cZs;
  const float* bz = bias ? bias + (long)z * biasZs : nullptr;
  #pragma unroll
  for (int i = 0; i < 4; i++) {
    int row = m0 + wrow + i * 16 + lq * 4;
    #pragma unroll
    for (int j = 0; j < 4; j++) {
      int col = n0 + wcol + j * 16 + lm;
      float bv = bz ? bz[col] : 0.f;
      #pragma unroll
      for (int r = 0; r < 4; r++) {
        float v = acc[i][j][r] + bv;
        if (ACT == 1) v = silu(v);
        long off = cz + (long)(row + r) * ldc + col;
        if (OUTBF) ((bf16*)Cv)[off] = (bf16)v;
        else       ((float*)Cv)[off] = v;
      }
    }
  }
}

// ---------------- 256x256 8-wave free-run MFMA GEMM ----------------
// 256^2 tile, BK=64, 512 threads = 8 waves (2M x 4N), per-wave output 128x64
// (acc[8][4] f32x4), LDS 128 KiB = 2 buffers x (A 256x64 + B 256x64) bf16.
// Schedule: ONE __syncthreads per K-tile (its vmcnt(0)+barrier both drains the
// stage issued a full iteration earlier and hands over the double buffers).
// NO inner barriers: waves slip freely, so one wave's ds_reads overlap another
// wave's MFMAs. setprio(1) around each MFMA cluster; b0 kept live across iter.
// LDS swizzle: slot ^= (row&7) within each 128B row; applied on the global
// source (LDS dest linear, required by gl16) and on the ds_read address.
template <int ACT>
__global__ __launch_bounds__(512) void gemm256(
    const bf16* __restrict__ A, int lda, long aZs,
    const bf16* __restrict__ Bt, int ldb, long bZs,
    const float* __restrict__ bias,
    bf16* __restrict__ C, int ldc, long cZs,
    int Mtiles, int Ntiles, int K) {
  __shared__ bf16 LDS[65536];   // [buf:2][mat:2][half:2][128][64] bf16 = 128 KiB
  const int tid = threadIdx.x;
  // XCD-aware bijective swizzle (gridDim.x % 8 == 0 in all launches here)
  const int cpx = gridDim.x >> 3;
  const int wg = (blockIdx.x & 7) * cpx + (blockIdx.x >> 3);
  const int per_z = Mtiles * Ntiles;
  const int z = wg / per_z, rwg = wg % per_z;
  const int m0 = (rwg / Ntiles) * 256, n0 = (rwg % Ntiles) * 256;
  const bf16* Ab = A + (long)z * aZs;
  const bf16* Bb = Bt + (long)z * bZs;
  // --- staging geometry: 2 x 16B chunks/thread per 128x64 half-tile ---
  const int c0 = tid, c1 = tid + 512;
  const int sr0 = c0 >> 3, sc0 = ((c0 & 7) ^ (sr0 & 7)) * 8;  // pre-swizzled src col
  const int sr1 = c1 >> 3, sc1 = ((c1 & 7) ^ (sr1 & 7)) * 8;
  const long a00 = (long)(m0 + sr0) * lda + sc0;
  const long a01 = (long)(m0 + sr1) * lda + sc1;
  const long a10 = (long)(m0 + 128 + sr0) * lda + sc0;
  const long a11 = (long)(m0 + 128 + sr1) * lda + sc1;
  const long b00 = (long)(n0 + sr0) * ldb + sc0;
  const long b01 = (long)(n0 + sr1) * ldb + sc1;
  const long b10 = (long)(n0 + 128 + sr0) * ldb + sc0;
  const long b11 = (long)(n0 + 128 + sr1) * ldb + sc1;
  const int d0 = c0 * 8, d1 = c1 * 8;                 // linear LDS dest (elems)
  auto stage = [&](int kt, int buf) {
    const bf16* Ak = Ab + kt * 64;
    const bf16* Bk = Bb + kt * 64;
    bf16* L = LDS + buf * 32768;
    gl16(Ak + a00, L + d0);         gl16(Ak + a01, L + d1);
    gl16(Ak + a10, L + 8192 + d0);  gl16(Ak + a11, L + 8192 + d1);
    gl16(Bk + b00, L + 16384 + d0); gl16(Bk + b01, L + 16384 + d1);
    gl16(Bk + b10, L + 24576 + d0); gl16(Bk + b11, L + 24576 + d1);
  };
  // --- wave geometry: 8 waves = 2M x 4N; per-wave output 128 x 64 ---
  const int wv = tid >> 6, lane = tid & 63;
  const int wm = wv >> 2, wn = wv & 3;
  const int lm = lane & 15, lq = lane >> 4;
  const int sw = lm & 7;                              // row&7 read-side XOR
  const int abase = wm * 8192;                        // wave's A half
  const int bbase = 16384 + (wn >> 1) * 8192;         // wave's B half
  const int brow0 = (wn & 1) * 64;                    // wave's rows within B half
  const int kq0 = (lq ^ sw) * 8;                      // swizzled slot, ks=0
  const int kq1 = ((4 + lq) ^ sw) * 8;                // swizzled slot, ks=1
  f32x4 acc[8][4] = {};
  const int NT = K >> 6;
  stage(0, 0);
  for (int s = 0; s < NT; ++s) {
    __syncthreads();   // vmcnt(0)+barrier: stage(s) landed; buffers handed over
    if (s + 1 < NT) stage(s + 1, (s + 1) & 1);
    const int bb = (s & 1) * 32768;
    const bf16* La = LDS + bb + abase + lm * 64;
    const bf16* Lb = LDS + bb + bbase + (brow0 + lm) * 64;
    bf16x8 a0[4][2], a1[4][2], b0[2][2], b1[2][2];
    #pragma unroll
    for (int f = 0; f < 4; f++) {
      a0[f][0] = *(const bf16x8*)(La + f * 1024 + kq0);
      a0[f][1] = *(const bf16x8*)(La + f * 1024 + kq1);
    }
    #pragma unroll
    for (int g = 0; g < 2; g++) {
      b0[g][0] = *(const bf16x8*)(Lb + g * 1024 + kq0);
      b0[g][1] = *(const bf16x8*)(Lb + g * 1024 + kq1);
    }
    // ---- Q00: acc[f][g] += A0 . B0 ----
    __builtin_amdgcn_s_setprio(1);
    #pragma unroll
    for (int f = 0; f < 4; f++)
      #pragma unroll
      for (int g = 0; g < 2; g++) {
        acc[f][g] = __builtin_amdgcn_mfma_f32_16x16x32_bf16(a0[f][0], b0[g][0], acc[f][g], 0, 0, 0);
        acc[f][g] = __builtin_amdgcn_mfma_f32_16x16x32_bf16(a0[f][1], b0[g][1], acc[f][g], 0, 0, 0);
      }
    __builtin_amdgcn_s_setprio(0);
    #pragma unroll
    for (int g = 0; g < 2; g++) {
      b1[g][0] = *(const bf16x8*)(Lb + 2048 + g * 1024 + kq0);
      b1[g][1] = *(const bf16x8*)(Lb + 2048 + g * 1024 + kq1);
    }
    // ---- Q01: acc[f][2+g] += A0 . B1 ----
    __builtin_amdgcn_s_setprio(1);
    #pragma unroll
    for (int f = 0; f < 4; f++)
      #pragma unroll
      for (int g = 0; g < 2; g++) {
        acc[f][2 + g] = __builtin_amdgcn_mfma_f32_16x16x32_bf16(a0[f][0], b1[g][0], acc[f][2 + g], 0, 0, 0);
        acc[f][2 + g] = __builtin_amdgcn_mfma_f32_16x16x32_bf16(a0[f][1], b1[g][1], acc[f][2 + g], 0, 0, 0);
      }
    __builtin_amdgcn_s_setprio(0);
    #pragma unroll
    for (int f = 0; f < 4; f++) {
      a1[f][0] = *(const bf16x8*)(La + 4096 + f * 1024 + kq0);
      a1[f][1] = *(const bf16x8*)(La + 4096 + f * 1024 + kq1);
    }
    // ---- Q11: acc[4+f][2+g] += A1 . B1 ----
    __builtin_amdgcn_s_setprio(1);
    #pragma unroll
    for (int f = 0; f < 4; f++)
      #pragma unroll
      for (int g = 0; g < 2; g++) {
        acc[4 + f][2 + g] = __builtin_amdgcn_mfma_f32_16x16x32_bf16(a1[f][0], b1[g][0], acc[4 + f][2 + g], 0, 0, 0);
        acc[4 + f][2 + g] = __builtin_amdgcn_mfma_f32_16x16x32_bf16(a1[f][1], b1[g][1], acc[4 + f][2 + g], 0, 0, 0);
      }
    __builtin_amdgcn_s_setprio(0);
    // ---- Q10: acc[4+f][g] += A1 . B0 (b0 kept live from phase 0) ----
    __builtin_amdgcn_s_setprio(1);
    #pragma unroll
    for (int f = 0; f < 4; f++)
      #pragma unroll
      for (int g = 0; g < 2; g++) {
        acc[4 + f][g] = __builtin_amdgcn_mfma_f32_16x16x32_bf16(a1[f][0], b0[g][0], acc[4 + f][g], 0, 0, 0);
        acc[4 + f][g] = __builtin_amdgcn_mfma_f32_16x16x32_bf16(a1[f][1], b0[g][1], acc[4 + f][g], 0, 0, 0);
      }
    __builtin_amdgcn_s_setprio(0);
  }
  // ---- epilogue ----
  const long cz = (long)z * cZs;
  #pragma unroll
  for (int i = 0; i < 8; i++) {
    const int row = m0 + wm * 128 + (i >> 2) * 64 + (i & 3) * 16 + lq * 4;
    #pragma unroll
    for (int j = 0; j < 4; j++) {
      const int col = n0 + wn * 64 + (j >> 1) * 32 + (j & 1) * 16 + lm;
      const float bv = bias ? bias[col] : 0.f;
      #pragma unroll
      for (int rr = 0; rr < 4; rr++) {
        float v = acc[i][j][rr] + bv;
        if (ACT == 1) v = silu(v);
        C[cz + (long)(row + rr) * ldc + col] = (bf16)v;
      }
    }
  }
}

// ---------------- bf16 MFMA GEMM 64x128 tile ----------------
// NORM=1 (qkv mode): after silu, 8-col-group rmsnorm for Q (x==0, qn, prescale) and
// K (x==1, kn); V (x==2) passthrough.
template <int ACT, int OUTBF, int ACC, int NORM>
__global__ __launch_bounds__(256) void gemm64(
    const bf16* __restrict__ A, int lda, long aZs,
    const bf16* __restrict__ Bt, int ldb, long bZs,
    const float* __restrict__ bias, int biasZs,
    void* __restrict__ Cv, int ldc, long cZs,
    int M, int N, int K,
    const float* __restrict__ qn, const float* __restrict__ kn) {
  __shared__ bf16 As[64 * 32];
  __shared__ bf16 Bs[128 * 32];
  int tid = threadIdx.x;
  int m0 = blockIdx.y * 64, n0 = blockIdx.x * 128;
  int z = blockIdx.z;
  const bf16* Ab = A + (long)z * aZs;
  const bf16* Bb = Bt + (long)z * bZs;
  f32x4 acc[4][2] = {};
  int wv = tid >> 6, lane = tid & 63;
  int lm = lane & 15, lq = lane >> 4;
  int wcol = wv * 32;
  const bf16* ag = Ab + (long)(m0 + (tid >> 2)) * lda + (tid & 3) * 8;
  const bf16* bg = Bb + (long)(n0 + (tid >> 2)) * ldb + (tid & 3) * 8;
  bf16* asd = As + tid * 8;
  bf16* bsd = Bs + tid * 8;
  for (int k0 = 0; k0 < K; k0 += 32) {
    gl16(ag + k0, asd);
    gl16(bg + k0, bsd);
    gl16(bg + k0 + 64L * ldb, bsd + 2048);
    __syncthreads();
    bf16x8 af[4], bfr[2];
    #pragma unroll
    for (int i = 0; i < 4; i++)
      af[i] = *(const bf16x8*)(As + (i * 16 + lm) * 32 + lq * 8);
    #pragma unroll
    for (int j = 0; j < 2; j++)
      bfr[j] = *(const bf16x8*)(Bs + (wcol + j * 16 + lm) * 32 + lq * 8);
    #pragma unroll
    for (int i = 0; i < 4; i++)
      #pragma unroll
      for (int j = 0; j < 2; j++)
        acc[i][j] = __builtin_amdgcn_mfma_f32_16x16x32_bf16(af[i], bfr[j], acc[i][j], 0, 0, 0);
    __syncthreads();
  }
  long cz = (long)z * cZs;
  const float* bz = bias ? bias + (long)z * biasZs : nullptr;
  if constexpr (NORM == 0) {
    #pragma unroll
    for (int i = 0; i < 4; i++) {
      int row = m0 + i * 16 + lq * 4;
      #pragma unroll
      for (int j = 0; j < 2; j++) {
        int col = n0 + wcol + j * 16 + lm;
        float bv = bz ? bz[col] : 0.f;
        #pragma unroll
        for (int r = 0; r < 4; r++) {
          float v = acc[i][j][r] + bv;
          long off = cz + (long)(row + r) * ldc + col;
          if (ACC) v += (float)((bf16*)Cv)[off];
          if (ACT == 1) v = silu(v);
          if (OUTBF) ((bf16*)Cv)[off] = (bf16)v;
          else       ((float*)Cv)[off] = v;
        }
      }
    }
  } else {
    int nsec = blockIdx.x;              // 0=Q, 1=K, 2=V
    bool don = nsec < 2;
    float wnv = 1.f;
    if (nsec == 0) wnv = qn[z * 8 + (lm & 7)] * QSCALE_E;
    else if (nsec == 1) wnv = kn[z * 8 + (lm & 7)];
    #pragma unroll
    for (int i = 0; i < 4; i++) {
      int row = m0 + i * 16 + lq * 4;
      #pragma unroll
      for (int j = 0; j < 2; j++) {
        int col = n0 + wcol + j * 16 + lm;
        float bv = bz ? bz[col] : 0.f;
        #pragma unroll
        for (int r = 0; r < 4; r++) {
          float v = acc[i][j][r] + bv;
          if (ACT == 1) v = silu(v);
          float s = v * v;
          s += __shfl_xor(s, 1);
          s += __shfl_xor(s, 2);
          s += __shfl_xor(s, 4);
          if (don) v = v * rsqrtf(s * 0.125f + EPS) * wnv;
          ((bf16*)Cv)[cz + (long)(row + r) * ldc + col] = (bf16)v;
        }
      }
    }
  }
}

// ---------------- embed + rmsnorm -> bf16 h ----------------
__global__ __launch_bounds__(256) void k_embed(const float* __restrict__ x,
    const float* __restrict__ emb, const float* __restrict__ pos,
    const float* __restrict__ nw, bf16* __restrict__ h) {
  __shared__ float red[4];
  int row = blockIdx.x;
  int l = row % Lq;
  int xi = (int)(x[row] * 255.f);
  xi = min(max(xi, 0), 255);
  const float* er = emb + (long)xi * WIDTH;
  const float* pr = pos + (long)l * WIDTH;
  int c0 = threadIdx.x * 4;
  float v[4]; float ss = 0.f;
  #pragma unroll
  for (int i = 0; i < 4; i++) { v[i] = er[c0 + i] + pr[c0 + i]; ss += v[i] * v[i]; }
  ss = blockReduceSum256(ss, red);
  float r = rsqrtf(ss / WIDTH + EPS);
  bf16* hr = h + (long)row * WIDTH;
  #pragma unroll
  for (int i = 0; i < 4; i++) hr[c0 + i] = (bf16)(v[i] * r * nw[c0 + i]);
}

// ---------------- mean over L, phase 1: 16 partials per b ----------------
__global__ void k_meanl_p(const bf16* __restrict__ h, float* __restrict__ part) {
  int lp = blockIdx.x, b = blockIdx.y, t = threadIdx.x;
  const bf16* p = h + ((long)b * Lq + (long)lp * 36) * WIDTH + t * 4;
  float a0 = 0, a1 = 0, a2 = 0, a3 = 0;
  for (int l = 0; l < 36; l++) {
    bf16x4 v = *(const bf16x4*)(p + (long)l * WIDTH);
    a0 += (float)v[0]; a1 += (float)v[1]; a2 += (float)v[2]; a3 += (float)v[3];
  }
  float* dst = part + ((long)b * 16 + lp) * WIDTH + t * 4;
  dst[0] = a0; dst[1] = a1; dst[2] = a2; dst[3] = a3;
}

// ---------------- SE phase 1 ----------------
__global__ __launch_bounds__(256) void k_se1(const float* __restrict__ part,
    const float* __restrict__ w1, const float* __restrict__ b1,
    float* __restrict__ t1) {
  __shared__ float sv[1024];
  __shared__ float red[256];
  int jb = blockIdx.x, b = blockIdx.y, t = threadIdx.x;
  for (int c = t; c < 1024; c += 256) {
    float a = 0.f;
    #pragma unroll
    for (int lp = 0; lp < 16; lp++) a += part[((long)b * 16 + lp) * 1024 + c];
    sv[c] = a * (1.f / 576.f);
  }
  __syncthreads();
  int j = t & 7, pt = t >> 3;
  int j0 = jb * 8;
  float acc = 0.f;
  int c0 = pt * 32;
  #pragma unroll 8
  for (int c = c0; c < c0 + 32; c++) acc += sv[c] * w1[c * 256 + j0 + j];
  red[t] = acc;
  __syncthreads();
  if (t < 8) {
    float a = b1[j0 + t];
    #pragma unroll
    for (int p = 0; p < 32; p++) a += red[p * 8 + t];
    t1[b * 256 + j0 + t] = silu(a);
  }
}

// ---------------- SE phase 2 ----------------
__global__ __launch_bounds__(256) void k_se2(const float* __restrict__ t1,
    const float* __restrict__ w2, const float* __restrict__ b2,
    float* __restrict__ s) {
  __shared__ float red[256];
  int jb = blockIdx.x, b = blockIdx.y, t = threadIdx.x;
  int j = t & 31, pt = t >> 5;
  int j0 = jb * 32;
  const float* tb = t1 + b * 256;
  float acc = 0.f;
  int c0 = pt * 32;
  #pragma unroll 8
  for (int c = c0; c < c0 + 32; c++) acc += tb[c] * w2[c * 1024 + j0 + j];
  red[t] = acc;
  __syncthreads();
  if (t < 32) {
    float a = b2[j0 + t];
    #pragma unroll
    for (int p = 0; p < 8; p++) a += red[p * 32 + t];
    s[b * 1024 + j0 + t] = 1.f / (1.f + __expf(-a));
  }
}

// ---------------- mix: h += rmsnorm(h*(s-1), mw) ----------------
__global__ __launch_bounds__(256) void k_mix_b(bf16* __restrict__ h,
    const float* __restrict__ s, const float* __restrict__ mw) {
  __shared__ float red[4];
  int row = blockIdx.x;
  int b = row / Lq;
  bf16* hr = h + (long)row * WIDTH;
  const float* sb = s + b * WIDTH;
  int c0 = threadIdx.x * 4;
  float hv[4], y[4]; float ss = 0.f;
  #pragma unroll
  for (int i = 0; i < 4; i++) {
    hv[i] = (float)hr[c0 + i];
    y[i] = hv[i] * (sb[c0 + i] - 1.f); ss += y[i] * y[i];
  }
  ss = blockReduceSum256(ss, red);
  float r = rsqrtf(ss / WIDTH + EPS);
  #pragma unroll
  for (int i = 0; i < 4; i++) hr[c0 + i] = (bf16)(hv[i] + y[i] * r * mw[c0 + i]);
}

// ---------------- h += rmsnorm(g, mw) ----------------
__global__ __launch_bounds__(256) void k_addnorm_b(bf16* __restrict__ h,
    const bf16* __restrict__ g, const float* __restrict__ mw) {
  __shared__ float red[4];
  int row = blockIdx.x;
  bf16* hr = h + (long)row * WIDTH;
  const bf16* gr = g + (long)row * WIDTH;
  int c0 = threadIdx.x * 4;
  float y[4]; float ss = 0.f;
  #pragma unroll
  for (int i = 0; i < 4; i++) { y[i] = (float)gr[c0 + i]; ss += y[i] * y[i]; }
  ss = blockReduceSum256(ss, red);
  float r = rsqrtf(ss / WIDTH + EPS);
  #pragma unroll
  for (int i = 0; i < 4; i++)
    hr[c0 + i] = (bf16)((float)hr[c0 + i] + y[i] * r * mw[c0 + i]);
}

// ---------------- h += rmsnorm(p0 + p1 + b2, mw)  (2-way K-split partials) --------
__global__ __launch_bounds__(256) void k_addnorm2(bf16* __restrict__ h,
    const bf16* __restrict__ p0, const bf16* __restrict__ p1,
    const float* __restrict__ b2, const float* __restrict__ mw) {
  __shared__ float red[4];
  int row = blockIdx.x;
  bf16* hr = h + (long)row * WIDTH;
  const bf16* g0 = p0 + (long)row * WIDTH;
  const bf16* g1 = p1 + (long)row * WIDTH;
  int c0 = threadIdx.x * 4;
  float y[4]; float ss = 0.f;
  #pragma unroll
  for (int i = 0; i < 4; i++) {
    y[i] = (float)g0[c0 + i] + (float)g1[c0 + i] + b2[c0 + i];
    ss += y[i] * y[i];
  }
  ss = blockReduceSum256(ss, red);
  float r = rsqrtf(ss / WIDTH + EPS);
  #pragma unroll
  for (int i = 0; i < 4; i++)
    hr[c0 + i] = (bf16)((float)hr[c0 + i] + y[i] * r * mw[c0 + i]);
}

// ---------------- h += rmsnorm(p0+p1+p2+p3 + b2, mw)  (4-way K-split) -------------
__global__ __launch_bounds__(256) void k_addnorm4(bf16* __restrict__ h,
    const bf16* __restrict__ parts, const float* __restrict__ b2,
    const float* __restrict__ mw) {
  __shared__ float red[4];
  int row = blockIdx.x;
  bf16* hr = h + (long)row * WIDTH;
  const bf16* g0 = parts + (long)row * WIDTH;
  int c0 = threadIdx.x * 4;
  float y[4]; float ss = 0.f;
  #pragma unroll
  for (int i = 0; i < 4; i++) {
    float a = b2[c0 + i];
    #pragma unroll
    for (int p = 0; p < 4; p++) a += (float)g0[(long)p * PSTRIDE + c0 + i];
    y[i] = a; ss += a * a;
  }
  ss = blockReduceSum256(ss, red);
  float r = rsqrtf(ss / WIDTH + EPS);
  #pragma unroll
  for (int i = 0; i < 4; i++)
    hr[c0 + i] = (bf16)((float)hr[c0 + i] + y[i] * r * mw[c0 + i]);
}

// ---------------- router + lambdas ----------------
__global__ __launch_bounds__(256) void k_router(const float* __restrict__ part,
    const float* __restrict__ rwgt, const float* __restrict__ rb,
    const float* __restrict__ lq1, const float* __restrict__ lk1,
    const float* __restrict__ lq2, const float* __restrict__ lk2,
    float* __restrict__ rw, float* __restrict__ lam) {
  __shared__ float sv[1024];
  __shared__ float red[256];
  __shared__ float lg[8];
  int b = blockIdx.x, t = threadIdx.x;
  for (int c = t; c < 1024; c += 256) {
    float a = 0.f;
    #pragma unroll
    for (int lp = 0; lp < 16; lp++) a += part[((long)b * 16 + lp) * 1024 + c];
    sv[c] = a * (1.f / 576.f);
  }
  __syncthreads();
  int j = t & 7, pt = t >> 3;
  float acc = 0.f;
  int c0 = pt * 32;
  #pragma unroll 8
  for (int c = c0; c < c0 + 32; c++) acc += sv[c] * rwgt[c * 8 + j];
  red[t] = acc;
  __syncthreads();
  if (t < 8) {
    float a = rb[t];
    for (int p = 0; p < 32; p++) a += red[p * 8 + t];
    lg[t] = a;
  }
  __syncthreads();
  if (t == 0) {
    float v[8]; bool sel[8];
    #pragma unroll
    for (int i = 0; i < 8; i++) { v[i] = lg[i]; sel[i] = false; }
    int idxs[4]; float vals[4];
    for (int s = 0; s < 4; s++) {
      int bi = -1; float bv = -1e30f;
      for (int i = 0; i < 8; i++) if (!sel[i] && v[i] > bv) { bv = v[i]; bi = i; }
      sel[bi] = true; idxs[s] = bi; vals[s] = bv;
    }
    float m = vals[0], den = 0.f, e[4];
    for (int s = 0; s < 4; s++) { e[s] = __expf(vals[s] - m); den += e[s]; }
    for (int i = 0; i < 8; i++) rw[b * 8 + i] = 0.f;
    for (int s = 0; s < 4; s++) rw[b * 8 + idxs[s]] = e[s] / den;
  }
  if (b == 0 && t >= 8 && t < 16) {
    int c = t - 8;
    float d1 = 0.f, d2 = 0.f;
    for (int i = 0; i < 8; i++) {
      d1 += lq1[c * 8 + i] * lk1[c * 8 + i];
      d2 += lq2[c * 8 + i] * lk2[c * 8 + i];
    }
    lam[c] = __expf(d1) - __expf(d2) + LAMINIT;
  }
}

// ---------------- MFMA causal differential attention (prenormed Q/K) --------------
// den on the MFMA pipe (ONES ones-vector trick). K staged via gl16 [576][16];
// V staged column-major Vt[16][584] (R3-verified layout). 512 threads = 8
// waves per block, grid (64,1,8): each (slice,head) staged ONCE (was twice
// with y=2), same per-wave pr map u = wv in [0,8): u<6 pair {u+2, 17-u};
// u>=6 triple {u-6, u+2, 17-u}. LDS 37376 B.
__global__ __launch_bounds__(512) void k_attn_mfma(
    const bf16* __restrict__ qkv, const float* __restrict__ lam,
    const float* __restrict__ hnw, bf16* __restrict__ dc) {
  __shared__ bf16 Ks[576 * 16];
  __shared__ bf16 Vt[16 * 584];
  int tid = threadIdx.x;
  int slice = blockIdx.x; int zc = slice >> 3, b = slice & 7;
  int head = blockIdx.z;
  const bf16* qkvb = qkv + ((long)zc * ROWS + (long)b * Lq) * 384;
  for (int i = tid; i < 1152; i += 512) {
    int row = i >> 1, hf = i & 1;
    gl16(qkvb + (long)row * 384 + 128 + head * 16 + hf * 8, Ks + i * 8);
  }
  for (int i = tid; i < 1152; i += 512) {
    int row = i >> 1, dh = i & 1;
    bf16x8 v = *(const bf16x8*)(qkvb + (long)row * 384 + 256 + head * 16 + dh * 8);
    #pragma unroll
    for (int j = 0; j < 8; j++) Vt[(dh * 8 + j) * 584 + row] = v[j];
  }
  __syncthreads();
  int wv = tid >> 6, lane = tid & 63;
  int lm = lane & 15, lq = lane >> 4;
  float lamv = lam[zc];
  float hwv[4];
  #pragma unroll
  for (int r = 0; r < 4; r++) hwv[r] = hnw[zc * 16 + lq * 4 + r] * (1.f - LAMINIT);
  const bf16 one = (bf16)1.0f;
  const bf16x4 ONES = {one, one, one, one};
  int u = wv;                           // 8 waves -> u in [0,8)
  int prA, prB, prC;
  if (u < 6) { prA = u + 2; prB = 17 - u; prC = -1; }
  else       { int v2 = u - 6; prA = v2; prB = 8 + v2; prC = 11 - v2; }
  for (int pi = 0; pi < 3; pi++) {
    int pr = (pi == 0) ? prA : (pi == 1) ? prB : prC;
    if (pr < 0) continue;
    bf16x8 bq0[2] = {{}, {}}, bq1[2] = {{}, {}};
    if (lq < 2) {
      #pragma unroll
      for (int tile = 0; tile < 2; tile++) {
        bf16x8 t8 = *(const bf16x8*)(
            qkvb + (long)(pr * 32 + tile * 16 + lm) * 384 + head * 16 + lq * 8);
        if (lq == 0) bq0[tile] = t8; else bq1[tile] = t8;
      }
    }
    f32x4 o[2][2] = {};
    f32x4 dacc[2][2] = {};
    for (int kc = 0; kc <= pr; kc++) {
      f32x4 sT[2][2][2] = {};
      #pragma unroll
      for (int t = 0; t < 2; t++) {
        bf16x8 aK = {};
        if (lq < 2) aK = *(const bf16x8*)(Ks + (kc * 32 + t * 16 + lm) * 16 + lq * 8);
        #pragma unroll
        for (int tile = 0; tile < 2; tile++) {
          sT[t][tile][0] = __builtin_amdgcn_mfma_f32_16x16x32_bf16(aK, bq0[tile], sT[t][tile][0], 0, 0, 0);
          sT[t][tile][1] = __builtin_amdgcn_mfma_f32_16x16x32_bf16(aK, bq1[tile], sT[t][tile][1], 0, 0, 0);
        }
      }
      bool diag = (kc == pr);
      #pragma unroll
      for (int t = 0; t < 2; t++) {
        bf16x4 aV = *(const bf16x4*)(Vt + lm * 584 + kc * 32 + t * 16 + lq * 4);
        #pragma unroll
        for (int tile = 0; tile < 2; tile++) {
          if (diag && tile == 0 && t == 1) continue;
          bool masked = diag && (tile == t);
          #pragma unroll
          for (int h2 = 0; h2 < 2; h2++) {
            bf16x4 pb;
            #pragma unroll
            for (int r = 0; r < 4; r++) {
              float ev = fexp2(sT[t][tile][h2][r]);
              if (masked && (lq * 4 + r > lm)) ev = 0.f;
              pb[r] = (bf16)ev;
            }
            dacc[tile][h2] = mfma16(ONES, pb, dacc[tile][h2]);
            o[tile][h2] = mfma16(aV, pb, o[tile][h2]);
          }
        }
      }
    }
    #pragma unroll
    for (int tile = 0; tile < 2; tile++) {
      float inv1 = 1.f / dacc[tile][0][0];
      float inv2 = lamv / dacc[tile][1][0];
      float dff[4]; float ss = 0.f;
      #pragma unroll
      for (int r = 0; r < 4; r++) {
        dff[r] = o[tile][0][r] * inv1 - o[tile][1][r] * inv2;
        ss += dff[r] * dff[r];
      }
      ss += __shfl_xor(ss, 16);
      ss += __shfl_xor(ss, 32);
      float rr = rsqrtf(ss * 0.0625f + EPS);
      bf16x4 outp;
      #pragma unroll
      for (int r = 0; r < 4; r++) outp[r] = (bf16)(dff[r] * rr * hwv[r]);
      long rowg = (long)zc * ROWS + (long)b * Lq + pr * 32 + tile * 16 + lm;
      *(bf16x4*)(dc + rowg * 128 + head * 16 + lq * 4) = outp;
    }
  }
}

// ---------------- seg + pool fused: 16 bins, 1-wave blocks ----------------
__global__ __launch_bounds__(64) void k_segpool(const bf16* __restrict__ h,
    const bf16* __restrict__ op, const float* __restrict__ segw,
    const float* __restrict__ rw, float* __restrict__ part) {
  int lp = blockIdx.x, b = blockIdx.y, ch = blockIdx.z;
  int t = threadIdx.x;
  int c0 = t * 2;
  float w0 = segw[ch * 128 + c0], w1 = segw[ch * 128 + c0 + 1];
  float rwv = rw[b * 8 + ch];
  float a0 = 0.f, a1 = 0.f;
  for (int l = 0; l < 36; l++) {
    int row = b * Lq + lp * 36 + l;
    const bf16* oprow = op + (long)ch * ROWS * CW + (long)row * CW;
    bf16x2 yv = *(const bf16x2*)(oprow + c0);
    float y0 = (float)yv[0], y1 = (float)yv[1];
    float ss = y0 * y0 + y1 * y1;
    #pragma unroll
    for (int m = 1; m < 64; m <<= 1) ss += __shfl_xor(ss, m);
    float r = rsqrtf(ss * (1.f / 128.f) + EPS);
    bf16x2 hv = *(const bf16x2*)(h + (long)row * WIDTH + ch * 128 + c0);
    a0 += ((float)hv[0] + y0 * r * w0) * rwv;
    a1 += ((float)hv[1] + y1 * r * w1) * rwv;
  }
  float* dst = part + ((long)b * 16 + lp) * 1024 + ch * 128 + c0;
  dst[0] = a0; dst[1] = a1;
}

// ---------------- head (reads 16 pool partials) ----------------
__global__ __launch_bounds__(256) void k_head(const float* __restrict__ part,
    const float* __restrict__ hw, const float* __restrict__ hb, float* __restrict__ out) {
  __shared__ float pool[1024];
  __shared__ float red[256];
  int b = blockIdx.x, t = threadIdx.x;
  for (int c = t; c < 1024; c += 256) {
    float a = 0.f;
    #pragma unroll
    for (int lp = 0; lp < 16; lp++) a += part[((long)b * 16 + lp) * 1024 + c];
    pool[c] = a * (1.f / 576.f);
  }
  __syncthreads();
  int j = t & 15, pt = t >> 4;
  float acc = 0.f;
  if (j < 10)
    for (int c = pt * 64; c < pt * 64 + 64; c++)
      acc += pool[c] * hw[c * 10 + j];
  red[t] = acc;
  __syncthreads();
  if (t < 10) {
    float a = hb[t];
    for (int p = 0; p < 16; p++) a += red[p * 16 + t];
    out[b * 10 + t] = a;
  }
}

// ---------------- launcher ----------------
extern "C" void kernel_launch(void* const* d_in, const int* in_sizes, int n_in,
                              void* d_out, int out_size, void* d_ws, size_t ws_size,
                              hipStream_t stream) {
  const float* x          = (const float*)d_in[0];
  const float* pixel_embed= (const float*)d_in[2];
  const float* freq_h     = (const float*)d_in[3];
  const float* freq_w     = (const float*)d_in[4];
  const float* phase_h    = (const float*)d_in[5];
  const float* phase_w    = (const float*)d_in[6];
  const float* pos_proj_w = (const float*)d_in[7];
  const float* pos_proj_b = (const float*)d_in[8];
  const float* embed_norm = (const float*)d_in[9];
  const float* se_w1      = (const float*)d_in[10];
  const float* se_b1      = (const float*)d_in[11];
  const float* se_w2      = (const float*)d_in[12];
  const float* se_b2      = (const float*)d_in[13];
  const float* mix_norm   = (const float*)d_in[14];
  const float* mlp_w1     = (const float*)d_in[15];
  const float* mlp_b1     = (const float*)d_in[16];
  const float* mlp_w2     = (const float*)d_in[17];
  const float* mlp_b2     = (const float*)d_in[18];
  const float* mlp_norm   = (const float*)d_in[19];
  const float* router_w   = (const float*)d_in[20];
  const float* router_b   = (const float*)d_in[21];
  const float* qkv_w      = (const float*)d_in[22];
  const float* qkv_b      = (const float*)d_in[23];
  const float* q_norm_w   = (const float*)d_in[24];
  const float* k_norm_w   = (const float*)d_in[25];
  const float* head_norm_w= (const float*)d_in[26];
  const float* lam_q1     = (const float*)d_in[27];
  const float* lam_k1     = (const float*)d_in[28];
  const float* lam_q2     = (const float*)d_in[29];
  const float* lam_k2     = (const float*)d_in[30];
  const float* out_w      = (const float*)d_in[31];
  const float* out_b      = (const float*)d_in[32];
  const float* seg_norm_w = (const float*)d_in[33];
  const float* head_w     = (const float*)d_in[34];
  const float* head_b     = (const float*)d_in[35];

  char* W = (char*)d_ws;
  bf16*  HB    = (bf16*)(W + B_HB);
  bf16*  G2B   = (bf16*)(W + B_G2B);
  float* POS   = (float*)(W + B_G2B);      // POS lives in G2B region (dead until MLP)
  bf16*  ENCB  = (bf16*)(W + B_ENCB);
  bf16*  POSWT = (bf16*)(W + B_POSWT);
  bf16*  QKVWT = (bf16*)(W + B_QKVWT);
  bf16*  OWT   = (bf16*)(W + B_OWT);
  float* SE    = (float*)(W + B_SE);
  float* T1    = (float*)(W + B_T1);
  float* MP    = (float*)(W + B_MP);
  float* RW    = (float*)(W + B_RW);
  float* LAM   = (float*)(W + B_LAM);
  char*  P     = W + B_POOL;
  bf16*  W1T   = (bf16*)P;
  bf16*  W2T   = (bf16*)(P + 8388608);
  bf16*  HID   = (bf16*)(P + 16777216);
  bf16*  PARTS = (bf16*)(P + 16777216 + 37748736);   // after full-width HID
  bf16*  QKV   = (bf16*)P;
  bf16*  DC    = (bf16*)(P + 28311552);
  float* out   = (float*)d_out;
  const int tier = (ws_size >= WS_BIG3) ? 3 : (ws_size >= WS_BIG2) ? 2
                 : (ws_size >= WS_BIG) ? 1 : 0;

  // 0. all weight casts in one dispatch
  k_tcast_all<<<8832, 256, 0, stream>>>(mlp_w1, mlp_w2, pos_proj_w, qkv_w, out_w,
                                        W1T, W2T, POSWT, QKVWT, OWT);
  // 1. positional encoding + projection (POS f32 in G2B region)
  k_enc_b<<<288, 256, 0, stream>>>(freq_h, freq_w, phase_h, phase_w, ENCB);
  gemm64<0, 0, 0, 0><<<dim3(8, 10, 1), 256, 0, stream>>>(
      ENCB, 128, 0, POSWT, 128, 0, pos_proj_b, 0, POS, 1024, 0, 640, 1024, 128,
      nullptr, nullptr);
  // 2. embed + rmsnorm -> bf16 h
  k_embed<<<ROWS, 256, 0, stream>>>(x, pixel_embed, POS, embed_norm, HB);
  // 3. SE gate
  k_meanl_p<<<dim3(16, 8), 256, 0, stream>>>(HB, MP);
  k_se1<<<dim3(32, 8), 256, 0, stream>>>(MP, se_w1, se_b1, T1);
  k_se2<<<dim3(32, 8), 256, 0, stream>>>(T1, se_w2, se_b2, SE);
  k_mix_b<<<ROWS, 256, 0, stream>>>(HB, SE, mix_norm);
  // 4. MLP
  if (tier >= 1) {
    // gemm1 main: 256^2 8-wave kernel, rows 0..4095 (16m x 16n = 256 blocks,
    // exactly one block-wave over 256 CUs); 128^2 tail covers rows 4096..4607.
    gemm256<1><<<256, 512, 0, stream>>>(
        HB, 1024, 0, W1T, 1024, 0, mlp_b1,
        HID, 4096, 0, 16, 16, 1024);
    gemm_bt<1, 1, 0><<<dim3(32, 4, 1), 256, 0, stream>>>(
        HB + 4096L * 1024, 1024, 0, W1T, 1024, 0, mlp_b1, 0,
        HID + 4096L * 4096, 4096, 0, 512, 4096, 1024);
    if (tier == 3) {
      // gemm2 main: 4-way K-split, 16m x 4n x 4z = 256 blocks; tail 128^2.
      gemm256<0><<<256, 512, 0, stream>>>(
          HID, 4096, 1024, W2T, 4096, 1024, nullptr,
          PARTS, 1024, PSTRIDE, 16, 4, 1024);
      gemm_bt<0, 1, 0><<<dim3(8, 4, 4), 256, 0, stream>>>(
          HID + 4096L * 4096, 4096, 1024, W2T, 4096, 1024, nullptr, 0,
          PARTS + 4096L * 1024, 1024, PSTRIDE, 512, 1024, 1024);
      k_addnorm4<<<ROWS, 256, 0, stream>>>(HB, PARTS, mlp_b2, mlp_norm);
    } else if (tier == 2) {
      // gemm2: 2-way K-split, XCD-pinned, partials in G2B + PARTS[0]
      gemm_bt<0, 1, 2><<<576, 256, 0, stream>>>(
          HID, 4096, 2048, W2T, 4096, 2048, nullptr, 0,
          G2B, 1024, (long)(PARTS - G2B), 4608, 1024, 2048);
      k_addnorm2<<<ROWS, 256, 0, stream>>>(HB, G2B, PARTS, mlp_b2, mlp_norm);
    } else {
      gemm64<0, 1, 0, 0><<<dim3(8, 72, 1), 256, 0, stream>>>(
          HID, 4096, 0, W2T, 4096, 0, mlp_b2, 0,
          G2B, 1024, 0, 4608, 1024, 4096, nullptr, nullptr);
      k_addnorm_b<<<ROWS, 256, 0, stream>>>(HB, G2B, mlp_norm);
    }
  } else {
    gemm_bt<1, 1, 0><<<dim3(16, 36, 1), 256, 0, stream>>>(
        HB, 1024, 0, W1T, 1024, 0, mlp_b1, 0, HID, 2048, 0, 4608, 2048, 1024);
    gemm64<0, 1, 0, 0><<<dim3(8, 72, 1), 256, 0, stream>>>(
        HID, 2048, 0, W2T, 4096, 0, mlp_b2, 0, G2B, 1024, 0, 4608, 1024, 2048,
        nullptr, nullptr);
    gemm_bt<1, 1, 0><<<dim3(16, 36, 1), 256, 0, stream>>>(
        HB, 1024, 0, W1T + 2048L * 1024, 1024, 0, mlp_b1 + 2048, 0, HID, 2048, 0,
        4608, 2048, 1024);
    gemm64<0, 1, 1, 0><<<dim3(8, 72, 1), 256, 0, stream>>>(
        HID, 2048, 0, W2T + 2048, 4096, 0, nullptr, 0, G2B, 1024, 0,
        4608, 1024, 2048, nullptr, nullptr);
    k_addnorm_b<<<ROWS, 256, 0, stream>>>(HB, G2B, mlp_norm);
  }
  // 5. router + lambdas
  k_meanl_p<<<dim3(16, 8), 256, 0, stream>>>(HB, MP);
  k_router<<<8, 256, 0, stream>>>(MP, router_w, router_b,
                                  lam_q1, lam_k1, lam_q2, lam_k2, RW, LAM);
  // 6. qkv-proj with fused silu + Q/K rmsnorm (+ Q prescale) in epilogue
  gemm64<1, 1, 0, 1><<<dim3(3, 72, 8), 256, 0, stream>>>(
      HB, 1024, CW, QKVWT, 128, 384 * 128, qkv_b, 384,
      QKV, 384, (long)ROWS * 384, ROWS, 384, 128, q_norm_w, k_norm_w);
  // 7. attention (prenormed), out-proj in-place on DC
  k_attn_mfma<<<dim3(64, 1, 8), 512, 0, stream>>>(QKV, LAM, head_norm_w, DC);
  gemm64<1, 1, 0, 0><<<dim3(1, 72, 8), 256, 0, stream>>>(
      DC, 128, (long)ROWS * 128, OWT, 128, 128 * 128, out_b, 128,
      DC, 128, (long)ROWS * 128, ROWS, 128, 128, nullptr, nullptr);
  // 8. seg + pool fused -> 16 partials; head folds the final reduce
  k_segpool<<<dim3(16, 8, 8), 64, 0, stream>>>(HB, DC, seg_norm_w, RW, MP);
  k_head<<<8, 256, 0, stream>>>(MP, head_w, head_b, out);
}

// Round 7
// 412.339 us; speedup vs baseline: 1.0794x; 1.0411x over previous
//
#include <hip/hip_runtime.h>
#include <math.h>

typedef __bf16 bf16;
typedef __bf16 bf16x8 __attribute__((ext_vector_type(8)));
typedef __bf16 bf16x4 __attribute__((ext_vector_type(4)));
typedef __bf16 bf16x2 __attribute__((ext_vector_type(2)));
typedef float f32x4 __attribute__((ext_vector_type(4)));
typedef short s16x4 __attribute__((ext_vector_type(4)));

// ---------------- constants ----------------
constexpr int Bsz = 8, HIMG = 24, WIMG = 24;
constexpr int Lq = 576;
constexpr int WIDTH = 1024, NCH = 8, CW = 128;
constexpr int NHEADS = 8, HD = 16, HALF = 8;
constexpr float EPS = 1e-6f;
constexpr float LAMINIT = 0.2f;
// 1/sqrt(8) * log2(e): scores exit MFMA in log2 domain -> v_exp_f32 directly
constexpr float QSCALE_E = 0.35355339059327373f * 1.4426950408889634f;
constexpr int ROWS = Bsz * Lq;              // 4608
constexpr long PSTRIDE = 4718592;           // bf16 elements per MLP partial buffer

__device__ __forceinline__ float fexp2(float x) {
#if __has_builtin(__builtin_amdgcn_exp2f)
  return __builtin_amdgcn_exp2f(x);
#else
  return exp2f(x);
#endif
}

// ---------------- workspace byte offsets ----------------
constexpr size_t B_HB    = 0;                        // bf16 h [4608][1024]
constexpr size_t B_G2B   = B_HB    + 9437184;        // bf16 g2/partial0; POS f32 early
constexpr size_t B_ENCB  = B_G2B   + 9437184;        // bf16 enc [640][128]
constexpr size_t B_POSWT = B_ENCB  + 163840;         // bf16 [1024][128]
constexpr size_t B_QKVWT = B_POSWT + 262144;         // bf16 [8][384][128]
constexpr size_t B_OWT   = B_QKVWT + 786432;         // bf16 [8][128][128]
constexpr size_t B_SE    = B_OWT   + 262144;         // f32 [8][1024]
constexpr size_t B_T1    = B_SE    + 32768;          // f32 [8][256]
constexpr size_t B_MP    = B_T1    + 8192;           // f32 [8][16][1024]
constexpr size_t B_RW    = B_MP    + 524288;         // f32 [64]
constexpr size_t B_LAM   = B_RW    + 256;            // f32 [8]
constexpr size_t B_POOL  = B_LAM   + 256;            // = 20914688; phase-shared pool
// pool (MLP small): W1T 8388608 | W2T 8388608 | HID 18874368            (58.7 MB)
// pool (MLP big):   W1T 8388608 | W2T 8388608 | HID 37748736            (75.4 MB)
// pool (MLP big2):  ... + PART1 bf16 9437184 after HID                  (84.9 MB)
// pool (MLP big3):  ... + PARTS bf16 4x9437184 after HID                (113.2 MB)
// pool (chan):      QKV 28311552 | DC 9437184 (out-proj IN-PLACE on DC) (58.7 MB)
constexpr size_t WS_BIG  = B_POOL + 8388608 + 8388608 + 37748736;     // 75440640
constexpr size_t WS_BIG2 = WS_BIG + 9437184;                          // 84877824
constexpr size_t WS_BIG3 = WS_BIG + 4 * 9437184;                      // 113189376

// ---------------- helpers ----------------
__device__ __forceinline__ float blockReduceSum256(float v, float* red) {
  #pragma unroll
  for (int off = 32; off; off >>= 1) v += __shfl_down(v, off, 64);
  int lane = threadIdx.x & 63, wid = threadIdx.x >> 6;
  if (lane == 0) red[wid] = v;
  __syncthreads();
  float total = 0.f;
  #pragma unroll
  for (int i = 0; i < 4; i++) total += red[i];
  return total;
}
__device__ __forceinline__ float silu(float x) { return x / (1.f + __expf(-x)); }

__device__ __forceinline__ void gl16(const bf16* g, bf16* l) {
  __builtin_amdgcn_global_load_lds(
      (const __attribute__((address_space(1))) void*)g,
      (__attribute__((address_space(3))) void*)l, 16, 0, 0);
}

// v_mfma_f32_16x16x16_bf16 wrapper (A,B = 4 bf16/lane; k = quad*4+j)
__device__ __forceinline__ f32x4 mfma16(bf16x4 a, bf16x4 b, f32x4 c) {
#if __has_builtin(__builtin_amdgcn_mfma_f32_16x16x16bf16_1k)
  union { bf16x4 h; s16x4 s; } ua, ub;
  ua.h = a; ub.h = b;
  return __builtin_amdgcn_mfma_f32_16x16x16bf16_1k(ua.s, ub.s, c, 0, 0, 0);
#else
  f32x4 d = c;
  asm volatile("v_mfma_f32_16x16x16_bf16 %0, %1, %2, %0"
               : "+v"(d) : "v"(a), "v"(b));
  return d;
#endif
}

// ---------------- batched cast+transpose of ALL weights, one dispatch -------------
__device__ __forceinline__ void tcast_tile(const float* __restrict__ W,
    bf16* __restrict__ Wt, int K, int N, long zo, int bx, int by) {
  __shared__ float t[32][33];
  int n0 = bx * 32, k0 = by * 32;
  int tid = threadIdx.x;
  int r = tid >> 3, c4 = (tid & 7) * 4;
  const float4 v = *(const float4*)(W + zo + (long)(k0 + r) * N + n0 + c4);
  t[c4 + 0][r] = v.x; t[c4 + 1][r] = v.y; t[c4 + 2][r] = v.z; t[c4 + 3][r] = v.w;
  __syncthreads();
  bf16* dst = Wt + zo + (long)(n0 + r) * K + k0 + c4;
  bf16x4 o4;
  o4[0] = (bf16)t[r][c4 + 0]; o4[1] = (bf16)t[r][c4 + 1];
  o4[2] = (bf16)t[r][c4 + 2]; o4[3] = (bf16)t[r][c4 + 3];
  *(bf16x4*)dst = o4;
}

__global__ __launch_bounds__(256) void k_tcast_all(
    const float* __restrict__ w1, const float* __restrict__ w2,
    const float* __restrict__ posw, const float* __restrict__ qkvw,
    const float* __restrict__ outw,
    bf16* __restrict__ W1T, bf16* __restrict__ W2T, bf16* __restrict__ POSWT,
    bf16* __restrict__ QKVWT, bf16* __restrict__ OWT) {
  int bid = blockIdx.x;
  if (bid < 4096) {
    tcast_tile(w1, W1T, 1024, 4096, 0, bid % 128, bid / 128);
  } else if (bid < 8192) {
    int t = bid - 4096;
    tcast_tile(w2, W2T, 4096, 1024, 0, t % 32, t / 32);
  } else if (bid < 8320) {
    int t = bid - 8192;
    tcast_tile(posw, POSWT, 128, 1024, 0, t % 32, t / 32);
  } else if (bid < 8704) {
    int t = bid - 8320;
    int z = t / 48; t -= z * 48;
    tcast_tile(qkvw, QKVWT, 128, 384, (long)z * 49152, t % 12, t / 12);
  } else {
    int t = bid - 8704;
    int z = t / 16; t -= z * 16;
    tcast_tile(outw, OWT, 128, 128, (long)z * 16384, t % 4, t / 4);
  }
}

// ---------------- positional encoding (bf16 out) ----------------
__global__ void k_enc_b(const float* __restrict__ fh, const float* __restrict__ fw,
                        const float* __restrict__ ph, const float* __restrict__ pw,
                        bf16* __restrict__ enc) {
  int idx = blockIdx.x * blockDim.x + threadIdx.x;
  if (idx >= Lq * 128) return;
  int l = idx >> 7, c = idx & 127;
  int hh = l / WIMG, ww = l % WIMG;
  float v;
  if (c < 64) {
    int f = c & 31;
    float fr = log1pf(__expf(fh[f])) * 10.f;
    float a = (hh / (float)HIMG) * fr + ph[f];
    v = (c < 32) ? sinf(a) : cosf(a);
  } else {
    int f = c & 31;
    float fr = log1pf(__expf(fw[f])) * 10.f;
    float a = (ww / (float)WIMG) * fr + pw[f];
    v = (c < 96) ? sinf(a) : cosf(a);
  }
  enc[idx] = (bf16)v;
}

// ---------------- bf16 MFMA GEMM 128x128 ----------------
// SWZ=0: 3D grid (x=n, y=m, z).  SWZ=1 (gemm1): 1D grid 1152; XCD-pinned groups
// (m, n-half): all 16 n-tiles of a group share lid%8 -> same XCD L2 serves A-panel.
// SWZ=2 (gemm2 K-split): 1D grid 8*G; group G=(m,z) owns its 8 n-tiles on one XCD.
template <int ACT, int OUTBF, int SWZ>
__global__ __launch_bounds__(256) void gemm_bt(
    const bf16* __restrict__ A, int lda, long aZs,
    const bf16* __restrict__ Bt, int ldb, long bZs,
    const float* __restrict__ bias, int biasZs,
    void* __restrict__ Cv, int ldc, long cZs,
    int M, int N, int K) {
  __shared__ bf16 As[128 * 32];
  __shared__ bf16 Bs[128 * 32];
  int tid = threadIdx.x;
  int m0, n0, z;
  if constexpr (SWZ == 0) {
    m0 = blockIdx.y * 128; n0 = blockIdx.x * 128; z = blockIdx.z;
  } else if constexpr (SWZ == 1) {
    int lid = blockIdx.x;
    int xcd = lid & 7, idx = lid >> 3;
    int j = idx & 15, G = xcd + 8 * (idx >> 4);   // G in [0,72)
    m0 = (G % 36) * 128; n0 = ((G / 36) * 16 + j) * 128; z = 0;
  } else {
    int lid = blockIdx.x;
    int xcd = lid & 7, idx = lid >> 3;
    int n = idx & 7, G = xcd + 8 * (idx >> 3);    // G in [0, grid/8)
    m0 = (G % 36) * 128; n0 = n * 128; z = G / 36;
  }
  const bf16* Ab = A + (long)z * aZs;
  const bf16* Bb = Bt + (long)z * bZs;
  f32x4 acc[4][4] = {};
  int wv = tid >> 6, lane = tid & 63;
  int wrow = (wv >> 1) * 64, wcol = (wv & 1) * 64;
  int lm = lane & 15, lq = lane >> 4;
  const bf16* ag = Ab + (long)(m0 + (tid >> 2)) * lda + (tid & 3) * 8;
  const bf16* bg = Bb + (long)(n0 + (tid >> 2)) * ldb + (tid & 3) * 8;
  bf16* asd = As + tid * 8;
  bf16* bsd = Bs + tid * 8;
  for (int k0 = 0; k0 < K; k0 += 32) {
    gl16(ag + k0, asd);
    gl16(ag + k0 + 64L * lda, asd + 2048);
    gl16(bg + k0, bsd);
    gl16(bg + k0 + 64L * ldb, bsd + 2048);
    __syncthreads();
    bf16x8 af[4], bfr[4];
    #pragma unroll
    for (int i = 0; i < 4; i++) {
      af[i]  = *(const bf16x8*)(As + (wrow + i * 16 + lm) * 32 + lq * 8);
      bfr[i] = *(const bf16x8*)(Bs + (wcol + i * 16 + lm) * 32 + lq * 8);
    }
    #pragma unroll
    for (int i = 0; i < 4; i++)
      #pragma unroll
      for (int j = 0; j < 4; j++)
        acc[i][j] = __builtin_amdgcn_mfma_f32_16x16x32_bf16(af[i], bfr[j], acc[i][j], 0, 0, 0);
    __syncthreads();
  }
  long cz = (long)z * cZs;
  const float* bz = bias ? bias + (long)z * biasZs : nullptr;
  #pragma unroll
  for (int i = 0; i < 4; i++) {
    int row = m0 + wrow + i * 16 + lq * 4;
    #pragma unroll
    for (int j = 0; j < 4; j++) {
      int col = n0 + wcol + j * 16 + lm;
      float bv = bz ? bz[col] : 0.f;
      #pragma unroll
      for (int r = 0; r < 4; r++) {
        float v = acc[i][j][r] + bv;
        if (ACT == 1) v = silu(v);
        long off = cz + (long)(row + r) * ldc + col;
        if (OUTBF) ((bf16*)Cv)[off] = (bf16)v;
        else       ((float*)Cv)[off] = v;
      }
    }
  }
}

// ---------------- 256x256 8-wave free-run MFMA GEMM ----------------
// 256^2 tile, BK=64, 512 threads = 8 waves (2M x 4N), per-wave output 128x64
// (acc[8][4] f32x4), LDS 128 KiB = 2 buffers x (A 256x64 + B 256x64) bf16.
// Schedule: ONE __syncthreads per K-tile (its vmcnt(0)+barrier both drains the
// stage issued a full iteration earlier and hands over the double buffers).
// NO inner barriers: waves slip freely, so one wave's ds_reads overlap another
// wave's MFMAs. setprio(1) around each MFMA cluster; b0 kept live across iter.
// Next-tile stage gl16s are spread 2-per-cluster to smooth LDS port sharing.
// LDS swizzle: slot ^= (row&7) within each 128B row; applied on the global
// source (LDS dest linear, required by gl16) and on the ds_read address.
template <int ACT>
__global__ __launch_bounds__(512) void gemm256(
    const bf16* __restrict__ A, int lda, long aZs,
    const bf16* __restrict__ Bt, int ldb, long bZs,
    const float* __restrict__ bias,
    bf16* __restrict__ C, int ldc, long cZs,
    int Mtiles, int Ntiles, int K) {
  __shared__ bf16 LDS[65536];   // [buf:2][mat:2][half:2][128][64] bf16 = 128 KiB
  const int tid = threadIdx.x;
  // XCD-aware bijective swizzle (gridDim.x % 8 == 0 in all launches here)
  const int cpx = gridDim.x >> 3;
  const int wg = (blockIdx.x & 7) * cpx + (blockIdx.x >> 3);
  const int per_z = Mtiles * Ntiles;
  const int z = wg / per_z, rwg = wg % per_z;
  const int m0 = (rwg / Ntiles) * 256, n0 = (rwg % Ntiles) * 256;
  const bf16* Ab = A + (long)z * aZs;
  const bf16* Bb = Bt + (long)z * bZs;
  // --- staging geometry: 2 x 16B chunks/thread per 128x64 half-tile ---
  const int c0 = tid, c1 = tid + 512;
  const int sr0 = c0 >> 3, sc0 = ((c0 & 7) ^ (sr0 & 7)) * 8;  // pre-swizzled src col
  const int sr1 = c1 >> 3, sc1 = ((c1 & 7) ^ (sr1 & 7)) * 8;
  const long a00 = (long)(m0 + sr0) * lda + sc0;
  const long a01 = (long)(m0 + sr1) * lda + sc1;
  const long a10 = (long)(m0 + 128 + sr0) * lda + sc0;
  const long a11 = (long)(m0 + 128 + sr1) * lda + sc1;
  const long b00 = (long)(n0 + sr0) * ldb + sc0;
  const long b01 = (long)(n0 + sr1) * ldb + sc1;
  const long b10 = (long)(n0 + 128 + sr0) * ldb + sc0;
  const long b11 = (long)(n0 + 128 + sr1) * ldb + sc1;
  const int d0 = c0 * 8, d1 = c1 * 8;                 // linear LDS dest (elems)
  // --- wave geometry: 8 waves = 2M x 4N; per-wave output 128 x 64 ---
  const int wv = tid >> 6, lane = tid & 63;
  const int wm = wv >> 2, wn = wv & 3;
  const int lm = lane & 15, lq = lane >> 4;
  const int sw = lm & 7;                              // row&7 read-side XOR
  const int abase = wm * 8192;                        // wave's A half
  const int bbase = 16384 + (wn >> 1) * 8192;         // wave's B half
  const int brow0 = (wn & 1) * 64;                    // wave's rows within B half
  const int kq0 = (lq ^ sw) * 8;                      // swizzled slot, ks=0
  const int kq1 = ((4 + lq) ^ sw) * 8;                // swizzled slot, ks=1
  f32x4 acc[8][4] = {};
  const int NT = K >> 6;
  {
    const bf16* Ak = Ab;
    const bf16* Bk = Bb;
    bf16* L = LDS;
    gl16(Ak + a00, L + d0);         gl16(Ak + a01, L + d1);
    gl16(Ak + a10, L + 8192 + d0);  gl16(Ak + a11, L + 8192 + d1);
    gl16(Bk + b00, L + 16384 + d0); gl16(Bk + b01, L + 16384 + d1);
    gl16(Bk + b10, L + 24576 + d0); gl16(Bk + b11, L + 24576 + d1);
  }
  for (int s = 0; s < NT; ++s) {
    __syncthreads();   // vmcnt(0)+barrier: stage(s) landed; buffers handed over
    const bool more = (s + 1 < NT);
    const bf16* Ak = Ab + (s + 1) * 64;
    const bf16* Bk = Bb + (s + 1) * 64;
    bf16* L = LDS + ((s + 1) & 1) * 32768;
    if (more) { gl16(Ak + a00, L + d0); gl16(Ak + a01, L + d1); }
    const int bb = (s & 1) * 32768;
    const bf16* La = LDS + bb + abase + lm * 64;
    const bf16* Lb = LDS + bb + bbase + (brow0 + lm) * 64;
    bf16x8 a0[4][2], a1[4][2], b0[2][2], b1[2][2];
    #pragma unroll
    for (int f = 0; f < 4; f++) {
      a0[f][0] = *(const bf16x8*)(La + f * 1024 + kq0);
      a0[f][1] = *(const bf16x8*)(La + f * 1024 + kq1);
    }
    #pragma unroll
    for (int g = 0; g < 2; g++) {
      b0[g][0] = *(const bf16x8*)(Lb + g * 1024 + kq0);
      b0[g][1] = *(const bf16x8*)(Lb + g * 1024 + kq1);
    }
    // ---- Q00: acc[f][g] += A0 . B0 ----
    __builtin_amdgcn_s_setprio(1);
    #pragma unroll
    for (int f = 0; f < 4; f++)
      #pragma unroll
      for (int g = 0; g < 2; g++) {
        acc[f][g] = __builtin_amdgcn_mfma_f32_16x16x32_bf16(a0[f][0], b0[g][0], acc[f][g], 0, 0, 0);
        acc[f][g] = __builtin_amdgcn_mfma_f32_16x16x32_bf16(a0[f][1], b0[g][1], acc[f][g], 0, 0, 0);
      }
    __builtin_amdgcn_s_setprio(0);
    if (more) { gl16(Ak + a10, L + 8192 + d0); gl16(Ak + a11, L + 8192 + d1); }
    #pragma unroll
    for (int g = 0; g < 2; g++) {
      b1[g][0] = *(const bf16x8*)(Lb + 2048 + g * 1024 + kq0);
      b1[g][1] = *(const bf16x8*)(Lb + 2048 + g * 1024 + kq1);
    }
    // ---- Q01: acc[f][2+g] += A0 . B1 ----
    __builtin_amdgcn_s_setprio(1);
    #pragma unroll
    for (int f = 0; f < 4; f++)
      #pragma unroll
      for (int g = 0; g < 2; g++) {
        acc[f][2 + g] = __builtin_amdgcn_mfma_f32_16x16x32_bf16(a0[f][0], b1[g][0], acc[f][2 + g], 0, 0, 0);
        acc[f][2 + g] = __builtin_amdgcn_mfma_f32_16x16x32_bf16(a0[f][1], b1[g][1], acc[f][2 + g], 0, 0, 0);
      }
    __builtin_amdgcn_s_setprio(0);
    if (more) { gl16(Bk + b00, L + 16384 + d0); gl16(Bk + b01, L + 16384 + d1); }
    #pragma unroll
    for (int f = 0; f < 4; f++) {
      a1[f][0] = *(const bf16x8*)(La + 4096 + f * 1024 + kq0);
      a1[f][1] = *(const bf16x8*)(La + 4096 + f * 1024 + kq1);
    }
    // ---- Q11: acc[4+f][2+g] += A1 . B1 ----
    __builtin_amdgcn_s_setprio(1);
    #pragma unroll
    for (int f = 0; f < 4; f++)
      #pragma unroll
      for (int g = 0; g < 2; g++) {
        acc[4 + f][2 + g] = __builtin_amdgcn_mfma_f32_16x16x32_bf16(a1[f][0], b1[g][0], acc[4 + f][2 + g], 0, 0, 0);
        acc[4 + f][2 + g] = __builtin_amdgcn_mfma_f32_16x16x32_bf16(a1[f][1], b1[g][1], acc[4 + f][2 + g], 0, 0, 0);
      }
    __builtin_amdgcn_s_setprio(0);
    if (more) { gl16(Bk + b10, L + 24576 + d0); gl16(Bk + b11, L + 24576 + d1); }
    // ---- Q10: acc[4+f][g] += A1 . B0 (b0 kept live from phase 0) ----
    __builtin_amdgcn_s_setprio(1);
    #pragma unroll
    for (int f = 0; f < 4; f++)
      #pragma unroll
      for (int g = 0; g < 2; g++) {
        acc[4 + f][g] = __builtin_amdgcn_mfma_f32_16x16x32_bf16(a1[f][0], b0[g][0], acc[4 + f][g], 0, 0, 0);
        acc[4 + f][g] = __builtin_amdgcn_mfma_f32_16x16x32_bf16(a1[f][1], b0[g][1], acc[4 + f][g], 0, 0, 0);
      }
    __builtin_amdgcn_s_setprio(0);
  }
  // ---- epilogue ----
  const long cz = (long)z * cZs;
  #pragma unroll
  for (int i = 0; i < 8; i++) {
    const int row = m0 + wm * 128 + (i >> 2) * 64 + (i & 3) * 16 + lq * 4;
    #pragma unroll
    for (int j = 0; j < 4; j++) {
      const int col = n0 + wn * 64 + (j >> 1) * 32 + (j & 1) * 16 + lm;
      const float bv = bias ? bias[col] : 0.f;
      #pragma unroll
      for (int rr = 0; rr < 4; rr++) {
        float v = acc[i][j][rr] + bv;
        if (ACT == 1) v = silu(v);
        C[cz + (long)(row + rr) * ldc + col] = (bf16)v;
      }
    }
  }
}

// ---------------- bf16 MFMA GEMM 64x128 tile ----------------
// NORM=1 (qkv mode): after silu, 8-col-group rmsnorm for Q (x==0, qn, prescale) and
// K (x==1, kn); V (x==2) passthrough.
template <int ACT, int OUTBF, int ACC, int NORM>
__global__ __launch_bounds__(256) void gemm64(
    const bf16* __restrict__ A, int lda, long aZs,
    const bf16* __restrict__ Bt, int ldb, long bZs,
    const float* __restrict__ bias, int biasZs,
    void* __restrict__ Cv, int ldc, long cZs,
    int M, int N, int K,
    const float* __restrict__ qn, const float* __restrict__ kn) {
  __shared__ bf16 As[64 * 32];
  __shared__ bf16 Bs[128 * 32];
  int tid = threadIdx.x;
  int m0 = blockIdx.y * 64, n0 = blockIdx.x * 128;
  int z = blockIdx.z;
  const bf16* Ab = A + (long)z * aZs;
  const bf16* Bb = Bt + (long)z * bZs;
  f32x4 acc[4][2] = {};
  int wv = tid >> 6, lane = tid & 63;
  int lm = lane & 15, lq = lane >> 4;
  int wcol = wv * 32;
  const bf16* ag = Ab + (long)(m0 + (tid >> 2)) * lda + (tid & 3) * 8;
  const bf16* bg = Bb + (long)(n0 + (tid >> 2)) * ldb + (tid & 3) * 8;
  bf16* asd = As + tid * 8;
  bf16* bsd = Bs + tid * 8;
  for (int k0 = 0; k0 < K; k0 += 32) {
    gl16(ag + k0, asd);
    gl16(bg + k0, bsd);
    gl16(bg + k0 + 64L * ldb, bsd + 2048);
    __syncthreads();
    bf16x8 af[4], bfr[2];
    #pragma unroll
    for (int i = 0; i < 4; i++)
      af[i] = *(const bf16x8*)(As + (i * 16 + lm) * 32 + lq * 8);
    #pragma unroll
    for (int j = 0; j < 2; j++)
      bfr[j] = *(const bf16x8*)(Bs + (wcol + j * 16 + lm) * 32 + lq * 8);
    #pragma unroll
    for (int i = 0; i < 4; i++)
      #pragma unroll
      for (int j = 0; j < 2; j++)
        acc[i][j] = __builtin_amdgcn_mfma_f32_16x16x32_bf16(af[i], bfr[j], acc[i][j], 0, 0, 0);
    __syncthreads();
  }
  long cz = (long)z * cZs;
  const float* bz = bias ? bias + (long)z * biasZs : nullptr;
  if constexpr (NORM == 0) {
    #pragma unroll
    for (int i = 0; i < 4; i++) {
      int row = m0 + i * 16 + lq * 4;
      #pragma unroll
      for (int j = 0; j < 2; j++) {
        int col = n0 + wcol + j * 16 + lm;
        float bv = bz ? bz[col] : 0.f;
        #pragma unroll
        for (int r = 0; r < 4; r++) {
          float v = acc[i][j][r] + bv;
          long off = cz + (long)(row + r) * ldc + col;
          if (ACC) v += (float)((bf16*)Cv)[off];
          if (ACT == 1) v = silu(v);
          if (OUTBF) ((bf16*)Cv)[off] = (bf16)v;
          else       ((float*)Cv)[off] = v;
        }
      }
    }
  } else {
    int nsec = blockIdx.x;              // 0=Q, 1=K, 2=V
    bool don = nsec < 2;
    float wnv = 1.f;
    if (nsec == 0) wnv = qn[z * 8 + (lm & 7)] * QSCALE_E;
    else if (nsec == 1) wnv = kn[z * 8 + (lm & 7)];
    #pragma unroll
    for (int i = 0; i < 4; i++) {
      int row = m0 + i * 16 + lq * 4;
      #pragma unroll
      for (int j = 0; j < 2; j++) {
        int col = n0 + wcol + j * 16 + lm;
        float bv = bz ? bz[col] : 0.f;
        #pragma unroll
        for (int r = 0; r < 4; r++) {
          float v = acc[i][j][r] + bv;
          if (ACT == 1) v = silu(v);
          float s = v * v;
          s += __shfl_xor(s, 1);
          s += __shfl_xor(s, 2);
          s += __shfl_xor(s, 4);
          if (don) v = v * rsqrtf(s * 0.125f + EPS) * wnv;
          ((bf16*)Cv)[cz + (long)(row + r) * ldc + col] = (bf16)v;
        }
      }
    }
  }
}

// ---------------- embed + rmsnorm -> bf16 h ----------------
__global__ __launch_bounds__(256) void k_embed(const float* __restrict__ x,
    const float* __restrict__ emb, const float* __restrict__ pos,
    const float* __restrict__ nw, bf16* __restrict__ h) {
  __shared__ float red[4];
  int row = blockIdx.x;
  int l = row % Lq;
  int xi = (int)(x[row] * 255.f);
  xi = min(max(xi, 0), 255);
  const float* er = emb + (long)xi * WIDTH;
  const float* pr = pos + (long)l * WIDTH;
  int c0 = threadIdx.x * 4;
  float v[4]; float ss = 0.f;
  #pragma unroll
  for (int i = 0; i < 4; i++) { v[i] = er[c0 + i] + pr[c0 + i]; ss += v[i] * v[i]; }
  ss = blockReduceSum256(ss, red);
  float r = rsqrtf(ss / WIDTH + EPS);
  bf16* hr = h + (long)row * WIDTH;
  #pragma unroll
  for (int i = 0; i < 4; i++) hr[c0 + i] = (bf16)(v[i] * r * nw[c0 + i]);
}

// ---------------- mean over L, phase 1: 16 partials per b ----------------
__global__ void k_meanl_p(const bf16* __restrict__ h, float* __restrict__ part) {
  int lp = blockIdx.x, b = blockIdx.y, t = threadIdx.x;
  const bf16* p = h + ((long)b * Lq + (long)lp * 36) * WIDTH + t * 4;
  float a0 = 0, a1 = 0, a2 = 0, a3 = 0;
  for (int l = 0; l < 36; l++) {
    bf16x4 v = *(const bf16x4*)(p + (long)l * WIDTH);
    a0 += (float)v[0]; a1 += (float)v[1]; a2 += (float)v[2]; a3 += (float)v[3];
  }
  float* dst = part + ((long)b * 16 + lp) * WIDTH + t * 4;
  dst[0] = a0; dst[1] = a1; dst[2] = a2; dst[3] = a3;
}

// ---------------- SE phase 1 ----------------
__global__ __launch_bounds__(256) void k_se1(const float* __restrict__ part,
    const float* __restrict__ w1, const float* __restrict__ b1,
    float* __restrict__ t1) {
  __shared__ float sv[1024];
  __shared__ float red[256];
  int jb = blockIdx.x, b = blockIdx.y, t = threadIdx.x;
  for (int c = t; c < 1024; c += 256) {
    float a = 0.f;
    #pragma unroll
    for (int lp = 0; lp < 16; lp++) a += part[((long)b * 16 + lp) * 1024 + c];
    sv[c] = a * (1.f / 576.f);
  }
  __syncthreads();
  int j = t & 7, pt = t >> 3;
  int j0 = jb * 8;
  float acc = 0.f;
  int c0 = pt * 32;
  #pragma unroll 8
  for (int c = c0; c < c0 + 32; c++) acc += sv[c] * w1[c * 256 + j0 + j];
  red[t] = acc;
  __syncthreads();
  if (t < 8) {
    float a = b1[j0 + t];
    #pragma unroll
    for (int p = 0; p < 32; p++) a += red[p * 8 + t];
    t1[b * 256 + j0 + t] = silu(a);
  }
}

// ---------------- SE phase 2 ----------------
__global__ __launch_bounds__(256) void k_se2(const float* __restrict__ t1,
    const float* __restrict__ w2, const float* __restrict__ b2,
    float* __restrict__ s) {
  __shared__ float red[256];
  int jb = blockIdx.x, b = blockIdx.y, t = threadIdx.x;
  int j = t & 31, pt = t >> 5;
  int j0 = jb * 32;
  const float* tb = t1 + b * 256;
  float acc = 0.f;
  int c0 = pt * 32;
  #pragma unroll 8
  for (int c = c0; c < c0 + 32; c++) acc += tb[c] * w2[c * 1024 + j0 + j];
  red[t] = acc;
  __syncthreads();
  if (t < 32) {
    float a = b2[j0 + t];
    #pragma unroll
    for (int p = 0; p < 8; p++) a += red[p * 32 + t];
    s[b * 1024 + j0 + t] = 1.f / (1.f + __expf(-a));
  }
}

// ---------------- mix: h += rmsnorm(h*(s-1), mw) ----------------
__global__ __launch_bounds__(256) void k_mix_b(bf16* __restrict__ h,
    const float* __restrict__ s, const float* __restrict__ mw) {
  __shared__ float red[4];
  int row = blockIdx.x;
  int b = row / Lq;
  bf16* hr = h + (long)row * WIDTH;
  const float* sb = s + b * WIDTH;
  int c0 = threadIdx.x * 4;
  float hv[4], y[4]; float ss = 0.f;
  #pragma unroll
  for (int i = 0; i < 4; i++) {
    hv[i] = (float)hr[c0 + i];
    y[i] = hv[i] * (sb[c0 + i] - 1.f); ss += y[i] * y[i];
  }
  ss = blockReduceSum256(ss, red);
  float r = rsqrtf(ss / WIDTH + EPS);
  #pragma unroll
  for (int i = 0; i < 4; i++) hr[c0 + i] = (bf16)(hv[i] + y[i] * r * mw[c0 + i]);
}

// ---------------- h += rmsnorm(g, mw) ----------------
__global__ __launch_bounds__(256) void k_addnorm_b(bf16* __restrict__ h,
    const bf16* __restrict__ g, const float* __restrict__ mw) {
  __shared__ float red[4];
  int row = blockIdx.x;
  bf16* hr = h + (long)row * WIDTH;
  const bf16* gr = g + (long)row * WIDTH;
  int c0 = threadIdx.x * 4;
  float y[4]; float ss = 0.f;
  #pragma unroll
  for (int i = 0; i < 4; i++) { y[i] = (float)gr[c0 + i]; ss += y[i] * y[i]; }
  ss = blockReduceSum256(ss, red);
  float r = rsqrtf(ss / WIDTH + EPS);
  #pragma unroll
  for (int i = 0; i < 4; i++)
    hr[c0 + i] = (bf16)((float)hr[c0 + i] + y[i] * r * mw[c0 + i]);
}

// ---------------- h += rmsnorm(p0 + p1 + b2, mw)  (2-way K-split partials) --------
__global__ __launch_bounds__(256) void k_addnorm2(bf16* __restrict__ h,
    const bf16* __restrict__ p0, const bf16* __restrict__ p1,
    const float* __restrict__ b2, const float* __restrict__ mw) {
  __shared__ float red[4];
  int row = blockIdx.x;
  bf16* hr = h + (long)row * WIDTH;
  const bf16* g0 = p0 + (long)row * WIDTH;
  const bf16* g1 = p1 + (long)row * WIDTH;
  int c0 = threadIdx.x * 4;
  float y[4]; float ss = 0.f;
  #pragma unroll
  for (int i = 0; i < 4; i++) {
    y[i] = (float)g0[c0 + i] + (float)g1[c0 + i] + b2[c0 + i];
    ss += y[i] * y[i];
  }
  ss = blockReduceSum256(ss, red);
  float r = rsqrtf(ss / WIDTH + EPS);
  #pragma unroll
  for (int i = 0; i < 4; i++)
    hr[c0 + i] = (bf16)((float)hr[c0 + i] + y[i] * r * mw[c0 + i]);
}

// ---------------- h += rmsnorm(p0+p1+p2+p3 + b2, mw)  (4-way K-split) -------------
__global__ __launch_bounds__(256) void k_addnorm4(bf16* __restrict__ h,
    const bf16* __restrict__ parts, const float* __restrict__ b2,
    const float* __restrict__ mw) {
  __shared__ float red[4];
  int row = blockIdx.x;
  bf16* hr = h + (long)row * WIDTH;
  const bf16* g0 = parts + (long)row * WIDTH;
  int c0 = threadIdx.x * 4;
  float y[4]; float ss = 0.f;
  #pragma unroll
  for (int i = 0; i < 4; i++) {
    float a = b2[c0 + i];
    #pragma unroll
    for (int p = 0; p < 4; p++) a += (float)g0[(long)p * PSTRIDE + c0 + i];
    y[i] = a; ss += a * a;
  }
  ss = blockReduceSum256(ss, red);
  float r = rsqrtf(ss / WIDTH + EPS);
  #pragma unroll
  for (int i = 0; i < 4; i++)
    hr[c0 + i] = (bf16)((float)hr[c0 + i] + y[i] * r * mw[c0 + i]);
}

// ---------------- router + lambdas ----------------
__global__ __launch_bounds__(256) void k_router(const float* __restrict__ part,
    const float* __restrict__ rwgt, const float* __restrict__ rb,
    const float* __restrict__ lq1, const float* __restrict__ lk1,
    const float* __restrict__ lq2, const float* __restrict__ lk2,
    float* __restrict__ rw, float* __restrict__ lam) {
  __shared__ float sv[1024];
  __shared__ float red[256];
  __shared__ float lg[8];
  int b = blockIdx.x, t = threadIdx.x;
  for (int c = t; c < 1024; c += 256) {
    float a = 0.f;
    #pragma unroll
    for (int lp = 0; lp < 16; lp++) a += part[((long)b * 16 + lp) * 1024 + c];
    sv[c] = a * (1.f / 576.f);
  }
  __syncthreads();
  int j = t & 7, pt = t >> 3;
  float acc = 0.f;
  int c0 = pt * 32;
  #pragma unroll 8
  for (int c = c0; c < c0 + 32; c++) acc += sv[c] * rwgt[c * 8 + j];
  red[t] = acc;
  __syncthreads();
  if (t < 8) {
    float a = rb[t];
    for (int p = 0; p < 32; p++) a += red[p * 8 + t];
    lg[t] = a;
  }
  __syncthreads();
  if (t == 0) {
    float v[8]; bool sel[8];
    #pragma unroll
    for (int i = 0; i < 8; i++) { v[i] = lg[i]; sel[i] = false; }
    int idxs[4]; float vals[4];
    for (int s = 0; s < 4; s++) {
      int bi = -1; float bv = -1e30f;
      for (int i = 0; i < 8; i++) if (!sel[i] && v[i] > bv) { bv = v[i]; bi = i; }
      sel[bi] = true; idxs[s] = bi; vals[s] = bv;
    }
    float m = vals[0], den = 0.f, e[4];
    for (int s = 0; s < 4; s++) { e[s] = __expf(vals[s] - m); den += e[s]; }
    for (int i = 0; i < 8; i++) rw[b * 8 + i] = 0.f;
    for (int s = 0; s < 4; s++) rw[b * 8 + idxs[s]] = e[s] / den;
  }
  if (b == 0 && t >= 8 && t < 16) {
    int c = t - 8;
    float d1 = 0.f, d2 = 0.f;
    for (int i = 0; i < 8; i++) {
      d1 += lq1[c * 8 + i] * lk1[c * 8 + i];
      d2 += lq2[c * 8 + i] * lk2[c * 8 + i];
    }
    lam[c] = __expf(d1) - __expf(d2) + LAMINIT;
  }
}

// ---------------- MFMA causal differential attention (prenormed Q/K) --------------
// den on the MFMA pipe (ONES ones-vector trick). K staged via gl16 [576][16];
// V staged column-major Vt[16][584] (R3-verified layout). 512 threads = 8
// waves per block, grid (64,1,8): each (slice,head) staged ONCE, per-wave pr
// map u = wv in [0,8): u<6 pair {u+2, 17-u}; u>=6 triple {u-6, u+2, 17-u}.
// LDS 37376 B.
__global__ __launch_bounds__(512) void k_attn_mfma(
    const bf16* __restrict__ qkv, const float* __restrict__ lam,
    const float* __restrict__ hnw, bf16* __restrict__ dc) {
  __shared__ bf16 Ks[576 * 16];
  __shared__ bf16 Vt[16 * 584];
  int tid = threadIdx.x;
  int slice = blockIdx.x; int zc = slice >> 3, b = slice & 7;
  int head = blockIdx.z;
  const bf16* qkvb = qkv + ((long)zc * ROWS + (long)b * Lq) * 384;
  for (int i = tid; i < 1152; i += 512) {
    int row = i >> 1, hf = i & 1;
    gl16(qkvb + (long)row * 384 + 128 + head * 16 + hf * 8, Ks + i * 8);
  }
  for (int i = tid; i < 1152; i += 512) {
    int row = i >> 1, dh = i & 1;
    bf16x8 v = *(const bf16x8*)(qkvb + (long)row * 384 + 256 + head * 16 + dh * 8);
    #pragma unroll
    for (int j = 0; j < 8; j++) Vt[(dh * 8 + j) * 584 + row] = v[j];
  }
  __syncthreads();
  int wv = tid >> 6, lane = tid & 63;
  int lm = lane & 15, lq = lane >> 4;
  float lamv = lam[zc];
  float hwv[4];
  #pragma unroll
  for (int r = 0; r < 4; r++) hwv[r] = hnw[zc * 16 + lq * 4 + r] * (1.f - LAMINIT);
  const bf16 one = (bf16)1.0f;
  const bf16x4 ONES = {one, one, one, one};
  int u = wv;                           // 8 waves -> u in [0,8)
  int prA, prB, prC;
  if (u < 6) { prA = u + 2; prB = 17 - u; prC = -1; }
  else       { int v2 = u - 6; prA = v2; prB = 8 + v2; prC = 11 - v2; }
  for (int pi = 0; pi < 3; pi++) {
    int pr = (pi == 0) ? prA : (pi == 1) ? prB : prC;
    if (pr < 0) continue;
    bf16x8 bq0[2] = {{}, {}}, bq1[2] = {{}, {}};
    if (lq < 2) {
      #pragma unroll
      for (int tile = 0; tile < 2; tile++) {
        bf16x8 t8 = *(const bf16x8*)(
            qkvb + (long)(pr * 32 + tile * 16 + lm) * 384 + head * 16 + lq * 8);
        if (lq == 0) bq0[tile] = t8; else bq1[tile] = t8;
      }
    }
    f32x4 o[2][2] = {};
    f32x4 dacc[2][2] = {};
    for (int kc = 0; kc <= pr; kc++) {
      f32x4 sT[2][2][2] = {};
      #pragma unroll
      for (int t = 0; t < 2; t++) {
        bf16x8 aK = {};
        if (lq < 2) aK = *(const bf16x8*)(Ks + (kc * 32 + t * 16 + lm) * 16 + lq * 8);
        #pragma unroll
        for (int tile = 0; tile < 2; tile++) {
          sT[t][tile][0] = __builtin_amdgcn_mfma_f32_16x16x32_bf16(aK, bq0[tile], sT[t][tile][0], 0, 0, 0);
          sT[t][tile][1] = __builtin_amdgcn_mfma_f32_16x16x32_bf16(aK, bq1[tile], sT[t][tile][1], 0, 0, 0);
        }
      }
      bool diag = (kc == pr);
      #pragma unroll
      for (int t = 0; t < 2; t++) {
        bf16x4 aV = *(const bf16x4*)(Vt + lm * 584 + kc * 32 + t * 16 + lq * 4);
        #pragma unroll
        for (int tile = 0; tile < 2; tile++) {
          if (diag && tile == 0 && t == 1) continue;
          bool masked = diag && (tile == t);
          #pragma unroll
          for (int h2 = 0; h2 < 2; h2++) {
            bf16x4 pb;
            #pragma unroll
            for (int r = 0; r < 4; r++) {
              float ev = fexp2(sT[t][tile][h2][r]);
              if (masked && (lq * 4 + r > lm)) ev = 0.f;
              pb[r] = (bf16)ev;
            }
            dacc[tile][h2] = mfma16(ONES, pb, dacc[tile][h2]);
            o[tile][h2] = mfma16(aV, pb, o[tile][h2]);
          }
        }
      }
    }
    #pragma unroll
    for (int tile = 0; tile < 2; tile++) {
      float inv1 = 1.f / dacc[tile][0][0];
      float inv2 = lamv / dacc[tile][1][0];
      float dff[4]; float ss = 0.f;
      #pragma unroll
      for (int r = 0; r < 4; r++) {
        dff[r] = o[tile][0][r] * inv1 - o[tile][1][r] * inv2;
        ss += dff[r] * dff[r];
      }
      ss += __shfl_xor(ss, 16);
      ss += __shfl_xor(ss, 32);
      float rr = rsqrtf(ss * 0.0625f + EPS);
      bf16x4 outp;
      #pragma unroll
      for (int r = 0; r < 4; r++) outp[r] = (bf16)(dff[r] * rr * hwv[r]);
      long rowg = (long)zc * ROWS + (long)b * Lq + pr * 32 + tile * 16 + lm;
      *(bf16x4*)(dc + rowg * 128 + head * 16 + lq * 4) = outp;
    }
  }
}

// ---------------- seg + pool fused: 16 bins, 1-wave blocks ----------------
__global__ __launch_bounds__(64) void k_segpool(const bf16* __restrict__ h,
    const bf16* __restrict__ op, const float* __restrict__ segw,
    const float* __restrict__ rw, float* __restrict__ part) {
  int lp = blockIdx.x, b = blockIdx.y, ch = blockIdx.z;
  int t = threadIdx.x;
  int c0 = t * 2;
  float w0 = segw[ch * 128 + c0], w1 = segw[ch * 128 + c0 + 1];
  float rwv = rw[b * 8 + ch];
  float a0 = 0.f, a1 = 0.f;
  for (int l = 0; l < 36; l++) {
    int row = b * Lq + lp * 36 + l;
    const bf16* oprow = op + (long)ch * ROWS * CW + (long)row * CW;
    bf16x2 yv = *(const bf16x2*)(oprow + c0);
    float y0 = (float)yv[0], y1 = (float)yv[1];
    float ss = y0 * y0 + y1 * y1;
    #pragma unroll
    for (int m = 1; m < 64; m <<= 1) ss += __shfl_xor(ss, m);
    float r = rsqrtf(ss * (1.f / 128.f) + EPS);
    bf16x2 hv = *(const bf16x2*)(h + (long)row * WIDTH + ch * 128 + c0);
    a0 += ((float)hv[0] + y0 * r * w0) * rwv;
    a1 += ((float)hv[1] + y1 * r * w1) * rwv;
  }
  float* dst = part + ((long)b * 16 + lp) * 1024 + ch * 128 + c0;
  dst[0] = a0; dst[1] = a1;
}

// ---------------- head (reads 16 pool partials) ----------------
__global__ __launch_bounds__(256) void k_head(const float* __restrict__ part,
    const float* __restrict__ hw, const float* __restrict__ hb, float* __restrict__ out) {
  __shared__ float pool[1024];
  __shared__ float red[256];
  int b = blockIdx.x, t = threadIdx.x;
  for (int c = t; c < 1024; c += 256) {
    float a = 0.f;
    #pragma unroll
    for (int lp = 0; lp < 16; lp++) a += part[((long)b * 16 + lp) * 1024 + c];
    pool[c] = a * (1.f / 576.f);
  }
  __syncthreads();
  int j = t & 15, pt = t >> 4;
  float acc = 0.f;
  if (j < 10)
    for (int c = pt * 64; c < pt * 64 + 64; c++)
      acc += pool[c] * hw[c * 10 + j];
  red[t] = acc;
  __syncthreads();
  if (t < 10) {
    float a = hb[t];
    for (int p = 0; p < 16; p++) a += red[p * 16 + t];
    out[b * 10 + t] = a;
  }
}

// ---------------- launcher ----------------
extern "C" void kernel_launch(void* const* d_in, const int* in_sizes, int n_in,
                              void* d_out, int out_size, void* d_ws, size_t ws_size,
                              hipStream_t stream) {
  const float* x          = (const float*)d_in[0];
  const float* pixel_embed= (const float*)d_in[2];
  const float* freq_h     = (const float*)d_in[3];
  const float* freq_w     = (const float*)d_in[4];
  const float* phase_h    = (const float*)d_in[5];
  const float* phase_w    = (const float*)d_in[6];
  const float* pos_proj_w = (const float*)d_in[7];
  const float* pos_proj_b = (const float*)d_in[8];
  const float* embed_norm = (const float*)d_in[9];
  const float* se_w1      = (const float*)d_in[10];
  const float* se_b1      = (const float*)d_in[11];
  const float* se_w2      = (const float*)d_in[12];
  const float* se_b2      = (const float*)d_in[13];
  const float* mix_norm   = (const float*)d_in[14];
  const float* mlp_w1     = (const float*)d_in[15];
  const float* mlp_b1     = (const float*)d_in[16];
  const float* mlp_w2     = (const float*)d_in[17];
  const float* mlp_b2     = (const float*)d_in[18];
  const float* mlp_norm   = (const float*)d_in[19];
  const float* router_w   = (const float*)d_in[20];
  const float* router_b   = (const float*)d_in[21];
  const float* qkv_w      = (const float*)d_in[22];
  const float* qkv_b      = (const float*)d_in[23];
  const float* q_norm_w   = (const float*)d_in[24];
  const float* k_norm_w   = (const float*)d_in[25];
  const float* head_norm_w= (const float*)d_in[26];
  const float* lam_q1     = (const float*)d_in[27];
  const float* lam_k1     = (const float*)d_in[28];
  const float* lam_q2     = (const float*)d_in[29];
  const float* lam_k2     = (const float*)d_in[30];
  const float* out_w      = (const float*)d_in[31];
  const float* out_b      = (const float*)d_in[32];
  const float* seg_norm_w = (const float*)d_in[33];
  const float* head_w     = (const float*)d_in[34];
  const float* head_b     = (const float*)d_in[35];

  char* W = (char*)d_ws;
  bf16*  HB    = (bf16*)(W + B_HB);
  bf16*  G2B   = (bf16*)(W + B_G2B);
  float* POS   = (float*)(W + B_G2B);      // POS lives in G2B region (dead until MLP)
  bf16*  ENCB  = (bf16*)(W + B_ENCB);
  bf16*  POSWT = (bf16*)(W + B_POSWT);
  bf16*  QKVWT = (bf16*)(W + B_QKVWT);
  bf16*  OWT   = (bf16*)(W + B_OWT);
  float* SE    = (float*)(W + B_SE);
  float* T1    = (float*)(W + B_T1);
  float* MP    = (float*)(W + B_MP);
  float* RW    = (float*)(W + B_RW);
  float* LAM   = (float*)(W + B_LAM);
  char*  P     = W + B_POOL;
  bf16*  W1T   = (bf16*)P;
  bf16*  W2T   = (bf16*)(P + 8388608);
  bf16*  HID   = (bf16*)(P + 16777216);
  bf16*  PARTS = (bf16*)(P + 16777216 + 37748736);   // after full-width HID
  bf16*  QKV   = (bf16*)P;
  bf16*  DC    = (bf16*)(P + 28311552);
  float* out   = (float*)d_out;
  const int tier = (ws_size >= WS_BIG3) ? 3 : (ws_size >= WS_BIG2) ? 2
                 : (ws_size >= WS_BIG) ? 1 : 0;

  // 0. all weight casts in one dispatch
  k_tcast_all<<<8832, 256, 0, stream>>>(mlp_w1, mlp_w2, pos_proj_w, qkv_w, out_w,
                                        W1T, W2T, POSWT, QKVWT, OWT);
  // 1. positional encoding + projection (POS f32 in G2B region)
  k_enc_b<<<288, 256, 0, stream>>>(freq_h, freq_w, phase_h, phase_w, ENCB);
  gemm64<0, 0, 0, 0><<<dim3(8, 10, 1), 256, 0, stream>>>(
      ENCB, 128, 0, POSWT, 128, 0, pos_proj_b, 0, POS, 1024, 0, 640, 1024, 128,
      nullptr, nullptr);
  // 2. embed + rmsnorm -> bf16 h
  k_embed<<<ROWS, 256, 0, stream>>>(x, pixel_embed, POS, embed_norm, HB);
  // 3. SE gate
  k_meanl_p<<<dim3(16, 8), 256, 0, stream>>>(HB, MP);
  k_se1<<<dim3(32, 8), 256, 0, stream>>>(MP, se_w1, se_b1, T1);
  k_se2<<<dim3(32, 8), 256, 0, stream>>>(T1, se_w2, se_b2, SE);
  k_mix_b<<<ROWS, 256, 0, stream>>>(HB, SE, mix_norm);
  // 4. MLP
  if (tier >= 1) {
    // gemm1 main: 256^2 8-wave kernel, rows 0..4095 (16m x 16n = 256 blocks,
    // one block/CU); tail rows 4096..4607 via gemm64 64-row tiles (256 blocks
    // -> full chip; was gemm_bt 128 blocks = half the CUs idle).
    gemm256<1><<<256, 512, 0, stream>>>(
        HB, 1024, 0, W1T, 1024, 0, mlp_b1,
        HID, 4096, 0, 16, 16, 1024);
    gemm64<1, 1, 0, 0><<<dim3(32, 8, 1), 256, 0, stream>>>(
        HB + 4096L * 1024, 1024, 0, W1T, 1024, 0, mlp_b1, 0,
        HID + 4096L * 4096, 4096, 0, 512, 4096, 1024, nullptr, nullptr);
    if (tier == 3) {
      // gemm2 main: 4-way K-split, 16m x 4n x 4z = 256 blocks; tail via gemm64
      // 64-row tiles (8n x 8m x 4z = 256 blocks, full chip).
      gemm256<0><<<256, 512, 0, stream>>>(
          HID, 4096, 1024, W2T, 4096, 1024, nullptr,
          PARTS, 1024, PSTRIDE, 16, 4, 1024);
      gemm64<0, 1, 0, 0><<<dim3(8, 8, 4), 256, 0, stream>>>(
          HID + 4096L * 4096, 4096, 1024, W2T, 4096, 1024, nullptr, 0,
          PARTS + 4096L * 1024, 1024, PSTRIDE, 512, 1024, 1024, nullptr, nullptr);
      k_addnorm4<<<ROWS, 256, 0, stream>>>(HB, PARTS, mlp_b2, mlp_norm);
    } else if (tier == 2) {
      // gemm2: 2-way K-split, XCD-pinned, partials in G2B + PARTS[0]
      gemm_bt<0, 1, 2><<<576, 256, 0, stream>>>(
          HID, 4096, 2048, W2T, 4096, 2048, nullptr, 0,
          G2B, 1024, (long)(PARTS - G2B), 4608, 1024, 2048);
      k_addnorm2<<<ROWS, 256, 0, stream>>>(HB, G2B, PARTS, mlp_b2, mlp_norm);
    } else {
      gemm64<0, 1, 0, 0><<<dim3(8, 72, 1), 256, 0, stream>>>(
          HID, 4096, 0, W2T, 4096, 0, mlp_b2, 0,
          G2B, 1024, 0, 4608, 1024, 4096, nullptr, nullptr);
      k_addnorm_b<<<ROWS, 256, 0, stream>>>(HB, G2B, mlp_norm);
    }
  } else {
    gemm_bt<1, 1, 0><<<dim3(16, 36, 1), 256, 0, stream>>>(
        HB, 1024, 0, W1T, 1024, 0, mlp_b1, 0, HID, 2048, 0, 4608, 2048, 1024);
    gemm64<0, 1, 0, 0><<<dim3(8, 72, 1), 256, 0, stream>>>(
        HID, 2048, 0, W2T, 4096, 0, mlp_b2, 0, G2B, 1024, 0, 4608, 1024, 2048,
        nullptr, nullptr);
    gemm_bt<1, 1, 0><<<dim3(16, 36, 1), 256, 0, stream>>>(
        HB, 1024, 0, W1T + 2048L * 1024, 1024, 0, mlp_b1 + 2048, 0, HID, 2048, 0,
        4608, 2048, 1024);
    gemm64<0, 1, 1, 0><<<dim3(8, 72, 1), 256, 0, stream>>>(
        HID, 2048, 0, W2T + 2048, 4096, 0, nullptr, 0, G2B, 1024, 0,
        4608, 1024, 2048, nullptr, nullptr);
    k_addnorm_b<<<ROWS, 256, 0, stream>>>(HB, G2B, mlp_norm);
  }
  // 5. router + lambdas
  k_meanl_p<<<dim3(16, 8), 256, 0, stream>>>(HB, MP);
  k_router<<<8, 256, 0, stream>>>(MP, router_w, router_b,
                                  lam_q1, lam_k1, lam_q2, lam_k2, RW, LAM);
  // 6. qkv-proj with fused silu + Q/K rmsnorm (+ Q prescale) in epilogue
  gemm64<1, 1, 0, 1><<<dim3(3, 72, 8), 256, 0, stream>>>(
      HB, 1024, CW, QKVWT, 128, 384 * 128, qkv_b, 384,
      QKV, 384, (long)ROWS * 384, ROWS, 384, 128, q_norm_w, k_norm_w);
  // 7. attention (prenormed), out-proj in-place on DC
  k_attn_mfma<<<dim3(64, 1, 8), 512, 0, stream>>>(QKV, LAM, head_norm_w, DC);
  gemm64<1, 1, 0, 0><<<dim3(1, 72, 8), 256, 0, stream>>>(
      DC, 128, (long)ROWS * 128, OWT, 128, 128 * 128, out_b, 128,
      DC, 128, (long)ROWS * 128, ROWS, 128, 128, nullptr, nullptr);
  // 8. seg + pool fused -> 16 partials; head folds the final reduce
  k_segpool<<<dim3(16, 8, 8), 64, 0, stream>>>(HB, DC, seg_norm_w, RW, MP);
  k_head<<<8, 256, 0, stream>>>(MP, head_w, head_b, out);
}

// Round 8
// 411.927 us; speedup vs baseline: 1.0805x; 1.0010x over previous
//
#include <hip/hip_runtime.h>
#include <math.h>

typedef __bf16 bf16;
typedef __bf16 bf16x8 __attribute__((ext_vector_type(8)));
typedef __bf16 bf16x4 __attribute__((ext_vector_type(4)));
typedef __bf16 bf16x2 __attribute__((ext_vector_type(2)));
typedef float f32x4 __attribute__((ext_vector_type(4)));
typedef short s16x4 __attribute__((ext_vector_type(4)));

// ---------------- constants ----------------
constexpr int Bsz = 8, HIMG = 24, WIMG = 24;
constexpr int Lq = 576;
constexpr int WIDTH = 1024, NCH = 8, CW = 128;
constexpr int NHEADS = 8, HD = 16, HALF = 8;
constexpr float EPS = 1e-6f;
constexpr float LAMINIT = 0.2f;
// 1/sqrt(8) * log2(e): scores exit MFMA in log2 domain -> v_exp_f32 directly
constexpr float QSCALE_E = 0.35355339059327373f * 1.4426950408889634f;
constexpr int ROWS = Bsz * Lq;              // 4608
constexpr long PSTRIDE = 4718592;           // bf16 elements per MLP partial buffer

__device__ __forceinline__ float fexp2(float x) {
#if __has_builtin(__builtin_amdgcn_exp2f)
  return __builtin_amdgcn_exp2f(x);
#else
  return exp2f(x);
#endif
}

// ---------------- workspace byte offsets ----------------
constexpr size_t B_HB    = 0;                        // bf16 h [4608][1024]
constexpr size_t B_G2B   = B_HB    + 9437184;        // bf16 g2/partial0; POS f32 early
constexpr size_t B_ENCB  = B_G2B   + 9437184;        // bf16 enc [640][128]
constexpr size_t B_POSWT = B_ENCB  + 163840;         // bf16 [1024][128]
constexpr size_t B_QKVWT = B_POSWT + 262144;         // bf16 [8][384][128]
constexpr size_t B_OWT   = B_QKVWT + 786432;         // bf16 [8][128][128]
constexpr size_t B_SE    = B_OWT   + 262144;         // f32 [8][1024]
constexpr size_t B_T1    = B_SE    + 32768;          // f32 [8][256]
constexpr size_t B_MP    = B_T1    + 8192;           // f32 [8][16][1024]
constexpr size_t B_RW    = B_MP    + 524288;         // f32 [64]
constexpr size_t B_LAM   = B_RW    + 256;            // f32 [8]
constexpr size_t B_POOL  = B_LAM   + 256;            // = 20914688; phase-shared pool
// pool (MLP small): W1T 8388608 | W2T 8388608 | HID 18874368            (58.7 MB)
// pool (MLP big):   W1T 8388608 | W2T 8388608 | HID 37748736            (75.4 MB)
// pool (MLP big2):  ... + PART1 bf16 9437184 after HID                  (84.9 MB)
// pool (MLP big3):  ... + PARTS bf16 4x9437184 after HID                (113.2 MB)
// pool (chan):      QKV 28311552 | DC 9437184 (out-proj IN-PLACE on DC) (58.7 MB)
constexpr size_t WS_BIG  = B_POOL + 8388608 + 8388608 + 37748736;     // 75440640
constexpr size_t WS_BIG2 = WS_BIG + 9437184;                          // 84877824
constexpr size_t WS_BIG3 = WS_BIG + 4 * 9437184;                      // 113189376

// ---------------- helpers ----------------
__device__ __forceinline__ float blockReduceSum256(float v, float* red) {
  #pragma unroll
  for (int off = 32; off; off >>= 1) v += __shfl_down(v, off, 64);
  int lane = threadIdx.x & 63, wid = threadIdx.x >> 6;
  if (lane == 0) red[wid] = v;
  __syncthreads();
  float total = 0.f;
  #pragma unroll
  for (int i = 0; i < 4; i++) total += red[i];
  return total;
}
__device__ __forceinline__ float silu(float x) { return x / (1.f + __expf(-x)); }

__device__ __forceinline__ void gl16(const bf16* g, bf16* l) {
  __builtin_amdgcn_global_load_lds(
      (const __attribute__((address_space(1))) void*)g,
      (__attribute__((address_space(3))) void*)l, 16, 0, 0);
}

// v_mfma_f32_16x16x16_bf16 wrapper (A,B = 4 bf16/lane; k = quad*4+j)
__device__ __forceinline__ f32x4 mfma16(bf16x4 a, bf16x4 b, f32x4 c) {
#if __has_builtin(__builtin_amdgcn_mfma_f32_16x16x16bf16_1k)
  union { bf16x4 h; s16x4 s; } ua, ub;
  ua.h = a; ub.h = b;
  return __builtin_amdgcn_mfma_f32_16x16x16bf16_1k(ua.s, ub.s, c, 0, 0, 0);
#else
  f32x4 d = c;
  asm volatile("v_mfma_f32_16x16x16_bf16 %0, %1, %2, %0"
               : "+v"(d) : "v"(a), "v"(b));
  return d;
#endif
}

// ---------------- batched cast+transpose of ALL weights, one dispatch -------------
__device__ __forceinline__ void tcast_tile(const float* __restrict__ W,
    bf16* __restrict__ Wt, int K, int N, long zo, int bx, int by) {
  __shared__ float t[32][33];
  int n0 = bx * 32, k0 = by * 32;
  int tid = threadIdx.x;
  int r = tid >> 3, c4 = (tid & 7) * 4;
  const float4 v = *(const float4*)(W + zo + (long)(k0 + r) * N + n0 + c4);
  t[c4 + 0][r] = v.x; t[c4 + 1][r] = v.y; t[c4 + 2][r] = v.z; t[c4 + 3][r] = v.w;
  __syncthreads();
  bf16* dst = Wt + zo + (long)(n0 + r) * K + k0 + c4;
  bf16x4 o4;
  o4[0] = (bf16)t[r][c4 + 0]; o4[1] = (bf16)t[r][c4 + 1];
  o4[2] = (bf16)t[r][c4 + 2]; o4[3] = (bf16)t[r][c4 + 3];
  *(bf16x4*)dst = o4;
}

__global__ __launch_bounds__(256) void k_tcast_all(
    const float* __restrict__ w1, const float* __restrict__ w2,
    const float* __restrict__ posw, const float* __restrict__ qkvw,
    const float* __restrict__ outw,
    bf16* __restrict__ W1T, bf16* __restrict__ W2T, bf16* __restrict__ POSWT,
    bf16* __restrict__ QKVWT, bf16* __restrict__ OWT) {
  int bid = blockIdx.x;
  if (bid < 4096) {
    tcast_tile(w1, W1T, 1024, 4096, 0, bid % 128, bid / 128);
  } else if (bid < 8192) {
    int t = bid - 4096;
    tcast_tile(w2, W2T, 4096, 1024, 0, t % 32, t / 32);
  } else if (bid < 8320) {
    int t = bid - 8192;
    tcast_tile(posw, POSWT, 128, 1024, 0, t % 32, t / 32);
  } else if (bid < 8704) {
    int t = bid - 8320;
    int z = t / 48; t -= z * 48;
    tcast_tile(qkvw, QKVWT, 128, 384, (long)z * 49152, t % 12, t / 12);
  } else {
    int t = bid - 8704;
    int z = t / 16; t -= z * 16;
    tcast_tile(outw, OWT, 128, 128, (long)z * 16384, t % 4, t / 4);
  }
}

// ---------------- positional encoding (bf16 out) ----------------
__global__ void k_enc_b(const float* __restrict__ fh, const float* __restrict__ fw,
                        const float* __restrict__ ph, const float* __restrict__ pw,
                        bf16* __restrict__ enc) {
  int idx = blockIdx.x * blockDim.x + threadIdx.x;
  if (idx >= Lq * 128) return;
  int l = idx >> 7, c = idx & 127;
  int hh = l / WIMG, ww = l % WIMG;
  float v;
  if (c < 64) {
    int f = c & 31;
    float fr = log1pf(__expf(fh[f])) * 10.f;
    float a = (hh / (float)HIMG) * fr + ph[f];
    v = (c < 32) ? sinf(a) : cosf(a);
  } else {
    int f = c & 31;
    float fr = log1pf(__expf(fw[f])) * 10.f;
    float a = (ww / (float)WIMG) * fr + pw[f];
    v = (c < 96) ? sinf(a) : cosf(a);
  }
  enc[idx] = (bf16)v;
}

// ---------------- bf16 MFMA GEMM 128x128 ----------------
// SWZ=0: 3D grid (x=n, y=m, z).  SWZ=1 (gemm1): 1D grid 1152; XCD-pinned groups
// (m, n-half): all 16 n-tiles of a group share lid%8 -> same XCD L2 serves A-panel.
// SWZ=2 (gemm2 K-split): 1D grid 8*G; group G=(m,z) owns its 8 n-tiles on one XCD.
template <int ACT, int OUTBF, int SWZ>
__global__ __launch_bounds__(256) void gemm_bt(
    const bf16* __restrict__ A, int lda, long aZs,
    const bf16* __restrict__ Bt, int ldb, long bZs,
    const float* __restrict__ bias, int biasZs,
    void* __restrict__ Cv, int ldc, long cZs,
    int M, int N, int K) {
  __shared__ bf16 As[128 * 32];
  __shared__ bf16 Bs[128 * 32];
  int tid = threadIdx.x;
  int m0, n0, z;
  if constexpr (SWZ == 0) {
    m0 = blockIdx.y * 128; n0 = blockIdx.x * 128; z = blockIdx.z;
  } else if constexpr (SWZ == 1) {
    int lid = blockIdx.x;
    int xcd = lid & 7, idx = lid >> 3;
    int j = idx & 15, G = xcd + 8 * (idx >> 4);   // G in [0,72)
    m0 = (G % 36) * 128; n0 = ((G / 36) * 16 + j) * 128; z = 0;
  } else {
    int lid = blockIdx.x;
    int xcd = lid & 7, idx = lid >> 3;
    int n = idx & 7, G = xcd + 8 * (idx >> 3);    // G in [0, grid/8)
    m0 = (G % 36) * 128; n0 = n * 128; z = G / 36;
  }
  const bf16* Ab = A + (long)z * aZs;
  const bf16* Bb = Bt + (long)z * bZs;
  f32x4 acc[4][4] = {};
  int wv = tid >> 6, lane = tid & 63;
  int wrow = (wv >> 1) * 64, wcol = (wv & 1) * 64;
  int lm = lane & 15, lq = lane >> 4;
  const bf16* ag = Ab + (long)(m0 + (tid >> 2)) * lda + (tid & 3) * 8;
  const bf16* bg = Bb + (long)(n0 + (tid >> 2)) * ldb + (tid & 3) * 8;
  bf16* asd = As + tid * 8;
  bf16* bsd = Bs + tid * 8;
  for (int k0 = 0; k0 < K; k0 += 32) {
    gl16(ag + k0, asd);
    gl16(ag + k0 + 64L * lda, asd + 2048);
    gl16(bg + k0, bsd);
    gl16(bg + k0 + 64L * ldb, bsd + 2048);
    __syncthreads();
    bf16x8 af[4], bfr[4];
    #pragma unroll
    for (int i = 0; i < 4; i++) {
      af[i]  = *(const bf16x8*)(As + (wrow + i * 16 + lm) * 32 + lq * 8);
      bfr[i] = *(const bf16x8*)(Bs + (wcol + i * 16 + lm) * 32 + lq * 8);
    }
    #pragma unroll
    for (int i = 0; i < 4; i++)
      #pragma unroll
      for (int j = 0; j < 4; j++)
        acc[i][j] = __builtin_amdgcn_mfma_f32_16x16x32_bf16(af[i], bfr[j], acc[i][j], 0, 0, 0);
    __syncthreads();
  }
  long cz = (long)z * cZs;
  const float* bz = bias ? bias + (long)z * biasZs : nullptr;
  #pragma unroll
  for (int i = 0; i < 4; i++) {
    int row = m0 + wrow + i * 16 + lq * 4;
    #pragma unroll
    for (int j = 0; j < 4; j++) {
      int col = n0 + wcol + j * 16 + lm;
      float bv = bz ? bz[col] : 0.f;
      #pragma unroll
      for (int r = 0; r < 4; r++) {
        float v = acc[i][j][r] + bv;
        if (ACT == 1) v = silu(v);
        long off = cz + (long)(row + r) * ldc + col;
        if (OUTBF) ((bf16*)Cv)[off] = (bf16)v;
        else       ((float*)Cv)[off] = v;
      }
    }
  }
}

// ---------------- 256x256 8-wave free-run MFMA GEMM ----------------
// 256^2 tile, BK=64, 512 threads = 8 waves (2M x 4N), per-wave output 128x64
// (acc[8][4] f32x4), LDS 128 KiB = 2 buffers x (A 256x64 + B 256x64) bf16.
// Schedule: ONE __syncthreads per K-tile (its vmcnt(0)+barrier both drains the
// stage issued a full iteration earlier and hands over the double buffers).
// NO inner barriers: waves slip freely, so one wave's ds_reads overlap another
// wave's MFMAs. setprio(1) around each MFMA cluster; b0 kept live across iter.
// Staging is a FRONT-LOADED burst right after the sync (R6-validated: spreading
// the gl16s across clusters cost +2.4 us/dispatch -- the burst fills the idle
// memory pipe while ds_reads start, and the MFMA clusters then run undisturbed).
// LDS swizzle: slot ^= (row&7) within each 128B row; applied on the global
// source (LDS dest linear, required by gl16) and on the ds_read address.
template <int ACT>
__global__ __launch_bounds__(512) void gemm256(
    const bf16* __restrict__ A, int lda, long aZs,
    const bf16* __restrict__ Bt, int ldb, long bZs,
    const float* __restrict__ bias,
    bf16* __restrict__ C, int ldc, long cZs,
    int Mtiles, int Ntiles, int K) {
  __shared__ bf16 LDS[65536];   // [buf:2][mat:2][half:2][128][64] bf16 = 128 KiB
  const int tid = threadIdx.x;
  // XCD-aware bijective swizzle (gridDim.x % 8 == 0 in all launches here)
  const int cpx = gridDim.x >> 3;
  const int wg = (blockIdx.x & 7) * cpx + (blockIdx.x >> 3);
  const int per_z = Mtiles * Ntiles;
  const int z = wg / per_z, rwg = wg % per_z;
  const int m0 = (rwg / Ntiles) * 256, n0 = (rwg % Ntiles) * 256;
  const bf16* Ab = A + (long)z * aZs;
  const bf16* Bb = Bt + (long)z * bZs;
  // --- staging geometry: 2 x 16B chunks/thread per 128x64 half-tile ---
  const int c0 = tid, c1 = tid + 512;
  const int sr0 = c0 >> 3, sc0 = ((c0 & 7) ^ (sr0 & 7)) * 8;  // pre-swizzled src col
  const int sr1 = c1 >> 3, sc1 = ((c1 & 7) ^ (sr1 & 7)) * 8;
  const long a00 = (long)(m0 + sr0) * lda + sc0;
  const long a01 = (long)(m0 + sr1) * lda + sc1;
  const long a10 = (long)(m0 + 128 + sr0) * lda + sc0;
  const long a11 = (long)(m0 + 128 + sr1) * lda + sc1;
  const long b00 = (long)(n0 + sr0) * ldb + sc0;
  const long b01 = (long)(n0 + sr1) * ldb + sc1;
  const long b10 = (long)(n0 + 128 + sr0) * ldb + sc0;
  const long b11 = (long)(n0 + 128 + sr1) * ldb + sc1;
  const int d0 = c0 * 8, d1 = c1 * 8;                 // linear LDS dest (elems)
  auto stage = [&](int kt, int buf) {
    const bf16* Ak = Ab + kt * 64;
    const bf16* Bk = Bb + kt * 64;
    bf16* L = LDS + buf * 32768;
    gl16(Ak + a00, L + d0);         gl16(Ak + a01, L + d1);
    gl16(Ak + a10, L + 8192 + d0);  gl16(Ak + a11, L + 8192 + d1);
    gl16(Bk + b00, L + 16384 + d0); gl16(Bk + b01, L + 16384 + d1);
    gl16(Bk + b10, L + 24576 + d0); gl16(Bk + b11, L + 24576 + d1);
  };
  // --- wave geometry: 8 waves = 2M x 4N; per-wave output 128 x 64 ---
  const int wv = tid >> 6, lane = tid & 63;
  const int wm = wv >> 2, wn = wv & 3;
  const int lm = lane & 15, lq = lane >> 4;
  const int sw = lm & 7;                              // row&7 read-side XOR
  const int abase = wm * 8192;                        // wave's A half
  const int bbase = 16384 + (wn >> 1) * 8192;         // wave's B half
  const int brow0 = (wn & 1) * 64;                    // wave's rows within B half
  const int kq0 = (lq ^ sw) * 8;                      // swizzled slot, ks=0
  const int kq1 = ((4 + lq) ^ sw) * 8;                // swizzled slot, ks=1
  f32x4 acc[8][4] = {};
  const int NT = K >> 6;
  stage(0, 0);
  for (int s = 0; s < NT; ++s) {
    __syncthreads();   // vmcnt(0)+barrier: stage(s) landed; buffers handed over
    if (s + 1 < NT) stage(s + 1, (s + 1) & 1);
    const int bb = (s & 1) * 32768;
    const bf16* La = LDS + bb + abase + lm * 64;
    const bf16* Lb = LDS + bb + bbase + (brow0 + lm) * 64;
    bf16x8 a0[4][2], a1[4][2], b0[2][2], b1[2][2];
    #pragma unroll
    for (int f = 0; f < 4; f++) {
      a0[f][0] = *(const bf16x8*)(La + f * 1024 + kq0);
      a0[f][1] = *(const bf16x8*)(La + f * 1024 + kq1);
    }
    #pragma unroll
    for (int g = 0; g < 2; g++) {
      b0[g][0] = *(const bf16x8*)(Lb + g * 1024 + kq0);
      b0[g][1] = *(const bf16x8*)(Lb + g * 1024 + kq1);
    }
    // ---- Q00: acc[f][g] += A0 . B0 ----
    __builtin_amdgcn_s_setprio(1);
    #pragma unroll
    for (int f = 0; f < 4; f++)
      #pragma unroll
      for (int g = 0; g < 2; g++) {
        acc[f][g] = __builtin_amdgcn_mfma_f32_16x16x32_bf16(a0[f][0], b0[g][0], acc[f][g], 0, 0, 0);
        acc[f][g] = __builtin_amdgcn_mfma_f32_16x16x32_bf16(a0[f][1], b0[g][1], acc[f][g], 0, 0, 0);
      }
    __builtin_amdgcn_s_setprio(0);
    #pragma unroll
    for (int g = 0; g < 2; g++) {
      b1[g][0] = *(const bf16x8*)(Lb + 2048 + g * 1024 + kq0);
      b1[g][1] = *(const bf16x8*)(Lb + 2048 + g * 1024 + kq1);
    }
    // ---- Q01: acc[f][2+g] += A0 . B1 ----
    __builtin_amdgcn_s_setprio(1);
    #pragma unroll
    for (int f = 0; f < 4; f++)
      #pragma unroll
      for (int g = 0; g < 2; g++) {
        acc[f][2 + g] = __builtin_amdgcn_mfma_f32_16x16x32_bf16(a0[f][0], b1[g][0], acc[f][2 + g], 0, 0, 0);
        acc[f][2 + g] = __builtin_amdgcn_mfma_f32_16x16x32_bf16(a0[f][1], b1[g][1], acc[f][2 + g], 0, 0, 0);
      }
    __builtin_amdgcn_s_setprio(0);
    #pragma unroll
    for (int f = 0; f < 4; f++) {
      a1[f][0] = *(const bf16x8*)(La + 4096 + f * 1024 + kq0);
      a1[f][1] = *(const bf16x8*)(La + 4096 + f * 1024 + kq1);
    }
    // ---- Q11: acc[4+f][2+g] += A1 . B1 ----
    __builtin_amdgcn_s_setprio(1);
    #pragma unroll
    for (int f = 0; f < 4; f++)
      #pragma unroll
      for (int g = 0; g < 2; g++) {
        acc[4 + f][2 + g] = __builtin_amdgcn_mfma_f32_16x16x32_bf16(a1[f][0], b1[g][0], acc[4 + f][2 + g], 0, 0, 0);
        acc[4 + f][2 + g] = __builtin_amdgcn_mfma_f32_16x16x32_bf16(a1[f][1], b1[g][1], acc[4 + f][2 + g], 0, 0, 0);
      }
    __builtin_amdgcn_s_setprio(0);
    // ---- Q10: acc[4+f][g] += A1 . B0 (b0 kept live from phase 0) ----
    __builtin_amdgcn_s_setprio(1);
    #pragma unroll
    for (int f = 0; f < 4; f++)
      #pragma unroll
      for (int g = 0; g < 2; g++) {
        acc[4 + f][g] = __builtin_amdgcn_mfma_f32_16x16x32_bf16(a1[f][0], b0[g][0], acc[4 + f][g], 0, 0, 0);
        acc[4 + f][g] = __builtin_amdgcn_mfma_f32_16x16x32_bf16(a1[f][1], b0[g][1], acc[4 + f][g], 0, 0, 0);
      }
    __builtin_amdgcn_s_setprio(0);
  }
  // ---- epilogue ----
  const long cz = (long)z * cZs;
  #pragma unroll
  for (int i = 0; i < 8; i++) {
    const int row = m0 + wm * 128 + (i >> 2) * 64 + (i & 3) * 16 + lq * 4;
    #pragma unroll
    for (int j = 0; j < 4; j++) {
      const int col = n0 + wn * 64 + (j >> 1) * 32 + (j & 1) * 16 + lm;
      const float bv = bias ? bias[col] : 0.f;
      #pragma unroll
      for (int rr = 0; rr < 4; rr++) {
        float v = acc[i][j][rr] + bv;
        if (ACT == 1) v = silu(v);
        C[cz + (long)(row + rr) * ldc + col] = (bf16)v;
      }
    }
  }
}

// ---------------- bf16 MFMA GEMM 64x128 tile ----------------
// NORM=1 (qkv mode): after silu, 8-col-group rmsnorm for Q (x==0, qn, prescale) and
// K (x==1, kn); V (x==2) passthrough.
template <int ACT, int OUTBF, int ACC, int NORM>
__global__ __launch_bounds__(256) void gemm64(
    const bf16* __restrict__ A, int lda, long aZs,
    const bf16* __restrict__ Bt, int ldb, long bZs,
    const float* __restrict__ bias, int biasZs,
    void* __restrict__ Cv, int ldc, long cZs,
    int M, int N, int K,
    const float* __restrict__ qn, const float* __restrict__ kn) {
  __shared__ bf16 As[64 * 32];
  __shared__ bf16 Bs[128 * 32];
  int tid = threadIdx.x;
  int m0 = blockIdx.y * 64, n0 = blockIdx.x * 128;
  int z = blockIdx.z;
  const bf16* Ab = A + (long)z * aZs;
  const bf16* Bb = Bt + (long)z * bZs;
  f32x4 acc[4][2] = {};
  int wv = tid >> 6, lane = tid & 63;
  int lm = lane & 15, lq = lane >> 4;
  int wcol = wv * 32;
  const bf16* ag = Ab + (long)(m0 + (tid >> 2)) * lda + (tid & 3) * 8;
  const bf16* bg = Bb + (long)(n0 + (tid >> 2)) * ldb + (tid & 3) * 8;
  bf16* asd = As + tid * 8;
  bf16* bsd = Bs + tid * 8;
  for (int k0 = 0; k0 < K; k0 += 32) {
    gl16(ag + k0, asd);
    gl16(bg + k0, bsd);
    gl16(bg + k0 + 64L * ldb, bsd + 2048);
    __syncthreads();
    bf16x8 af[4], bfr[2];
    #pragma unroll
    for (int i = 0; i < 4; i++)
      af[i] = *(const bf16x8*)(As + (i * 16 + lm) * 32 + lq * 8);
    #pragma unroll
    for (int j = 0; j < 2; j++)
      bfr[j] = *(const bf16x8*)(Bs + (wcol + j * 16 + lm) * 32 + lq * 8);
    #pragma unroll
    for (int i = 0; i < 4; i++)
      #pragma unroll
      for (int j = 0; j < 2; j++)
        acc[i][j] = __builtin_amdgcn_mfma_f32_16x16x32_bf16(af[i], bfr[j], acc[i][j], 0, 0, 0);
    __syncthreads();
  }
  long cz = (long)z * cZs;
  const float* bz = bias ? bias + (long)z * biasZs : nullptr;
  if constexpr (NORM == 0) {
    #pragma unroll
    for (int i = 0; i < 4; i++) {
      int row = m0 + i * 16 + lq * 4;
      #pragma unroll
      for (int j = 0; j < 2; j++) {
        int col = n0 + wcol + j * 16 + lm;
        float bv = bz ? bz[col] : 0.f;
        #pragma unroll
        for (int r = 0; r < 4; r++) {
          float v = acc[i][j][r] + bv;
          long off = cz + (long)(row + r) * ldc + col;
          if (ACC) v += (float)((bf16*)Cv)[off];
          if (ACT == 1) v = silu(v);
          if (OUTBF) ((bf16*)Cv)[off] = (bf16)v;
          else       ((float*)Cv)[off] = v;
        }
      }
    }
  } else {
    int nsec = blockIdx.x;              // 0=Q, 1=K, 2=V
    bool don = nsec < 2;
    float wnv = 1.f;
    if (nsec == 0) wnv = qn[z * 8 + (lm & 7)] * QSCALE_E;
    else if (nsec == 1) wnv = kn[z * 8 + (lm & 7)];
    #pragma unroll
    for (int i = 0; i < 4; i++) {
      int row = m0 + i * 16 + lq * 4;
      #pragma unroll
      for (int j = 0; j < 2; j++) {
        int col = n0 + wcol + j * 16 + lm;
        float bv = bz ? bz[col] : 0.f;
        #pragma unroll
        for (int r = 0; r < 4; r++) {
          float v = acc[i][j][r] + bv;
          if (ACT == 1) v = silu(v);
          float s = v * v;
          s += __shfl_xor(s, 1);
          s += __shfl_xor(s, 2);
          s += __shfl_xor(s, 4);
          if (don) v = v * rsqrtf(s * 0.125f + EPS) * wnv;
          ((bf16*)Cv)[cz + (long)(row + r) * ldc + col] = (bf16)v;
        }
      }
    }
  }
}

// ---------------- embed + rmsnorm -> bf16 h ----------------
__global__ __launch_bounds__(256) void k_embed(const float* __restrict__ x,
    const float* __restrict__ emb, const float* __restrict__ pos,
    const float* __restrict__ nw, bf16* __restrict__ h) {
  __shared__ float red[4];
  int row = blockIdx.x;
  int l = row % Lq;
  int xi = (int)(x[row] * 255.f);
  xi = min(max(xi, 0), 255);
  const float* er = emb + (long)xi * WIDTH;
  const float* pr = pos + (long)l * WIDTH;
  int c0 = threadIdx.x * 4;
  float v[4]; float ss = 0.f;
  #pragma unroll
  for (int i = 0; i < 4; i++) { v[i] = er[c0 + i] + pr[c0 + i]; ss += v[i] * v[i]; }
  ss = blockReduceSum256(ss, red);
  float r = rsqrtf(ss / WIDTH + EPS);
  bf16* hr = h + (long)row * WIDTH;
  #pragma unroll
  for (int i = 0; i < 4; i++) hr[c0 + i] = (bf16)(v[i] * r * nw[c0 + i]);
}

// ---------------- mean over L, phase 1: 16 partials per b ----------------
__global__ void k_meanl_p(const bf16* __restrict__ h, float* __restrict__ part) {
  int lp = blockIdx.x, b = blockIdx.y, t = threadIdx.x;
  const bf16* p = h + ((long)b * Lq + (long)lp * 36) * WIDTH + t * 4;
  float a0 = 0, a1 = 0, a2 = 0, a3 = 0;
  for (int l = 0; l < 36; l++) {
    bf16x4 v = *(const bf16x4*)(p + (long)l * WIDTH);
    a0 += (float)v[0]; a1 += (float)v[1]; a2 += (float)v[2]; a3 += (float)v[3];
  }
  float* dst = part + ((long)b * 16 + lp) * WIDTH + t * 4;
  dst[0] = a0; dst[1] = a1; dst[2] = a2; dst[3] = a3;
}

// ---------------- SE phase 1 ----------------
__global__ __launch_bounds__(256) void k_se1(const float* __restrict__ part,
    const float* __restrict__ w1, const float* __restrict__ b1,
    float* __restrict__ t1) {
  __shared__ float sv[1024];
  __shared__ float red[256];
  int jb = blockIdx.x, b = blockIdx.y, t = threadIdx.x;
  for (int c = t; c < 1024; c += 256) {
    float a = 0.f;
    #pragma unroll
    for (int lp = 0; lp < 16; lp++) a += part[((long)b * 16 + lp) * 1024 + c];
    sv[c] = a * (1.f / 576.f);
  }
  __syncthreads();
  int j = t & 7, pt = t >> 3;
  int j0 = jb * 8;
  float acc = 0.f;
  int c0 = pt * 32;
  #pragma unroll 8
  for (int c = c0; c < c0 + 32; c++) acc += sv[c] * w1[c * 256 + j0 + j];
  red[t] = acc;
  __syncthreads();
  if (t < 8) {
    float a = b1[j0 + t];
    #pragma unroll
    for (int p = 0; p < 32; p++) a += red[p * 8 + t];
    t1[b * 256 + j0 + t] = silu(a);
  }
}

// ---------------- SE phase 2 ----------------
__global__ __launch_bounds__(256) void k_se2(const float* __restrict__ t1,
    const float* __restrict__ w2, const float* __restrict__ b2,
    float* __restrict__ s) {
  __shared__ float red[256];
  int jb = blockIdx.x, b = blockIdx.y, t = threadIdx.x;
  int j = t & 31, pt = t >> 5;
  int j0 = jb * 32;
  const float* tb = t1 + b * 256;
  float acc = 0.f;
  int c0 = pt * 32;
  #pragma unroll 8
  for (int c = c0; c < c0 + 32; c++) acc += tb[c] * w2[c * 1024 + j0 + j];
  red[t] = acc;
  __syncthreads();
  if (t < 32) {
    float a = b2[j0 + t];
    #pragma unroll
    for (int p = 0; p < 8; p++) a += red[p * 32 + t];
    s[b * 1024 + j0 + t] = 1.f / (1.f + __expf(-a));
  }
}

// ---------------- mix: h += rmsnorm(h*(s-1), mw) ----------------
__global__ __launch_bounds__(256) void k_mix_b(bf16* __restrict__ h,
    const float* __restrict__ s, const float* __restrict__ mw) {
  __shared__ float red[4];
  int row = blockIdx.x;
  int b = row / Lq;
  bf16* hr = h + (long)row * WIDTH;
  const float* sb = s + b * WIDTH;
  int c0 = threadIdx.x * 4;
  float hv[4], y[4]; float ss = 0.f;
  #pragma unroll
  for (int i = 0; i < 4; i++) {
    hv[i] = (float)hr[c0 + i];
    y[i] = hv[i] * (sb[c0 + i] - 1.f); ss += y[i] * y[i];
  }
  ss = blockReduceSum256(ss, red);
  float r = rsqrtf(ss / WIDTH + EPS);
  #pragma unroll
  for (int i = 0; i < 4; i++) hr[c0 + i] = (bf16)(hv[i] + y[i] * r * mw[c0 + i]);
}

// ---------------- h += rmsnorm(g, mw) ----------------
__global__ __launch_bounds__(256) void k_addnorm_b(bf16* __restrict__ h,
    const bf16* __restrict__ g, const float* __restrict__ mw) {
  __shared__ float red[4];
  int row = blockIdx.x;
  bf16* hr = h + (long)row * WIDTH;
  const bf16* gr = g + (long)row * WIDTH;
  int c0 = threadIdx.x * 4;
  float y[4]; float ss = 0.f;
  #pragma unroll
  for (int i = 0; i < 4; i++) { y[i] = (float)gr[c0 + i]; ss += y[i] * y[i]; }
  ss = blockReduceSum256(ss, red);
  float r = rsqrtf(ss / WIDTH + EPS);
  #pragma unroll
  for (int i = 0; i < 4; i++)
    hr[c0 + i] = (bf16)((float)hr[c0 + i] + y[i] * r * mw[c0 + i]);
}

// ---------------- h += rmsnorm(p0 + p1 + b2, mw)  (2-way K-split partials) --------
__global__ __launch_bounds__(256) void k_addnorm2(bf16* __restrict__ h,
    const bf16* __restrict__ p0, const bf16* __restrict__ p1,
    const float* __restrict__ b2, const float* __restrict__ mw) {
  __shared__ float red[4];
  int row = blockIdx.x;
  bf16* hr = h + (long)row * WIDTH;
  const bf16* g0 = p0 + (long)row * WIDTH;
  const bf16* g1 = p1 + (long)row * WIDTH;
  int c0 = threadIdx.x * 4;
  float y[4]; float ss = 0.f;
  #pragma unroll
  for (int i = 0; i < 4; i++) {
    y[i] = (float)g0[c0 + i] + (float)g1[c0 + i] + b2[c0 + i];
    ss += y[i] * y[i];
  }
  ss = blockReduceSum256(ss, red);
  float r = rsqrtf(ss / WIDTH + EPS);
  #pragma unroll
  for (int i = 0; i < 4; i++)
    hr[c0 + i] = (bf16)((float)hr[c0 + i] + y[i] * r * mw[c0 + i]);
}

// ---------------- h += rmsnorm(p0+p1+p2+p3 + b2, mw)  (4-way K-split) -------------
__global__ __launch_bounds__(256) void k_addnorm4(bf16* __restrict__ h,
    const bf16* __restrict__ parts, const float* __restrict__ b2,
    const float* __restrict__ mw) {
  __shared__ float red[4];
  int row = blockIdx.x;
  bf16* hr = h + (long)row * WIDTH;
  const bf16* g0 = parts + (long)row * WIDTH;
  int c0 = threadIdx.x * 4;
  float y[4]; float ss = 0.f;
  #pragma unroll
  for (int i = 0; i < 4; i++) {
    float a = b2[c0 + i];
    #pragma unroll
    for (int p = 0; p < 4; p++) a += (float)g0[(long)p * PSTRIDE + c0 + i];
    y[i] = a; ss += a * a;
  }
  ss = blockReduceSum256(ss, red);
  float r = rsqrtf(ss / WIDTH + EPS);
  #pragma unroll
  for (int i = 0; i < 4; i++)
    hr[c0 + i] = (bf16)((float)hr[c0 + i] + y[i] * r * mw[c0 + i]);
}

// ---------------- router + lambdas ----------------
__global__ __launch_bounds__(256) void k_router(const float* __restrict__ part,
    const float* __restrict__ rwgt, const float* __restrict__ rb,
    const float* __restrict__ lq1, const float* __restrict__ lk1,
    const float* __restrict__ lq2, const float* __restrict__ lk2,
    float* __restrict__ rw, float* __restrict__ lam) {
  __shared__ float sv[1024];
  __shared__ float red[256];
  __shared__ float lg[8];
  int b = blockIdx.x, t = threadIdx.x;
  for (int c = t; c < 1024; c += 256) {
    float a = 0.f;
    #pragma unroll
    for (int lp = 0; lp < 16; lp++) a += part[((long)b * 16 + lp) * 1024 + c];
    sv[c] = a * (1.f / 576.f);
  }
  __syncthreads();
  int j = t & 7, pt = t >> 3;
  float acc = 0.f;
  int c0 = pt * 32;
  #pragma unroll 8
  for (int c = c0; c < c0 + 32; c++) acc += sv[c] * rwgt[c * 8 + j];
  red[t] = acc;
  __syncthreads();
  if (t < 8) {
    float a = rb[t];
    for (int p = 0; p < 32; p++) a += red[p * 8 + t];
    lg[t] = a;
  }
  __syncthreads();
  if (t == 0) {
    float v[8]; bool sel[8];
    #pragma unroll
    for (int i = 0; i < 8; i++) { v[i] = lg[i]; sel[i] = false; }
    int idxs[4]; float vals[4];
    for (int s = 0; s < 4; s++) {
      int bi = -1; float bv = -1e30f;
      for (int i = 0; i < 8; i++) if (!sel[i] && v[i] > bv) { bv = v[i]; bi = i; }
      sel[bi] = true; idxs[s] = bi; vals[s] = bv;
    }
    float m = vals[0], den = 0.f, e[4];
    for (int s = 0; s < 4; s++) { e[s] = __expf(vals[s] - m); den += e[s]; }
    for (int i = 0; i < 8; i++) rw[b * 8 + i] = 0.f;
    for (int s = 0; s < 4; s++) rw[b * 8 + idxs[s]] = e[s] / den;
  }
  if (b == 0 && t >= 8 && t < 16) {
    int c = t - 8;
    float d1 = 0.f, d2 = 0.f;
    for (int i = 0; i < 8; i++) {
      d1 += lq1[c * 8 + i] * lk1[c * 8 + i];
      d2 += lq2[c * 8 + i] * lk2[c * 8 + i];
    }
    lam[c] = __expf(d1) - __expf(d2) + LAMINIT;
  }
}

// ---------------- MFMA causal differential attention (prenormed Q/K) --------------
// den on the MFMA pipe (ONES ones-vector trick). K staged via gl16 [576][16];
// V staged column-major Vt[16][584] (R3-verified layout). 512 threads = 8
// waves per block, grid (64,1,8): each (slice,head) staged ONCE, per-wave pr
// map u = wv in [0,8): u<6 pair {u+2, 17-u}; u>=6 triple {u-6, u+2, 17-u}.
// LDS 37376 B.
__global__ __launch_bounds__(512) void k_attn_mfma(
    const bf16* __restrict__ qkv, const float* __restrict__ lam,
    const float* __restrict__ hnw, bf16* __restrict__ dc) {
  __shared__ bf16 Ks[576 * 16];
  __shared__ bf16 Vt[16 * 584];
  int tid = threadIdx.x;
  int slice = blockIdx.x; int zc = slice >> 3, b = slice & 7;
  int head = blockIdx.z;
  const bf16* qkvb = qkv + ((long)zc * ROWS + (long)b * Lq) * 384;
  for (int i = tid; i < 1152; i += 512) {
    int row = i >> 1, hf = i & 1;
    gl16(qkvb + (long)row * 384 + 128 + head * 16 + hf * 8, Ks + i * 8);
  }
  for (int i = tid; i < 1152; i += 512) {
    int row = i >> 1, dh = i & 1;
    bf16x8 v = *(const bf16x8*)(qkvb + (long)row * 384 + 256 + head * 16 + dh * 8);
    #pragma unroll
    for (int j = 0; j < 8; j++) Vt[(dh * 8 + j) * 584 + row] = v[j];
  }
  __syncthreads();
  int wv = tid >> 6, lane = tid & 63;
  int lm = lane & 15, lq = lane >> 4;
  float lamv = lam[zc];
  float hwv[4];
  #pragma unroll
  for (int r = 0; r < 4; r++) hwv[r] = hnw[zc * 16 + lq * 4 + r] * (1.f - LAMINIT);
  const bf16 one = (bf16)1.0f;
  const bf16x4 ONES = {one, one, one, one};
  int u = wv;                           // 8 waves -> u in [0,8)
  int prA, prB, prC;
  if (u < 6) { prA = u + 2; prB = 17 - u; prC = -1; }
  else       { int v2 = u - 6; prA = v2; prB = 8 + v2; prC = 11 - v2; }
  for (int pi = 0; pi < 3; pi++) {
    int pr = (pi == 0) ? prA : (pi == 1) ? prB : prC;
    if (pr < 0) continue;
    bf16x8 bq0[2] = {{}, {}}, bq1[2] = {{}, {}};
    if (lq < 2) {
      #pragma unroll
      for (int tile = 0; tile < 2; tile++) {
        bf16x8 t8 = *(const bf16x8*)(
            qkvb + (long)(pr * 32 + tile * 16 + lm) * 384 + head * 16 + lq * 8);
        if (lq == 0) bq0[tile] = t8; else bq1[tile] = t8;
      }
    }
    f32x4 o[2][2] = {};
    f32x4 dacc[2][2] = {};
    for (int kc = 0; kc <= pr; kc++) {
      f32x4 sT[2][2][2] = {};
      #pragma unroll
      for (int t = 0; t < 2; t++) {
        bf16x8 aK = {};
        if (lq < 2) aK = *(const bf16x8*)(Ks + (kc * 32 + t * 16 + lm) * 16 + lq * 8);
        #pragma unroll
        for (int tile = 0; tile < 2; tile++) {
          sT[t][tile][0] = __builtin_amdgcn_mfma_f32_16x16x32_bf16(aK, bq0[tile], sT[t][tile][0], 0, 0, 0);
          sT[t][tile][1] = __builtin_amdgcn_mfma_f32_16x16x32_bf16(aK, bq1[tile], sT[t][tile][1], 0, 0, 0);
        }
      }
      bool diag = (kc == pr);
      #pragma unroll
      for (int t = 0; t < 2; t++) {
        bf16x4 aV = *(const bf16x4*)(Vt + lm * 584 + kc * 32 + t * 16 + lq * 4);
        #pragma unroll
        for (int tile = 0; tile < 2; tile++) {
          if (diag && tile == 0 && t == 1) continue;
          bool masked = diag && (tile == t);
          #pragma unroll
          for (int h2 = 0; h2 < 2; h2++) {
            bf16x4 pb;
            #pragma unroll
            for (int r = 0; r < 4; r++) {
              float ev = fexp2(sT[t][tile][h2][r]);
              if (masked && (lq * 4 + r > lm)) ev = 0.f;
              pb[r] = (bf16)ev;
            }
            dacc[tile][h2] = mfma16(ONES, pb, dacc[tile][h2]);
            o[tile][h2] = mfma16(aV, pb, o[tile][h2]);
          }
        }
      }
    }
    #pragma unroll
    for (int tile = 0; tile < 2; tile++) {
      float inv1 = 1.f / dacc[tile][0][0];
      float inv2 = lamv / dacc[tile][1][0];
      float dff[4]; float ss = 0.f;
      #pragma unroll
      for (int r = 0; r < 4; r++) {
        dff[r] = o[tile][0][r] * inv1 - o[tile][1][r] * inv2;
        ss += dff[r] * dff[r];
      }
      ss += __shfl_xor(ss, 16);
      ss += __shfl_xor(ss, 32);
      float rr = rsqrtf(ss * 0.0625f + EPS);
      bf16x4 outp;
      #pragma unroll
      for (int r = 0; r < 4; r++) outp[r] = (bf16)(dff[r] * rr * hwv[r]);
      long rowg = (long)zc * ROWS + (long)b * Lq + pr * 32 + tile * 16 + lm;
      *(bf16x4*)(dc + rowg * 128 + head * 16 + lq * 4) = outp;
    }
  }
}

// ---------------- seg + pool fused: 16 bins, 1-wave blocks ----------------
__global__ __launch_bounds__(64) void k_segpool(const bf16* __restrict__ h,
    const bf16* __restrict__ op, const float* __restrict__ segw,
    const float* __restrict__ rw, float* __restrict__ part) {
  int lp = blockIdx.x, b = blockIdx.y, ch = blockIdx.z;
  int t = threadIdx.x;
  int c0 = t * 2;
  float w0 = segw[ch * 128 + c0], w1 = segw[ch * 128 + c0 + 1];
  float rwv = rw[b * 8 + ch];
  float a0 = 0.f, a1 = 0.f;
  for (int l = 0; l < 36; l++) {
    int row = b * Lq + lp * 36 + l;
    const bf16* oprow = op + (long)ch * ROWS * CW + (long)row * CW;
    bf16x2 yv = *(const bf16x2*)(oprow + c0);
    float y0 = (float)yv[0], y1 = (float)yv[1];
    float ss = y0 * y0 + y1 * y1;
    #pragma unroll
    for (int m = 1; m < 64; m <<= 1) ss += __shfl_xor(ss, m);
    float r = rsqrtf(ss * (1.f / 128.f) + EPS);
    bf16x2 hv = *(const bf16x2*)(h + (long)row * WIDTH + ch * 128 + c0);
    a0 += ((float)hv[0] + y0 * r * w0) * rwv;
    a1 += ((float)hv[1] + y1 * r * w1) * rwv;
  }
  float* dst = part + ((long)b * 16 + lp) * 1024 + ch * 128 + c0;
  dst[0] = a0; dst[1] = a1;
}

// ---------------- head (reads 16 pool partials) ----------------
__global__ __launch_bounds__(256) void k_head(const float* __restrict__ part,
    const float* __restrict__ hw, const float* __restrict__ hb, float* __restrict__ out) {
  __shared__ float pool[1024];
  __shared__ float red[256];
  int b = blockIdx.x, t = threadIdx.x;
  for (int c = t; c < 1024; c += 256) {
    float a = 0.f;
    #pragma unroll
    for (int lp = 0; lp < 16; lp++) a += part[((long)b * 16 + lp) * 1024 + c];
    pool[c] = a * (1.f / 576.f);
  }
  __syncthreads();
  int j = t & 15, pt = t >> 4;
  float acc = 0.f;
  if (j < 10)
    for (int c = pt * 64; c < pt * 64 + 64; c++)
      acc += pool[c] * hw[c * 10 + j];
  red[t] = acc;
  __syncthreads();
  if (t < 10) {
    float a = hb[t];
    for (int p = 0; p < 16; p++) a += red[p * 16 + t];
    out[b * 10 + t] = a;
  }
}

// ---------------- launcher ----------------
extern "C" void kernel_launch(void* const* d_in, const int* in_sizes, int n_in,
                              void* d_out, int out_size, void* d_ws, size_t ws_size,
                              hipStream_t stream) {
  const float* x          = (const float*)d_in[0];
  const float* pixel_embed= (const float*)d_in[2];
  const float* freq_h     = (const float*)d_in[3];
  const float* freq_w     = (const float*)d_in[4];
  const float* phase_h    = (const float*)d_in[5];
  const float* phase_w    = (const float*)d_in[6];
  const float* pos_proj_w = (const float*)d_in[7];
  const float* pos_proj_b = (const float*)d_in[8];
  const float* embed_norm = (const float*)d_in[9];
  const float* se_w1      = (const float*)d_in[10];
  const float* se_b1      = (const float*)d_in[11];
  const float* se_w2      = (const float*)d_in[12];
  const float* se_b2      = (const float*)d_in[13];
  const float* mix_norm   = (const float*)d_in[14];
  const float* mlp_w1     = (const float*)d_in[15];
  const float* mlp_b1     = (const float*)d_in[16];
  const float* mlp_w2     = (const float*)d_in[17];
  const float* mlp_b2     = (const float*)d_in[18];
  const float* mlp_norm   = (const float*)d_in[19];
  const float* router_w   = (const float*)d_in[20];
  const float* router_b   = (const float*)d_in[21];
  const float* qkv_w      = (const float*)d_in[22];
  const float* qkv_b      = (const float*)d_in[23];
  const float* q_norm_w   = (const float*)d_in[24];
  const float* k_norm_w   = (const float*)d_in[25];
  const float* head_norm_w= (const float*)d_in[26];
  const float* lam_q1     = (const float*)d_in[27];
  const float* lam_k1     = (const float*)d_in[28];
  const float* lam_q2     = (const float*)d_in[29];
  const float* lam_k2     = (const float*)d_in[30];
  const float* out_w      = (const float*)d_in[31];
  const float* out_b      = (const float*)d_in[32];
  const float* seg_norm_w = (const float*)d_in[33];
  const float* head_w     = (const float*)d_in[34];
  const float* head_b     = (const float*)d_in[35];

  char* W = (char*)d_ws;
  bf16*  HB    = (bf16*)(W + B_HB);
  bf16*  G2B   = (bf16*)(W + B_G2B);
  float* POS   = (float*)(W + B_G2B);      // POS lives in G2B region (dead until MLP)
  bf16*  ENCB  = (bf16*)(W + B_ENCB);
  bf16*  POSWT = (bf16*)(W + B_POSWT);
  bf16*  QKVWT = (bf16*)(W + B_QKVWT);
  bf16*  OWT   = (bf16*)(W + B_OWT);
  float* SE    = (float*)(W + B_SE);
  float* T1    = (float*)(W + B_T1);
  float* MP    = (float*)(W + B_MP);
  float* RW    = (float*)(W + B_RW);
  float* LAM   = (float*)(W + B_LAM);
  char*  P     = W + B_POOL;
  bf16*  W1T   = (bf16*)P;
  bf16*  W2T   = (bf16*)(P + 8388608);
  bf16*  HID   = (bf16*)(P + 16777216);
  bf16*  PARTS = (bf16*)(P + 16777216 + 37748736);   // after full-width HID
  bf16*  QKV   = (bf16*)P;
  bf16*  DC    = (bf16*)(P + 28311552);
  float* out   = (float*)d_out;
  const int tier = (ws_size >= WS_BIG3) ? 3 : (ws_size >= WS_BIG2) ? 2
                 : (ws_size >= WS_BIG) ? 1 : 0;

  // 0. all weight casts in one dispatch
  k_tcast_all<<<8832, 256, 0, stream>>>(mlp_w1, mlp_w2, pos_proj_w, qkv_w, out_w,
                                        W1T, W2T, POSWT, QKVWT, OWT);
  // 1. positional encoding + projection (POS f32 in G2B region)
  k_enc_b<<<288, 256, 0, stream>>>(freq_h, freq_w, phase_h, phase_w, ENCB);
  gemm64<0, 0, 0, 0><<<dim3(8, 10, 1), 256, 0, stream>>>(
      ENCB, 128, 0, POSWT, 128, 0, pos_proj_b, 0, POS, 1024, 0, 640, 1024, 128,
      nullptr, nullptr);
  // 2. embed + rmsnorm -> bf16 h
  k_embed<<<ROWS, 256, 0, stream>>>(x, pixel_embed, POS, embed_norm, HB);
  // 3. SE gate
  k_meanl_p<<<dim3(16, 8), 256, 0, stream>>>(HB, MP);
  k_se1<<<dim3(32, 8), 256, 0, stream>>>(MP, se_w1, se_b1, T1);
  k_se2<<<dim3(32, 8), 256, 0, stream>>>(T1, se_w2, se_b2, SE);
  k_mix_b<<<ROWS, 256, 0, stream>>>(HB, SE, mix_norm);
  // 4. MLP
  if (tier >= 1) {
    // gemm1 main: 256^2 8-wave kernel, rows 0..4095 (16m x 16n = 256 blocks,
    // one block/CU); tail rows 4096..4607 via gemm64 64-row tiles (256 blocks
    // -> full chip).
    gemm256<1><<<256, 512, 0, stream>>>(
        HB, 1024, 0, W1T, 1024, 0, mlp_b1,
        HID, 4096, 0, 16, 16, 1024);
    gemm64<1, 1, 0, 0><<<dim3(32, 8, 1), 256, 0, stream>>>(
        HB + 4096L * 1024, 1024, 0, W1T, 1024, 0, mlp_b1, 0,
        HID + 4096L * 4096, 4096, 0, 512, 4096, 1024, nullptr, nullptr);
    if (tier == 3) {
      // gemm2 main: 4-way K-split, 16m x 4n x 4z = 256 blocks; tail via gemm64
      // 64-row tiles (8n x 8m x 4z = 256 blocks, full chip).
      gemm256<0><<<256, 512, 0, stream>>>(
          HID, 4096, 1024, W2T, 4096, 1024, nullptr,
          PARTS, 1024, PSTRIDE, 16, 4, 1024);
      gemm64<0, 1, 0, 0><<<dim3(8, 8, 4), 256, 0, stream>>>(
          HID + 4096L * 4096, 4096, 1024, W2T, 4096, 1024, nullptr, 0,
          PARTS + 4096L * 1024, 1024, PSTRIDE, 512, 1024, 1024, nullptr, nullptr);
      k_addnorm4<<<ROWS, 256, 0, stream>>>(HB, PARTS, mlp_b2, mlp_norm);
    } else if (tier == 2) {
      // gemm2: 2-way K-split, XCD-pinned, partials in G2B + PARTS[0]
      gemm_bt<0, 1, 2><<<576, 256, 0, stream>>>(
          HID, 4096, 2048, W2T, 4096, 2048, nullptr, 0,
          G2B, 1024, (long)(PARTS - G2B), 4608, 1024, 2048);
      k_addnorm2<<<ROWS, 256, 0, stream>>>(HB, G2B, PARTS, mlp_b2, mlp_norm);
    } else {
      gemm64<0, 1, 0, 0><<<dim3(8, 72, 1), 256, 0, stream>>>(
          HID, 4096, 0, W2T, 4096, 0, mlp_b2, 0,
          G2B, 1024, 0, 4608, 1024, 4096, nullptr, nullptr);
      k_addnorm_b<<<ROWS, 256, 0, stream>>>(HB, G2B, mlp_norm);
    }
  } else {
    gemm_bt<1, 1, 0><<<dim3(16, 36, 1), 256, 0, stream>>>(
        HB, 1024, 0, W1T, 1024, 0, mlp_b1, 0, HID, 2048, 0, 4608, 2048, 1024);
    gemm64<0, 1, 0, 0><<<dim3(8, 72, 1), 256, 0, stream>>>(
        HID, 2048, 0, W2T, 4096, 0, mlp_b2, 0, G2B, 1024, 0, 4608, 1024, 2048,
        nullptr, nullptr);
    gemm_bt<1, 1, 0><<<dim3(16, 36, 1), 256, 0, stream>>>(
        HB, 1024, 0, W1T + 2048L * 1024, 1024, 0, mlp_b1 + 2048, 0, HID, 2048, 0,
        4608, 2048, 1024);
    gemm64<0, 1, 1, 0><<<dim3(8, 72, 1), 256, 0, stream>>>(
        HID, 2048, 0, W2T + 2048, 4096, 0, nullptr, 0, G2B, 1024, 0,
        4608, 1024, 2048, nullptr, nullptr);
    k_addnorm_b<<<ROWS, 256, 0, stream>>>(HB, G2B, mlp_norm);
  }
  // 5. router + lambdas
  k_meanl_p<<<dim3(16, 8), 256, 0, stream>>>(HB, MP);
  k_router<<<8, 256, 0, stream>>>(MP, router_w, router_b,
                                  lam_q1, lam_k1, lam_q2, lam_k2, RW, LAM);
  // 6. qkv-proj with fused silu + Q/K rmsnorm (+ Q prescale) in epilogue
  gemm64<1, 1, 0, 1><<<dim3(3, 72, 8), 256, 0, stream>>>(
      HB, 1024, CW, QKVWT, 128, 384 * 128, qkv_b, 384,
      QKV, 384, (long)ROWS * 384, ROWS, 384, 128, q_norm_w, k_norm_w);
  // 7. attention (prenormed), out-proj in-place on DC
  k_attn_mfma<<<dim3(64, 1, 8), 512, 0, stream>>>(QKV, LAM, head_norm_w, DC);
  gemm64<1, 1, 0, 0><<<dim3(1, 72, 8), 256, 0, stream>>>(
      DC, 128, (long)ROWS * 128, OWT, 128, 128 * 128, out_b, 128,
      DC, 128, (long)ROWS * 128, ROWS, 128, 128, nullptr, nullptr);
  // 8. seg + pool fused -> 16 partials; head folds the final reduce
  k_segpool<<<dim3(16, 8, 8), 64, 0, stream>>>(HB, DC, seg_norm_w, RW, MP);
  k_head<<<8, 256, 0, stream>>>(MP, head_w, head_b, out);
}